// Round 5
// baseline (982.682 us; speedup 1.0000x reference)
//
#include <hip/hip_runtime.h>
#include <math.h>

// GCN 2-layer + sigmoid head. Bucket-staged edge-centric push aggregation.
// R20: delete k_sort + k_gat1 + k_gat2. The binned region (edges grouped per
//  256-node bucket, word=((d&255)<<18)|s) is aggregated directly: one block
//  per bucket, acc[256][F] in LDS, stream region coalesced, gather payload
//  (L2-resident), LDS fp32 atomics (ds_add_f32), per-node MLP epilogue from
//  LDS. Kills the latency-bound rowptr->csr->payload pull chase (R19's top
//  kernel), the 29MB csr write and its 2x25.6MB reads.
//   k_fb1:   per-chunk bucket histogram -> C[chunk][nb]; + global deg[dst]++
//   k_scan1: thread t scans bucket-column b over its chunk segment
//   k_scan2: scan 32 segment sums per bucket, fold b*CAP -> segbase, btot
//   k_prep:  dinv = rsqrt(deg+1); xdq = bf16(x*dinv) (prescaled payload)
//   k_fillbin: LDS chunk counting-sort -> binned (deterministic, no atomics)
//   k_agg1:  bucket push: acc6 += xdq[s]; epilogue @W1 relu @W2 *di -> g2q
//   k_agg2:  bucket push: acc8 += g2q[s]; fused head -> out

#define TPB 256
#define NBS 8
#define NBKT 256        // nodes per bucket
#define MAXB 1024       // max buckets (n <= 262144)
#define BPT (MAXB / TPB)
#define CHUNK 4096      // edges per fillbin block
#define EPT (CHUNK / TPB)
#define CAP 9216        // bucket region capacity (mean 8192 + ~11 sigma)
#define NWAVE (TPB / 64)
#define NSEG 32         // chunk segments for the 2-level offset scan

__device__ __forceinline__ unsigned short f2bf(float f) {
    unsigned u = __float_as_uint(f);
    unsigned r = (u + 0x7FFFu + ((u >> 16) & 1u)) >> 16;  // RNE
    return (unsigned short)r;
}
__device__ __forceinline__ unsigned pk2(float a, float b) {
    return (unsigned)f2bf(a) | ((unsigned)f2bf(b) << 16);
}
#define BFLO(u) __uint_as_float((u) << 16)
#define BFHI(u) __uint_as_float((u) & 0xFFFF0000u)

// per-chunk bucket histogram -> C[chunk][nb]; fused node-degree histogram
// (global non-returning atomics, hidden under the streaming read).
__global__ void __launch_bounds__(TPB) k_fb1(
        const int* __restrict__ dst, int* __restrict__ C,
        int* __restrict__ deg, int e, int nb) {
    __shared__ int h[MAXB];
    int t = threadIdx.x;
    int c0 = blockIdx.x * CHUNK;
    int csize = min(e - c0, CHUNK);
#pragma unroll
    for (int k = 0; k < BPT; k++) h[t * BPT + k] = 0;
    __syncthreads();
    if (csize == CHUNK && ((((size_t)(const void*)(dst + c0)) & 15) == 0)) {
        const int4* d4 = (const int4*)(dst + c0);
#pragma unroll
        for (int k = 0; k < EPT / 4; k++) {
            int4 d = d4[t + k * TPB];
            atomicAdd(&h[d.x >> NBS], 1);
            atomicAdd(&h[d.y >> NBS], 1);
            atomicAdd(&h[d.z >> NBS], 1);
            atomicAdd(&h[d.w >> NBS], 1);
            atomicAdd(&deg[d.x], 1);
            atomicAdd(&deg[d.y], 1);
            atomicAdd(&deg[d.z], 1);
            atomicAdd(&deg[d.w], 1);
        }
    } else {
        for (int i = t; i < csize; i += TPB) {
            int d = dst[c0 + i];
            atomicAdd(&h[d >> NBS], 1);
            atomicAdd(&deg[d], 1);
        }
    }
    __syncthreads();
    int* row = C + (size_t)blockIdx.x * nb;
    for (int b = t; b < nb; b += TPB) row[b] = h[b];
}

// level-1: thread t serially scans bucket-column b over chunk segment s.
__global__ void __launch_bounds__(TPB) k_scan1(
        const int* __restrict__ C, int* __restrict__ O, int* __restrict__ Sseg,
        int nchunk, int nb, int cps, int ngrp) {
    int bid = blockIdx.x;
    int s = bid / ngrp, g = bid - s * ngrp;
    int b = g * TPB + threadIdx.x;
    if (b >= nb) return;
    int cbeg = s * cps;
    int cend = min(cbeg + cps, nchunk);
    int run = 0;
#pragma unroll 4
    for (int c = cbeg; c < cend; c++) {
        int v = C[(size_t)c * nb + b];
        O[(size_t)c * nb + b] = run;
        run += v;
    }
    Sseg[s * nb + b] = run;
}

// level-2: per bucket, exclusive scan of NSEG segment sums; fold in b*CAP.
__global__ void __launch_bounds__(TPB) k_scan2(
        const int* __restrict__ Sseg, int* __restrict__ segbase,
        int* __restrict__ btot, int nb) {
    int b = blockIdx.x * TPB + threadIdx.x;
    if (b >= nb) return;
    int run = b * CAP;
#pragma unroll
    for (int s = 0; s < NSEG; s++) {
        segbase[s * nb + b] = run;
        run += Sseg[s * nb + b];
    }
    btot[b] = run - b * CAP;
}

// per-node: dinv = rsqrt(deg+1); xdq = bf16-packed x*dinv (prescaled payload)
__global__ void __launch_bounds__(TPB) k_prep(
        const int* __restrict__ deg, const float* __restrict__ x,
        float* __restrict__ dinv, uint4* __restrict__ xdq, int n) {
    int i = blockIdx.x * TPB + threadIdx.x;
    if (i >= n) return;
    float di = rsqrtf((float)(deg[i] + 1));
    dinv[i] = di;
    uint4 q;
    q.x = pk2(x[i * 6 + 0] * di, x[i * 6 + 1] * di);
    q.y = pk2(x[i * 6 + 2] * di, x[i * 6 + 3] * di);
    q.z = pk2(x[i * 6 + 4] * di, x[i * 6 + 5] * di);
    q.w = 0;
    xdq[i] = q;
}

// bin edges into fixed-cap bucket regions. LDS counting sort of the chunk;
// deterministic delta from segbase+O (no atomics). word: ((d&255)<<18)|s
__global__ void __launch_bounds__(TPB) k_fillbin(
        const int* __restrict__ src, const int* __restrict__ dst,
        const int* __restrict__ O, const int* __restrict__ segbase,
        int* __restrict__ binned, int e, int nb, int cps) {
    __shared__ int stage[CHUNK];            // 16 KB, bucket-sorted packed words
    __shared__ unsigned short bs[CHUNK];    // 8 KB, bucket id per sorted slot
    __shared__ int h[MAXB];                 // 4 KB, hist -> stage cursor
    __shared__ int delta[MAXB];             // 4 KB
    __shared__ int wsum[NWAVE];
    int t = threadIdx.x;
    int c0 = blockIdx.x * CHUNK;
    int csize = min(e - c0, CHUNK);
#pragma unroll
    for (int k = 0; k < BPT; k++) h[t * BPT + k] = 0;
    __syncthreads();
    int dreg[EPT], sreg[EPT];
    if (csize == CHUNK && ((((size_t)(const void*)(dst + c0)) & 15) == 0)
                       && ((((size_t)(const void*)(src + c0)) & 15) == 0)) {
        const int4* d4 = (const int4*)(dst + c0);
        const int4* s4 = (const int4*)(src + c0);
#pragma unroll
        for (int k = 0; k < EPT / 4; k++) {
            int4 d = d4[t + k * TPB];
            int4 s = s4[t + k * TPB];
            dreg[4 * k + 0] = d.x; sreg[4 * k + 0] = s.x;
            dreg[4 * k + 1] = d.y; sreg[4 * k + 1] = s.y;
            dreg[4 * k + 2] = d.z; sreg[4 * k + 2] = s.z;
            dreg[4 * k + 3] = d.w; sreg[4 * k + 3] = s.w;
            atomicAdd(&h[d.x >> NBS], 1);
            atomicAdd(&h[d.y >> NBS], 1);
            atomicAdd(&h[d.z >> NBS], 1);
            atomicAdd(&h[d.w >> NBS], 1);
        }
    } else {
#pragma unroll
        for (int k = 0; k < EPT; k++) {
            int idx = t + k * TPB;
            int d = (idx < csize) ? dst[c0 + idx] : -1;
            int s = (idx < csize) ? src[c0 + idx] : 0;
            dreg[k] = d;
            sreg[k] = s;
            if (d >= 0) atomicAdd(&h[d >> NBS], 1);
        }
    }
    __syncthreads();
    // per-thread local prefix over its BPT bins
    int loc[BPT], hreg[BPT];
    int ts = 0;
#pragma unroll
    for (int k = 0; k < BPT; k++) {
        hreg[k] = h[t * BPT + k];
        loc[k] = ts;
        ts += hreg[k];
    }
    // block-wide inclusive scan of ts: wave shfl scan + wave-sum combine
    int lane = t & 63, wid = t >> 6;
    int v = ts;
#pragma unroll
    for (int off = 1; off < 64; off <<= 1) {
        int u = __shfl_up(v, off);
        if (lane >= off) v += u;
    }
    if (lane == 63) wsum[wid] = v;
    __syncthreads();
    int pre = 0;
#pragma unroll
    for (int wq = 0; wq < NWAVE - 1; wq++)
        if (wid > wq) pre += wsum[wq];
    int tbase = pre + v - ts;  // exclusive prefix for this thread's first bin
    // deterministic delta: global slot = segbase[s][b] + O[c][b] + rank
    const int* Orow = O + (size_t)blockIdx.x * nb;
    const int* segrow = segbase + (size_t)(blockIdx.x / cps) * nb;
#pragma unroll
    for (int k = 0; k < BPT; k++) {
        int b = t * BPT + k;
        int ex = tbase + loc[k];
        h[b] = ex;  // stage cursor
        delta[b] = (b < nb) ? (segrow[b] + Orow[b] - ex) : 0;
    }
    __syncthreads();
    // LDS counting sort of the chunk (registers -> LDS only)
#pragma unroll
    for (int k = 0; k < EPT; k++) {
        int d = dreg[k];
        if (d >= 0) {
            int b = d >> NBS;
            int r = atomicAdd(&h[b], 1);
            stage[r] = ((d & (NBKT - 1)) << 18) | sreg[k];
            bs[r] = (unsigned short)b;
        }
    }
    __syncthreads();
    for (int k = t; k < csize; k += TPB)
        binned[delta[bs[k]] + k] = stage[k];
}

// layer-1 bucket push: acc[256][6] (LDS, padded stride 7) self-init from xdq,
// stream region edges, gather xdq[s], ds_add_f32 accumulate. Epilogue per
// node: a @W1 -> relu(di*.+b1) -> @W2 -> *di -> g2q (bf16x8 in uint4).
__global__ void __launch_bounds__(TPB) k_agg1(
        const int* __restrict__ binned, const int* __restrict__ btot,
        const uint4* __restrict__ xdq, const float* __restrict__ dinv,
        const float* __restrict__ b1, const float* __restrict__ W1,
        const float* __restrict__ W2, uint4* __restrict__ g2q, int n) {
    __shared__ float acc[NBKT][7];  // stride 7 (coprime 32): conflict-spread
    __shared__ float w1[96];   // 6 x 16
    __shared__ float w2[128];  // 16 x 8
    __shared__ float bb[16];
    int b = blockIdx.x, t = threadIdx.x;
    if (t < 96) w1[t] = W1[t];
    if (t < 128) w2[t] = W2[t];
    if (t < 16) bb[t] = b1[t];
    int i = (b << NBS) + t;
    if (i < n) {  // self-loop init (xdq already prescaled by own dinv)
        uint4 q = xdq[i];
        acc[t][0] = BFLO(q.x); acc[t][1] = BFHI(q.x);
        acc[t][2] = BFLO(q.y); acc[t][3] = BFHI(q.y);
        acc[t][4] = BFLO(q.z); acc[t][5] = BFHI(q.z);
    } else {
#pragma unroll
        for (int f = 0; f < 6; f++) acc[t][f] = 0.f;
    }
    int base = b * CAP;
    int c = btot[b];
    __syncthreads();
    int k = t;
    for (; k + TPB < c; k += 2 * TPB) {  // 2x unrolled independent gathers
        int w0 = binned[base + k];
        int w1v = binned[base + k + TPB];
        uint4 q0 = xdq[w0 & 0x3FFFF];
        uint4 q1 = xdq[w1v & 0x3FFFF];
        int d0 = w0 >> 18, d1 = w1v >> 18;
        atomicAdd(&acc[d0][0], BFLO(q0.x));
        atomicAdd(&acc[d0][1], BFHI(q0.x));
        atomicAdd(&acc[d0][2], BFLO(q0.y));
        atomicAdd(&acc[d0][3], BFHI(q0.y));
        atomicAdd(&acc[d0][4], BFLO(q0.z));
        atomicAdd(&acc[d0][5], BFHI(q0.z));
        atomicAdd(&acc[d1][0], BFLO(q1.x));
        atomicAdd(&acc[d1][1], BFHI(q1.x));
        atomicAdd(&acc[d1][2], BFLO(q1.y));
        atomicAdd(&acc[d1][3], BFHI(q1.y));
        atomicAdd(&acc[d1][4], BFLO(q1.z));
        atomicAdd(&acc[d1][5], BFHI(q1.z));
    }
    if (k < c) {
        int w0 = binned[base + k];
        uint4 q0 = xdq[w0 & 0x3FFFF];
        int d0 = w0 >> 18;
        atomicAdd(&acc[d0][0], BFLO(q0.x));
        atomicAdd(&acc[d0][1], BFHI(q0.x));
        atomicAdd(&acc[d0][2], BFLO(q0.y));
        atomicAdd(&acc[d0][3], BFHI(q0.y));
        atomicAdd(&acc[d0][4], BFLO(q0.z));
        atomicAdd(&acc[d0][5], BFHI(q0.z));
    }
    __syncthreads();
    if (i < n) {  // per-node MLP epilogue (weights broadcast from LDS)
        float di = dinv[i];
        float a0 = acc[t][0], a1 = acc[t][1], a2 = acc[t][2];
        float a3 = acc[t][3], a4 = acc[t][4], a5 = acc[t][5];
        float o0 = 0.f, o1 = 0.f, o2 = 0.f, o3 = 0.f;
        float o4 = 0.f, o5 = 0.f, o6 = 0.f, o7 = 0.f;
#pragma unroll
        for (int f = 0; f < 16; f++) {
            float hf = a0 * w1[f] + a1 * w1[16 + f] + a2 * w1[32 + f]
                     + a3 * w1[48 + f] + a4 * w1[64 + f] + a5 * w1[80 + f];
            float tf = fmaxf(di * hf + bb[f], 0.0f);
            o0 += tf * w2[f * 8 + 0]; o1 += tf * w2[f * 8 + 1];
            o2 += tf * w2[f * 8 + 2]; o3 += tf * w2[f * 8 + 3];
            o4 += tf * w2[f * 8 + 4]; o5 += tf * w2[f * 8 + 5];
            o6 += tf * w2[f * 8 + 6]; o7 += tf * w2[f * 8 + 7];
        }
        uint4 r;
        r.x = pk2(o0 * di, o1 * di);
        r.y = pk2(o2 * di, o3 * di);
        r.z = pk2(o4 * di, o5 * di);
        r.w = pk2(o6 * di, o7 * di);
        g2q[i] = r;
    }
}

// layer-2 bucket push: acc[256][8] (stride 9) self-init from g2q, stream
// region, gather g2q[s], accumulate. Fused head -> out = sigmoid(..).
__global__ void __launch_bounds__(TPB) k_agg2(
        const int* __restrict__ binned, const int* __restrict__ btot,
        const uint4* __restrict__ g2q, const float* __restrict__ dinv,
        const float* __restrict__ b2, const float* __restrict__ Wfc,
        const float* __restrict__ bfc, float* __restrict__ out, int n) {
    __shared__ float acc[NBKT][9];  // stride 9 (coprime 32): conflict-spread
    __shared__ float wf[8];
    __shared__ float bb[8];
    __shared__ float bf;
    int b = blockIdx.x, t = threadIdx.x;
    if (t < 8) { wf[t] = Wfc[t]; bb[t] = b2[t]; }
    if (t == 0) bf = bfc[0];
    int i = (b << NBS) + t;
    if (i < n) {  // self-loop init (g2q already prescaled by own dinv)
        uint4 q = g2q[i];
        acc[t][0] = BFLO(q.x); acc[t][1] = BFHI(q.x);
        acc[t][2] = BFLO(q.y); acc[t][3] = BFHI(q.y);
        acc[t][4] = BFLO(q.z); acc[t][5] = BFHI(q.z);
        acc[t][6] = BFLO(q.w); acc[t][7] = BFHI(q.w);
    } else {
#pragma unroll
        for (int f = 0; f < 8; f++) acc[t][f] = 0.f;
    }
    int base = b * CAP;
    int c = btot[b];
    __syncthreads();
    int k = t;
    for (; k + TPB < c; k += 2 * TPB) {
        int w0 = binned[base + k];
        int w1v = binned[base + k + TPB];
        uint4 q0 = g2q[w0 & 0x3FFFF];
        uint4 q1 = g2q[w1v & 0x3FFFF];
        int d0 = w0 >> 18, d1 = w1v >> 18;
        atomicAdd(&acc[d0][0], BFLO(q0.x));
        atomicAdd(&acc[d0][1], BFHI(q0.x));
        atomicAdd(&acc[d0][2], BFLO(q0.y));
        atomicAdd(&acc[d0][3], BFHI(q0.y));
        atomicAdd(&acc[d0][4], BFLO(q0.z));
        atomicAdd(&acc[d0][5], BFHI(q0.z));
        atomicAdd(&acc[d0][6], BFLO(q0.w));
        atomicAdd(&acc[d0][7], BFHI(q0.w));
        atomicAdd(&acc[d1][0], BFLO(q1.x));
        atomicAdd(&acc[d1][1], BFHI(q1.x));
        atomicAdd(&acc[d1][2], BFLO(q1.y));
        atomicAdd(&acc[d1][3], BFHI(q1.y));
        atomicAdd(&acc[d1][4], BFLO(q1.z));
        atomicAdd(&acc[d1][5], BFHI(q1.z));
        atomicAdd(&acc[d1][6], BFLO(q1.w));
        atomicAdd(&acc[d1][7], BFHI(q1.w));
    }
    if (k < c) {
        int w0 = binned[base + k];
        uint4 q0 = g2q[w0 & 0x3FFFF];
        int d0 = w0 >> 18;
        atomicAdd(&acc[d0][0], BFLO(q0.x));
        atomicAdd(&acc[d0][1], BFHI(q0.x));
        atomicAdd(&acc[d0][2], BFLO(q0.y));
        atomicAdd(&acc[d0][3], BFHI(q0.y));
        atomicAdd(&acc[d0][4], BFLO(q0.z));
        atomicAdd(&acc[d0][5], BFHI(q0.z));
        atomicAdd(&acc[d0][6], BFLO(q0.w));
        atomicAdd(&acc[d0][7], BFHI(q0.w));
    }
    __syncthreads();
    if (i < n) {
        float di = dinv[i];
        float o = bf;
        o += fmaxf(di * acc[t][0] + bb[0], 0.0f) * wf[0];
        o += fmaxf(di * acc[t][1] + bb[1], 0.0f) * wf[1];
        o += fmaxf(di * acc[t][2] + bb[2], 0.0f) * wf[2];
        o += fmaxf(di * acc[t][3] + bb[3], 0.0f) * wf[3];
        o += fmaxf(di * acc[t][4] + bb[4], 0.0f) * wf[4];
        o += fmaxf(di * acc[t][5] + bb[5], 0.0f) * wf[5];
        o += fmaxf(di * acc[t][6] + bb[6], 0.0f) * wf[6];
        o += fmaxf(di * acc[t][7] + bb[7], 0.0f) * wf[7];
        out[i] = 1.0f / (1.0f + expf(-o));
    }
}

extern "C" void kernel_launch(void* const* d_in, const int* in_sizes, int n_in,
                              void* d_out, int out_size, void* d_ws, size_t ws_size,
                              hipStream_t stream) {
    const float* x   = (const float*)d_in[0];
    const int*   ei  = (const int*)d_in[1];
    const float* W1  = (const float*)d_in[2];
    const float* b1  = (const float*)d_in[3];
    const float* W2  = (const float*)d_in[4];
    const float* b2  = (const float*)d_in[5];
    const float* Wfc = (const float*)d_in[6];
    const float* bfc = (const float*)d_in[7];
    float* out = (float*)d_out;

    const int n = in_sizes[0] / 6;   // 200000 (<= 262144 for 18-bit packing)
    const int e = in_sizes[1] / 2;   // 6400000
    const int* src = ei;
    const int* dst = ei + e;
    const int nb = (n + NBKT - 1) >> NBS;  // 782
    const size_t np = (size_t)nb << NBS;   // padded node count (200192)
    const int nblk = (e + CHUNK - 1) / CHUNK;  // 1563 chunks
    const int cps = (nblk + NSEG - 1) / NSEG;  // chunks per segment (49)
    const int ngrp = (nb + TPB - 1) / TPB;     // bucket groups (4)
    const size_t reg = (size_t)nb * CAP;   // bucket-region total (7.2M words)

    int* C       = (int*)d_ws;                 // nblk * nb
    int* O       = C + (size_t)nblk * nb;      // nblk * nb
    int* Sseg    = O + (size_t)nblk * nb;      // NSEG * MAXB
    int* segbase = Sseg + (size_t)NSEG * MAXB; // NSEG * MAXB
    int* btot    = segbase + (size_t)NSEG * MAXB; // MAXB
    int* deg     = btot + MAXB;                // np
    int* binned  = deg + np;                   // reg
    float* dinv  = (float*)(binned + reg);     // np
    size_t off   = (size_t)((int*)(dinv + np) - (int*)d_ws);
    off = (off + 3) & ~(size_t)3;              // 16B-align the uint4 arrays
    uint4* xdq   = (uint4*)((int*)d_ws + off); // np * 16 B
    uint4* g2q   = xdq + np;                   // np * 16 B

    hipMemsetAsync(deg, 0, np * sizeof(int), stream);
    k_fb1<<<nblk, TPB, 0, stream>>>(dst, C, deg, e, nb);
    k_scan1<<<NSEG * ngrp, TPB, 0, stream>>>(C, O, Sseg, nblk, nb, cps, ngrp);
    k_scan2<<<ngrp, TPB, 0, stream>>>(Sseg, segbase, btot, nb);
    k_prep<<<(n + TPB - 1) / TPB, TPB, 0, stream>>>(deg, x, dinv, xdq, n);
    k_fillbin<<<nblk, TPB, 0, stream>>>(src, dst, O, segbase, binned, e, nb, cps);
    k_agg1<<<nb, TPB, 0, stream>>>(binned, btot, xdq, dinv, b1, W1, W2, g2q, n);
    k_agg2<<<nb, TPB, 0, stream>>>(binned, btot, (const uint4*)g2q, dinv, b2, Wfc, bfc, out, n);
}

// Round 6
// 491.228 us; speedup vs baseline: 2.0005x; 2.0005x over previous
//
#include <hip/hip_runtime.h>
#include <math.h>

// GCN 2-layer + sigmoid head. CSR pull-gather, zero fp32 atomics.
// R21: fuse layer-1 gather+MLP into k_sort (delete k_gat1). k_sort already
//  has the node-sorted edge list in LDS (stage[]); thread t owns node t and
//  serially gathers its row (4-deep pipelined 16B L2 gathers, register acc),
//  then runs the MLP epilogue -> g2q. Sort work + csr flush hide under the
//  gather latency (R19: k_sort 30us vmem-idle + k_gat1 50us at gather floor
//  -> fused ~max not sum). dinv/xdq move to k_prep (deg atomics in k_fb1),
//  both R20-proven, since gathers read xdq cross-block.
//   k_fb1:   per-chunk bucket histogram -> C[chunk][nb]; + global deg[dst]++
//   k_scan1/2: 2-level deterministic offset scan (coalesced, no barriers)
//   k_prep:  dinv = rsqrt(deg+1); xdq = bf16(x*dinv) (prescaled payload)
//   k_fillbin: LDS chunk counting-sort -> binned (deterministic, no atomics)
//   k_sort:  bucket counting sort -> csr flush + fused L1 gather/MLP -> g2q
//   k_gat2:  node-group gather (16 lanes/node) + fused head -> out

#define TPB 256
#define NBS 8
#define NBKT 256        // nodes per bucket
#define MAXB 1024       // max buckets (n <= 262144)
#define BPT (MAXB / TPB)
#define CHUNK 4096      // edges per fillbin block
#define EPT (CHUNK / TPB)
#define CAP 9216        // bucket region capacity (mean 8192 + ~11 sigma)
#define RPT (CAP / TPB) // 36 register-cached words per k_sort thread
#define NWAVE (TPB / 64)
#define NSEG 32         // chunk segments for the 2-level offset scan

__device__ __forceinline__ unsigned short f2bf(float f) {
    unsigned u = __float_as_uint(f);
    unsigned r = (u + 0x7FFFu + ((u >> 16) & 1u)) >> 16;  // RNE
    return (unsigned short)r;
}
__device__ __forceinline__ unsigned pk2(float a, float b) {
    return (unsigned)f2bf(a) | ((unsigned)f2bf(b) << 16);
}
#define BFLO(u) __uint_as_float((u) << 16)
#define BFHI(u) __uint_as_float((u) & 0xFFFF0000u)

// per-chunk bucket histogram -> C[chunk][nb]; fused node-degree histogram
// (global non-returning atomics, hidden under the streaming read).
__global__ void __launch_bounds__(TPB) k_fb1(
        const int* __restrict__ dst, int* __restrict__ C,
        int* __restrict__ deg, int e, int nb) {
    __shared__ int h[MAXB];
    int t = threadIdx.x;
    int c0 = blockIdx.x * CHUNK;
    int csize = min(e - c0, CHUNK);
#pragma unroll
    for (int k = 0; k < BPT; k++) h[t * BPT + k] = 0;
    __syncthreads();
    if (csize == CHUNK && ((((size_t)(const void*)(dst + c0)) & 15) == 0)) {
        const int4* d4 = (const int4*)(dst + c0);
#pragma unroll
        for (int k = 0; k < EPT / 4; k++) {
            int4 d = d4[t + k * TPB];
            atomicAdd(&h[d.x >> NBS], 1);
            atomicAdd(&h[d.y >> NBS], 1);
            atomicAdd(&h[d.z >> NBS], 1);
            atomicAdd(&h[d.w >> NBS], 1);
            atomicAdd(&deg[d.x], 1);
            atomicAdd(&deg[d.y], 1);
            atomicAdd(&deg[d.z], 1);
            atomicAdd(&deg[d.w], 1);
        }
    } else {
        for (int i = t; i < csize; i += TPB) {
            int d = dst[c0 + i];
            atomicAdd(&h[d >> NBS], 1);
            atomicAdd(&deg[d], 1);
        }
    }
    __syncthreads();
    int* row = C + (size_t)blockIdx.x * nb;
    for (int b = t; b < nb; b += TPB) row[b] = h[b];
}

// level-1: thread t serially scans bucket-column b over chunk segment s.
__global__ void __launch_bounds__(TPB) k_scan1(
        const int* __restrict__ C, int* __restrict__ O, int* __restrict__ Sseg,
        int nchunk, int nb, int cps, int ngrp) {
    int bid = blockIdx.x;
    int s = bid / ngrp, g = bid - s * ngrp;
    int b = g * TPB + threadIdx.x;
    if (b >= nb) return;
    int cbeg = s * cps;
    int cend = min(cbeg + cps, nchunk);
    int run = 0;
#pragma unroll 4
    for (int c = cbeg; c < cend; c++) {
        int v = C[(size_t)c * nb + b];
        O[(size_t)c * nb + b] = run;
        run += v;
    }
    Sseg[s * nb + b] = run;
}

// level-2: per bucket, exclusive scan of NSEG segment sums; fold in b*CAP.
__global__ void __launch_bounds__(TPB) k_scan2(
        const int* __restrict__ Sseg, int* __restrict__ segbase,
        int* __restrict__ btot, int nb) {
    int b = blockIdx.x * TPB + threadIdx.x;
    if (b >= nb) return;
    int run = b * CAP;
#pragma unroll
    for (int s = 0; s < NSEG; s++) {
        segbase[s * nb + b] = run;
        run += Sseg[s * nb + b];
    }
    btot[b] = run - b * CAP;
}

// per-node: dinv = rsqrt(deg+1); xdq = bf16-packed x*dinv (prescaled payload)
__global__ void __launch_bounds__(TPB) k_prep(
        const int* __restrict__ deg, const float* __restrict__ x,
        float* __restrict__ dinv, uint4* __restrict__ xdq, int n) {
    int i = blockIdx.x * TPB + threadIdx.x;
    if (i >= n) return;
    float di = rsqrtf((float)(deg[i] + 1));
    dinv[i] = di;
    uint4 q;
    q.x = pk2(x[i * 6 + 0] * di, x[i * 6 + 1] * di);
    q.y = pk2(x[i * 6 + 2] * di, x[i * 6 + 3] * di);
    q.z = pk2(x[i * 6 + 4] * di, x[i * 6 + 5] * di);
    q.w = 0;
    xdq[i] = q;
}

// bin edges into fixed-cap bucket regions. LDS counting sort of the chunk;
// deterministic delta from segbase+O (no atomics). word: ((d&255)<<18)|s
__global__ void __launch_bounds__(TPB) k_fillbin(
        const int* __restrict__ src, const int* __restrict__ dst,
        const int* __restrict__ O, const int* __restrict__ segbase,
        int* __restrict__ binned, int e, int nb, int cps) {
    __shared__ int stage[CHUNK];            // 16 KB, bucket-sorted packed words
    __shared__ unsigned short bs[CHUNK];    // 8 KB, bucket id per sorted slot
    __shared__ int h[MAXB];                 // 4 KB, hist -> stage cursor
    __shared__ int delta[MAXB];             // 4 KB
    __shared__ int wsum[NWAVE];
    int t = threadIdx.x;
    int c0 = blockIdx.x * CHUNK;
    int csize = min(e - c0, CHUNK);
#pragma unroll
    for (int k = 0; k < BPT; k++) h[t * BPT + k] = 0;
    __syncthreads();
    int dreg[EPT], sreg[EPT];
    if (csize == CHUNK && ((((size_t)(const void*)(dst + c0)) & 15) == 0)
                       && ((((size_t)(const void*)(src + c0)) & 15) == 0)) {
        const int4* d4 = (const int4*)(dst + c0);
        const int4* s4 = (const int4*)(src + c0);
#pragma unroll
        for (int k = 0; k < EPT / 4; k++) {
            int4 d = d4[t + k * TPB];
            int4 s = s4[t + k * TPB];
            dreg[4 * k + 0] = d.x; sreg[4 * k + 0] = s.x;
            dreg[4 * k + 1] = d.y; sreg[4 * k + 1] = s.y;
            dreg[4 * k + 2] = d.z; sreg[4 * k + 2] = s.z;
            dreg[4 * k + 3] = d.w; sreg[4 * k + 3] = s.w;
            atomicAdd(&h[d.x >> NBS], 1);
            atomicAdd(&h[d.y >> NBS], 1);
            atomicAdd(&h[d.z >> NBS], 1);
            atomicAdd(&h[d.w >> NBS], 1);
        }
    } else {
#pragma unroll
        for (int k = 0; k < EPT; k++) {
            int idx = t + k * TPB;
            int d = (idx < csize) ? dst[c0 + idx] : -1;
            int s = (idx < csize) ? src[c0 + idx] : 0;
            dreg[k] = d;
            sreg[k] = s;
            if (d >= 0) atomicAdd(&h[d >> NBS], 1);
        }
    }
    __syncthreads();
    // per-thread local prefix over its BPT bins
    int loc[BPT], hreg[BPT];
    int ts = 0;
#pragma unroll
    for (int k = 0; k < BPT; k++) {
        hreg[k] = h[t * BPT + k];
        loc[k] = ts;
        ts += hreg[k];
    }
    // block-wide inclusive scan of ts: wave shfl scan + wave-sum combine
    int lane = t & 63, wid = t >> 6;
    int v = ts;
#pragma unroll
    for (int off = 1; off < 64; off <<= 1) {
        int u = __shfl_up(v, off);
        if (lane >= off) v += u;
    }
    if (lane == 63) wsum[wid] = v;
    __syncthreads();
    int pre = 0;
#pragma unroll
    for (int wq = 0; wq < NWAVE - 1; wq++)
        if (wid > wq) pre += wsum[wq];
    int tbase = pre + v - ts;  // exclusive prefix for this thread's first bin
    // deterministic delta: global slot = segbase[s][b] + O[c][b] + rank
    const int* Orow = O + (size_t)blockIdx.x * nb;
    const int* segrow = segbase + (size_t)(blockIdx.x / cps) * nb;
#pragma unroll
    for (int k = 0; k < BPT; k++) {
        int b = t * BPT + k;
        int ex = tbase + loc[k];
        h[b] = ex;  // stage cursor
        delta[b] = (b < nb) ? (segrow[b] + Orow[b] - ex) : 0;
    }
    __syncthreads();
    // LDS counting sort of the chunk (registers -> LDS only)
#pragma unroll
    for (int k = 0; k < EPT; k++) {
        int d = dreg[k];
        if (d >= 0) {
            int b = d >> NBS;
            int r = atomicAdd(&h[b], 1);
            stage[r] = ((d & (NBKT - 1)) << 18) | sreg[k];
            bs[r] = (unsigned short)b;
        }
    }
    __syncthreads();
    for (int k = t; k < csize; k += TPB)
        binned[delta[bs[k]] + k] = stage[k];
}

// full-bucket counting sort + FUSED layer-1 gather/MLP.
// 1) reg-cache region + node histogram  2) scan -> rowptr/rowend
// 3) scatter to LDS stage (node-sorted) 4) csr flush (streaming stores)
// 5) thread t = node t: pipelined gathers of xdq[stage[ex..ex+v)], register
//    acc, MLP epilogue (@W1 relu @W2 *di) -> g2q (bf16x8).
__global__ void __launch_bounds__(TPB) k_sort(
        const int* __restrict__ binned, const int* __restrict__ btot,
        const uint4* __restrict__ xdq, const float* __restrict__ dinv,
        const float* __restrict__ b1, const float* __restrict__ W1,
        const float* __restrict__ W2, int* __restrict__ csr,
        int* __restrict__ rowptr, int* __restrict__ rowend,
        uint4* __restrict__ g2q, int n) {
    __shared__ int stage[CAP];     // 36 KB
    __shared__ int cnt[NBKT];
    __shared__ int curs[NBKT];
    __shared__ int wsum[NWAVE];
    __shared__ float w1[96];   // 6 x 16
    __shared__ float w2[128];  // 16 x 8
    __shared__ float bb[16];
    int b = blockIdx.x, t = threadIdx.x;
    if (t < 96) w1[t] = W1[t];
    if (t < 128) w2[t] = W2[t];
    if (t < 16) bb[t] = b1[t];
    int base = b * CAP;
    int c = btot[b];
    cnt[t] = 0;
    __syncthreads();
    // 1) read region once into registers + histogram
    int w[RPT];
#pragma unroll
    for (int k = 0; k < RPT; k++) {
        int idx = t + k * TPB;               // coalesced
        w[k] = (idx < c) ? binned[base + idx] : -1;
        if (w[k] >= 0) atomicAdd(&cnt[w[k] >> 18], 1);
    }
    __syncthreads();
    // 2) exclusive scan of 256 bins: wave shfl scan + combine (1 barrier)
    int v = cnt[t];
    int lane = t & 63, wid = t >> 6;
    int iv = v;
#pragma unroll
    for (int off = 1; off < 64; off <<= 1) {
        int u = __shfl_up(iv, off);
        if (lane >= off) iv += u;
    }
    if (lane == 63) wsum[wid] = iv;
    __syncthreads();
    int pre = 0;
#pragma unroll
    for (int wq = 0; wq < NWAVE - 1; wq++)
        if (wid > wq) pre += wsum[wq];
    int ex = pre + iv - v;  // exclusive
    curs[t] = ex;
    int i = (b << NBS) + t;
    rowptr[i] = base + ex;
    rowend[i] = base + ex + v;
    __syncthreads();
    // 3) scatter from registers into LDS stage (node-sorted order)
#pragma unroll
    for (int k = 0; k < RPT; k++) {
        if (w[k] >= 0) {
            int r = atomicAdd(&curs[w[k] >> 18], 1);
            stage[r] = w[k] & 0x3FFFF;
        }
    }
    __syncthreads();
    // 4) dense csr flush (fire-and-forget streaming stores)
    for (int k = t; k < c; k += TPB)
        csr[base + k] = stage[k];
    // 5) fused layer-1 gather + MLP (thread t = node t; row in stage[ex..ex+v))
    float a0 = 0.f, a1 = 0.f, a2 = 0.f, a3 = 0.f, a4 = 0.f, a5 = 0.f;
    if (i < n) {  // self-loop (xdq prescaled by own dinv)
        uint4 q = xdq[i];
        a0 = BFLO(q.x); a1 = BFHI(q.x);
        a2 = BFLO(q.y); a3 = BFHI(q.y);
        a4 = BFLO(q.z); a5 = BFHI(q.z);
    }
    int kk = ex, kend = ex + v;
    for (; kk + 4 <= kend; kk += 4) {  // 4 independent gathers in flight
        int s0 = stage[kk], s1 = stage[kk + 1];
        int s2 = stage[kk + 2], s3 = stage[kk + 3];
        uint4 q0 = xdq[s0], q1 = xdq[s1], q2 = xdq[s2], q3 = xdq[s3];
        a0 += BFLO(q0.x) + BFLO(q1.x) + BFLO(q2.x) + BFLO(q3.x);
        a1 += BFHI(q0.x) + BFHI(q1.x) + BFHI(q2.x) + BFHI(q3.x);
        a2 += BFLO(q0.y) + BFLO(q1.y) + BFLO(q2.y) + BFLO(q3.y);
        a3 += BFHI(q0.y) + BFHI(q1.y) + BFHI(q2.y) + BFHI(q3.y);
        a4 += BFLO(q0.z) + BFLO(q1.z) + BFLO(q2.z) + BFLO(q3.z);
        a5 += BFHI(q0.z) + BFHI(q1.z) + BFHI(q2.z) + BFHI(q3.z);
    }
    for (; kk < kend; kk++) {
        uint4 q = xdq[stage[kk]];
        a0 += BFLO(q.x); a1 += BFHI(q.x);
        a2 += BFLO(q.y); a3 += BFHI(q.y);
        a4 += BFLO(q.z); a5 += BFHI(q.z);
    }
    if (i < n) {  // MLP epilogue (weights broadcast from LDS)
        float di = dinv[i];
        float o0 = 0.f, o1 = 0.f, o2 = 0.f, o3 = 0.f;
        float o4 = 0.f, o5 = 0.f, o6 = 0.f, o7 = 0.f;
#pragma unroll
        for (int f = 0; f < 16; f++) {
            float hf = a0 * w1[f] + a1 * w1[16 + f] + a2 * w1[32 + f]
                     + a3 * w1[48 + f] + a4 * w1[64 + f] + a5 * w1[80 + f];
            float tf = fmaxf(di * hf + bb[f], 0.0f);
            o0 += tf * w2[f * 8 + 0]; o1 += tf * w2[f * 8 + 1];
            o2 += tf * w2[f * 8 + 2]; o3 += tf * w2[f * 8 + 3];
            o4 += tf * w2[f * 8 + 4]; o5 += tf * w2[f * 8 + 5];
            o6 += tf * w2[f * 8 + 6]; o7 += tf * w2[f * 8 + 7];
        }
        uint4 r;
        r.x = pk2(o0 * di, o1 * di);
        r.y = pk2(o2 * di, o3 * di);
        r.z = pk2(o4 * di, o5 * di);
        r.w = pk2(o6 * di, o7 * di);
        g2q[i] = r;
    }
}

// layer-2 gather (bf16 payload): 16 lanes/node, 4 nodes/wave.
// fused head: h = relu(dinv*agg8 + b2); out = sigmoid(h @ Wfc + bfc)
__global__ void __launch_bounds__(TPB) k_gat2(
        const uint4* __restrict__ g2q, const int* __restrict__ csr,
        const int* __restrict__ rowptr, const int* __restrict__ rowend,
        const float* __restrict__ dinv,
        const float* __restrict__ b2, const float* __restrict__ Wfc,
        const float* __restrict__ bfc, float* __restrict__ out, int n) {
    __shared__ float w[8];
    __shared__ float bb[8];
    __shared__ float bf;
    if (threadIdx.x < 8) { w[threadIdx.x] = Wfc[threadIdx.x]; bb[threadIdx.x] = b2[threadIdx.x]; }
    if (threadIdx.x == 0) bf = bfc[0];
    __syncthreads();
    int sub = threadIdx.x & 15;
    int i = blockIdx.x * 16 + (threadIdx.x >> 4);
    bool valid = (i < n);
    int r0 = rowptr[i], r1 = rowend[i];
    float a0 = 0.f, a1 = 0.f, a2 = 0.f, a3 = 0.f;
    float a4 = 0.f, a5 = 0.f, a6 = 0.f, a7 = 0.f;
    if (valid && sub == 0) {  // self-loop term
        uint4 q = g2q[i];
        a0 += BFLO(q.x); a1 += BFHI(q.x); a2 += BFLO(q.y); a3 += BFHI(q.y);
        a4 += BFLO(q.z); a5 += BFHI(q.z); a6 += BFLO(q.w); a7 += BFHI(q.w);
    }
    float c0 = 0.f, c1 = 0.f, c2 = 0.f, c3 = 0.f;
    float c4 = 0.f, c5 = 0.f, c6 = 0.f, c7 = 0.f;
    int j = r0 + sub;
    while (j + 16 < r1) {
        uint4 q = g2q[csr[j]];
        uint4 p = g2q[csr[j + 16]];
        a0 += BFLO(q.x); a1 += BFHI(q.x); a2 += BFLO(q.y); a3 += BFHI(q.y);
        a4 += BFLO(q.z); a5 += BFHI(q.z); a6 += BFLO(q.w); a7 += BFHI(q.w);
        c0 += BFLO(p.x); c1 += BFHI(p.x); c2 += BFLO(p.y); c3 += BFHI(p.y);
        c4 += BFLO(p.z); c5 += BFHI(p.z); c6 += BFLO(p.w); c7 += BFHI(p.w);
        j += 32;
    }
    if (j < r1) {
        uint4 q = g2q[csr[j]];
        a0 += BFLO(q.x); a1 += BFHI(q.x); a2 += BFLO(q.y); a3 += BFHI(q.y);
        a4 += BFLO(q.z); a5 += BFHI(q.z); a6 += BFLO(q.w); a7 += BFHI(q.w);
    }
    a0 += c0; a1 += c1; a2 += c2; a3 += c3;
    a4 += c4; a5 += c5; a6 += c6; a7 += c7;
#pragma unroll
    for (int m = 1; m <= 8; m <<= 1) {  // reduce within 16-lane node group
        a0 += __shfl_xor(a0, m); a1 += __shfl_xor(a1, m);
        a2 += __shfl_xor(a2, m); a3 += __shfl_xor(a3, m);
        a4 += __shfl_xor(a4, m); a5 += __shfl_xor(a5, m);
        a6 += __shfl_xor(a6, m); a7 += __shfl_xor(a7, m);
    }
    if (valid && sub == 0) {  // head computed once per node (cheap, no shfl)
        float di = dinv[i];
        float o = bf;
        o += fmaxf(di * a0 + bb[0], 0.0f) * w[0];
        o += fmaxf(di * a1 + bb[1], 0.0f) * w[1];
        o += fmaxf(di * a2 + bb[2], 0.0f) * w[2];
        o += fmaxf(di * a3 + bb[3], 0.0f) * w[3];
        o += fmaxf(di * a4 + bb[4], 0.0f) * w[4];
        o += fmaxf(di * a5 + bb[5], 0.0f) * w[5];
        o += fmaxf(di * a6 + bb[6], 0.0f) * w[6];
        o += fmaxf(di * a7 + bb[7], 0.0f) * w[7];
        out[i] = 1.0f / (1.0f + expf(-o));
    }
}

extern "C" void kernel_launch(void* const* d_in, const int* in_sizes, int n_in,
                              void* d_out, int out_size, void* d_ws, size_t ws_size,
                              hipStream_t stream) {
    const float* x   = (const float*)d_in[0];
    const int*   ei  = (const int*)d_in[1];
    const float* W1  = (const float*)d_in[2];
    const float* b1  = (const float*)d_in[3];
    const float* W2  = (const float*)d_in[4];
    const float* b2  = (const float*)d_in[5];
    const float* Wfc = (const float*)d_in[6];
    const float* bfc = (const float*)d_in[7];
    float* out = (float*)d_out;

    const int n = in_sizes[0] / 6;   // 200000 (<= 262144 for 18-bit packing)
    const int e = in_sizes[1] / 2;   // 6400000
    const int* src = ei;
    const int* dst = ei + e;
    const int nb = (n + NBKT - 1) >> NBS;  // 782
    const size_t np = (size_t)nb << NBS;   // padded node count (200192)
    const int nblk = (e + CHUNK - 1) / CHUNK;  // 1563 chunks
    const int cps = (nblk + NSEG - 1) / NSEG;  // chunks per segment (49)
    const int ngrp = (nb + TPB - 1) / TPB;     // bucket groups (4)
    const size_t reg = (size_t)nb * CAP;   // bucket-region total (7.2M words)

    int* C       = (int*)d_ws;                 // nblk * nb
    int* O       = C + (size_t)nblk * nb;      // nblk * nb
    int* Sseg    = O + (size_t)nblk * nb;      // NSEG * MAXB
    int* segbase = Sseg + (size_t)NSEG * MAXB; // NSEG * MAXB
    int* btot    = segbase + (size_t)NSEG * MAXB; // MAXB
    int* deg     = btot + MAXB;                // np
    int* binned  = deg + np;                   // reg
    int* csr     = binned + reg;               // reg
    int* rowptr  = csr + reg;                  // np
    int* rowend  = rowptr + np;                // np
    float* dinv  = (float*)(rowend + np);      // np
    size_t off   = (size_t)((int*)(dinv + np) - (int*)d_ws);
    off = (off + 3) & ~(size_t)3;              // 16B-align the uint4 arrays
    uint4* xdq   = (uint4*)((int*)d_ws + off); // np * 16 B
    uint4* g2q   = xdq + np;                   // np * 16 B

    int gw = (n + 15) / 16;              // node-group blocks (16 nodes/block)

    hipMemsetAsync(deg, 0, np * sizeof(int), stream);
    k_fb1<<<nblk, TPB, 0, stream>>>(dst, C, deg, e, nb);
    k_scan1<<<NSEG * ngrp, TPB, 0, stream>>>(C, O, Sseg, nblk, nb, cps, ngrp);
    k_scan2<<<ngrp, TPB, 0, stream>>>(Sseg, segbase, btot, nb);
    k_prep<<<(n + TPB - 1) / TPB, TPB, 0, stream>>>(deg, x, dinv, xdq, n);
    k_fillbin<<<nblk, TPB, 0, stream>>>(src, dst, O, segbase, binned, e, nb, cps);
    k_sort<<<nb, TPB, 0, stream>>>(binned, btot, xdq, dinv, b1, W1, W2,
                                   csr, rowptr, rowend, g2q, n);
    k_gat2<<<gw, TPB, 0, stream>>>(g2q, csr, rowptr, rowend, dinv, b2, Wfc, bfc, out, n);
}

// Round 7
// 280.486 us; speedup vs baseline: 3.5035x; 1.7513x over previous
//
#include <hip/hip_runtime.h>
#include <math.h>

// GCN 2-layer + sigmoid head. CSR pull-gather, zero fp32 atomics.
// R22: R19 structure (proven 244.6us) + non-temporal hints on stream-once
//  arrays so the hot gather tables (xdq/g2q, 3.2MB, L2-resident per XCD)
//  are not evicted by streaming traffic:
//   - k_fb1/k_fillbin: src/dst reads nt; binned stores nt
//   - k_sort: binned reads nt; csr stores nt
//   - k_gat1/k_gat2: csr reads nt
//  R21 lessons: never compute deg via global atomics (204MB coherence
//  traffic, 252us); 16-lane cooperative gather beats 1-thread-per-node.
//   k_fb1:   per-chunk bucket histogram -> C[chunk][nb]
//   k_scan1/2: 2-level deterministic offset scan (coalesced, no barriers)
//   k_fillbin: LDS chunk counting-sort -> binned (deterministic, no atomics)
//   k_sort:  bucket counting sort -> dense csr, rowptr/rowend, dinv, xdq
//   k_gat1/2: node-group gathers (16 lanes/node, bf16 payloads L2-resident)

#define TPB 256
#define NBS 8
#define NBKT 256        // nodes per bucket
#define MAXB 1024       // max buckets (n <= 262144)
#define BPT (MAXB / TPB)
#define CHUNK 4096      // edges per fillbin block
#define EPT (CHUNK / TPB)
#define CAP 9216        // bucket region capacity (mean 8192 + ~11 sigma)
#define RPT (CAP / TPB) // 36 register-cached words per k_sort thread
#define NWAVE (TPB / 64)
#define NSEG 32         // chunk segments for the 2-level offset scan

typedef int i32x4 __attribute__((ext_vector_type(4)));

__device__ __forceinline__ int4 ntload4(const int* p) {
    i32x4 v = __builtin_nontemporal_load((const i32x4*)p);
    int4 r; r.x = v.x; r.y = v.y; r.z = v.z; r.w = v.w;
    return r;
}
__device__ __forceinline__ int ntload(const int* p) {
    return __builtin_nontemporal_load(p);
}
__device__ __forceinline__ void ntstore(int* p, int v) {
    __builtin_nontemporal_store(v, p);
}

__device__ __forceinline__ unsigned short f2bf(float f) {
    unsigned u = __float_as_uint(f);
    unsigned r = (u + 0x7FFFu + ((u >> 16) & 1u)) >> 16;  // RNE
    return (unsigned short)r;
}
__device__ __forceinline__ unsigned pk2(float a, float b) {
    return (unsigned)f2bf(a) | ((unsigned)f2bf(b) << 16);
}
#define BFLO(u) __uint_as_float((u) << 16)
#define BFHI(u) __uint_as_float((u) & 0xFFFF0000u)

// per-chunk bucket histogram -> C[chunk][nb] (coalesced row store)
__global__ void __launch_bounds__(TPB) k_fb1(
        const int* __restrict__ dst, int* __restrict__ C, int e, int nb) {
    __shared__ int h[MAXB];
    int t = threadIdx.x;
    int c0 = blockIdx.x * CHUNK;
    int csize = min(e - c0, CHUNK);
#pragma unroll
    for (int k = 0; k < BPT; k++) h[t * BPT + k] = 0;
    __syncthreads();
    if (csize == CHUNK && ((((size_t)(const void*)(dst + c0)) & 15) == 0)) {
        const int* dp = dst + c0;
#pragma unroll
        for (int k = 0; k < EPT / 4; k++) {
            int4 d = ntload4(dp + 4 * (t + k * TPB));
            atomicAdd(&h[d.x >> NBS], 1);
            atomicAdd(&h[d.y >> NBS], 1);
            atomicAdd(&h[d.z >> NBS], 1);
            atomicAdd(&h[d.w >> NBS], 1);
        }
    } else {
        for (int i = t; i < csize; i += TPB)
            atomicAdd(&h[dst[c0 + i] >> NBS], 1);
    }
    __syncthreads();
    int* row = C + (size_t)blockIdx.x * nb;
    for (int b = t; b < nb; b += TPB) row[b] = h[b];
}

// level-1: thread t serially scans bucket-column b over chunk segment s.
__global__ void __launch_bounds__(TPB) k_scan1(
        const int* __restrict__ C, int* __restrict__ O, int* __restrict__ Sseg,
        int nchunk, int nb, int cps, int ngrp) {
    int bid = blockIdx.x;
    int s = bid / ngrp, g = bid - s * ngrp;
    int b = g * TPB + threadIdx.x;
    if (b >= nb) return;
    int cbeg = s * cps;
    int cend = min(cbeg + cps, nchunk);
    int run = 0;
#pragma unroll 4
    for (int c = cbeg; c < cend; c++) {
        int v = C[(size_t)c * nb + b];
        O[(size_t)c * nb + b] = run;
        run += v;
    }
    Sseg[s * nb + b] = run;
}

// level-2: per bucket, exclusive scan of NSEG segment sums; fold in b*CAP.
__global__ void __launch_bounds__(TPB) k_scan2(
        const int* __restrict__ Sseg, int* __restrict__ segbase,
        int* __restrict__ btot, int nb) {
    int b = blockIdx.x * TPB + threadIdx.x;
    if (b >= nb) return;
    int run = b * CAP;
#pragma unroll
    for (int s = 0; s < NSEG; s++) {
        segbase[s * nb + b] = run;
        run += Sseg[s * nb + b];
    }
    btot[b] = run - b * CAP;
}

// bin edges into fixed-cap bucket regions. LDS counting sort of the chunk;
// deterministic delta from segbase+O (no atomics). word: ((d&255)<<18)|s
__global__ void __launch_bounds__(TPB) k_fillbin(
        const int* __restrict__ src, const int* __restrict__ dst,
        const int* __restrict__ O, const int* __restrict__ segbase,
        int* __restrict__ binned, int e, int nb, int cps) {
    __shared__ int stage[CHUNK];            // 16 KB, bucket-sorted packed words
    __shared__ unsigned short bs[CHUNK];    // 8 KB, bucket id per sorted slot
    __shared__ int h[MAXB];                 // 4 KB, hist -> stage cursor
    __shared__ int delta[MAXB];             // 4 KB
    __shared__ int wsum[NWAVE];
    int t = threadIdx.x;
    int c0 = blockIdx.x * CHUNK;
    int csize = min(e - c0, CHUNK);
#pragma unroll
    for (int k = 0; k < BPT; k++) h[t * BPT + k] = 0;
    __syncthreads();
    int dreg[EPT], sreg[EPT];
    if (csize == CHUNK && ((((size_t)(const void*)(dst + c0)) & 15) == 0)
                       && ((((size_t)(const void*)(src + c0)) & 15) == 0)) {
        const int* dp = dst + c0;
        const int* sp = src + c0;
#pragma unroll
        for (int k = 0; k < EPT / 4; k++) {
            int4 d = ntload4(dp + 4 * (t + k * TPB));
            int4 s = ntload4(sp + 4 * (t + k * TPB));
            dreg[4 * k + 0] = d.x; sreg[4 * k + 0] = s.x;
            dreg[4 * k + 1] = d.y; sreg[4 * k + 1] = s.y;
            dreg[4 * k + 2] = d.z; sreg[4 * k + 2] = s.z;
            dreg[4 * k + 3] = d.w; sreg[4 * k + 3] = s.w;
            atomicAdd(&h[d.x >> NBS], 1);
            atomicAdd(&h[d.y >> NBS], 1);
            atomicAdd(&h[d.z >> NBS], 1);
            atomicAdd(&h[d.w >> NBS], 1);
        }
    } else {
#pragma unroll
        for (int k = 0; k < EPT; k++) {
            int idx = t + k * TPB;
            int d = (idx < csize) ? dst[c0 + idx] : -1;
            int s = (idx < csize) ? src[c0 + idx] : 0;
            dreg[k] = d;
            sreg[k] = s;
            if (d >= 0) atomicAdd(&h[d >> NBS], 1);
        }
    }
    __syncthreads();
    // per-thread local prefix over its BPT bins
    int loc[BPT], hreg[BPT];
    int ts = 0;
#pragma unroll
    for (int k = 0; k < BPT; k++) {
        hreg[k] = h[t * BPT + k];
        loc[k] = ts;
        ts += hreg[k];
    }
    // block-wide inclusive scan of ts: wave shfl scan + wave-sum combine
    int lane = t & 63, wid = t >> 6;
    int v = ts;
#pragma unroll
    for (int off = 1; off < 64; off <<= 1) {
        int u = __shfl_up(v, off);
        if (lane >= off) v += u;
    }
    if (lane == 63) wsum[wid] = v;
    __syncthreads();
    int pre = 0;
#pragma unroll
    for (int wq = 0; wq < NWAVE - 1; wq++)
        if (wid > wq) pre += wsum[wq];
    int tbase = pre + v - ts;  // exclusive prefix for this thread's first bin
    // deterministic delta: global slot = segbase[s][b] + O[c][b] + rank
    const int* Orow = O + (size_t)blockIdx.x * nb;
    const int* segrow = segbase + (size_t)(blockIdx.x / cps) * nb;
#pragma unroll
    for (int k = 0; k < BPT; k++) {
        int b = t * BPT + k;
        int ex = tbase + loc[k];
        h[b] = ex;  // stage cursor
        delta[b] = (b < nb) ? (segrow[b] + Orow[b] - ex) : 0;
    }
    __syncthreads();
    // LDS counting sort of the chunk (registers -> LDS only)
#pragma unroll
    for (int k = 0; k < EPT; k++) {
        int d = dreg[k];
        if (d >= 0) {
            int b = d >> NBS;
            int r = atomicAdd(&h[b], 1);
            stage[r] = ((d & (NBKT - 1)) << 18) | sreg[k];
            bs[r] = (unsigned short)b;
        }
    }
    __syncthreads();
    for (int k = t; k < csize; k += TPB)
        ntstore(&binned[delta[bs[k]] + k], stage[k]);
}

// full-bucket counting sort, register-cached (single region read), LDS-staged
// dense csr flush. Also rowptr/rowend/dinv/xdq(bf16).
__global__ void __launch_bounds__(TPB) k_sort(
        const int* __restrict__ binned, const int* __restrict__ btot,
        const float* __restrict__ x, int* __restrict__ csr,
        int* __restrict__ rowptr, int* __restrict__ rowend,
        float* __restrict__ dinv, uint4* __restrict__ xdq, int n) {
    __shared__ int stage[CAP];     // 36 KB
    __shared__ int cnt[NBKT];
    __shared__ int curs[NBKT];
    __shared__ int wsum[NWAVE];
    int b = blockIdx.x, t = threadIdx.x;
    int base = b * CAP;
    int c = btot[b];
    cnt[t] = 0;
    __syncthreads();
    // 1) read region once into registers + histogram
    int w[RPT];
#pragma unroll
    for (int k = 0; k < RPT; k++) {
        int idx = t + k * TPB;               // coalesced
        w[k] = (idx < c) ? ntload(&binned[base + idx]) : -1;
        if (w[k] >= 0) atomicAdd(&cnt[w[k] >> 18], 1);
    }
    __syncthreads();
    // 2) exclusive scan of 256 bins: wave shfl scan + combine (1 barrier)
    int v = cnt[t];
    int lane = t & 63, wid = t >> 6;
    int iv = v;
#pragma unroll
    for (int off = 1; off < 64; off <<= 1) {
        int u = __shfl_up(iv, off);
        if (lane >= off) iv += u;
    }
    if (lane == 63) wsum[wid] = iv;
    __syncthreads();
    int pre = 0;
#pragma unroll
    for (int wq = 0; wq < NWAVE - 1; wq++)
        if (wid > wq) pre += wsum[wq];
    int ex = pre + iv - v;  // exclusive
    curs[t] = ex;
    // 3) per-node outputs
    int i = (b << NBS) + t;
    rowptr[i] = base + ex;
    rowend[i] = base + ex + v;
    if (i < n) {
        float di = rsqrtf((float)(v + 1));
        dinv[i] = di;
        uint4 q;
        q.x = pk2(x[i * 6 + 0] * di, x[i * 6 + 1] * di);
        q.y = pk2(x[i * 6 + 2] * di, x[i * 6 + 3] * di);
        q.z = pk2(x[i * 6 + 4] * di, x[i * 6 + 5] * di);
        q.w = 0;
        xdq[i] = q;
    }
    __syncthreads();
    // 4) scatter from registers into LDS stage (node-sorted order)
#pragma unroll
    for (int k = 0; k < RPT; k++) {
        if (w[k] >= 0) {
            int r = atomicAdd(&curs[w[k] >> 18], 1);
            stage[r] = w[k] & 0x3FFFF;
        }
    }
    __syncthreads();
    // 5) dense flush (nt: consumed much later; keep L2 for xdq)
    for (int k = t; k < c; k += TPB)
        ntstore(&csr[base + k], stage[k]);
}

// layer-1 gather (pre-W1 domain, bf16 payload): 16 lanes/node, 4 nodes/wave.
// epilogue: agg6 (incl self) -> @W1 -> relu(di*.+b1) -> @W2 -> *di -> g2q (bf16)
__global__ void __launch_bounds__(TPB) k_gat1(
        const uint4* __restrict__ xdq, const int* __restrict__ csr,
        const int* __restrict__ rowptr, const int* __restrict__ rowend,
        const float* __restrict__ dinv,
        const float* __restrict__ b1, const float* __restrict__ W1,
        const float* __restrict__ W2, uint2* __restrict__ g2q, int n) {
    __shared__ float w1[96];   // 6 x 16
    __shared__ float w2[128];  // 16 x 8
    __shared__ float bb[16];
    if (threadIdx.x < 96) w1[threadIdx.x] = W1[threadIdx.x];
    if (threadIdx.x < 128) w2[threadIdx.x] = W2[threadIdx.x];
    if (threadIdx.x < 16) bb[threadIdx.x] = b1[threadIdx.x];
    __syncthreads();
    int sub = threadIdx.x & 15;                    // lane within node group
    int i = blockIdx.x * 16 + (threadIdx.x >> 4);  // 16 nodes per block
    bool valid = (i < n);
    int r0 = rowptr[i], r1 = rowend[i];            // padded nodes: r0 == r1
    float a0 = 0.f, a1 = 0.f, a2 = 0.f, a3 = 0.f, a4 = 0.f, a5 = 0.f;
    float c0 = 0.f, c1 = 0.f, c2 = 0.f, c3 = 0.f, c4 = 0.f, c5 = 0.f;
    if (valid && sub == 0) {  // self-loop term
        uint4 q = xdq[i];
        a0 += BFLO(q.x); a1 += BFHI(q.x);
        a2 += BFLO(q.y); a3 += BFHI(q.y);
        a4 += BFLO(q.z); a5 += BFHI(q.z);
    }
    int j = r0 + sub;
    while (j + 16 < r1) {
        int i0 = ntload(&csr[j]);
        int i1 = ntload(&csr[j + 16]);
        uint4 q = xdq[i0];
        uint4 p = xdq[i1];
        a0 += BFLO(q.x); a1 += BFHI(q.x);
        a2 += BFLO(q.y); a3 += BFHI(q.y);
        a4 += BFLO(q.z); a5 += BFHI(q.z);
        c0 += BFLO(p.x); c1 += BFHI(p.x);
        c2 += BFLO(p.y); c3 += BFHI(p.y);
        c4 += BFLO(p.z); c5 += BFHI(p.z);
        j += 32;
    }
    if (j < r1) {
        uint4 q = xdq[ntload(&csr[j])];
        a0 += BFLO(q.x); a1 += BFHI(q.x);
        a2 += BFLO(q.y); a3 += BFHI(q.y);
        a4 += BFLO(q.z); a5 += BFHI(q.z);
    }
    a0 += c0; a1 += c1; a2 += c2; a3 += c3; a4 += c4; a5 += c5;
#pragma unroll
    for (int m = 1; m <= 8; m <<= 1) {  // reduce within 16-lane node group
        a0 += __shfl_xor(a0, m); a1 += __shfl_xor(a1, m);
        a2 += __shfl_xor(a2, m); a3 += __shfl_xor(a3, m);
        a4 += __shfl_xor(a4, m); a5 += __shfl_xor(a5, m);
    }
    float di = valid ? dinv[i] : 0.f;
    int f = sub;  // lane = hidden feature
    float hf = a0 * w1[f] + a1 * w1[16 + f] + a2 * w1[32 + f]
             + a3 * w1[48 + f] + a4 * w1[64 + f] + a5 * w1[80 + f];
    float tf = fmaxf(di * hf + bb[f], 0.0f);
    float p0 = tf * w2[f * 8 + 0], p1 = tf * w2[f * 8 + 1];
    float p2 = tf * w2[f * 8 + 2], p3 = tf * w2[f * 8 + 3];
    float p4 = tf * w2[f * 8 + 4], p5 = tf * w2[f * 8 + 5];
    float p6 = tf * w2[f * 8 + 6], p7 = tf * w2[f * 8 + 7];
#pragma unroll
    for (int m = 1; m <= 8; m <<= 1) {  // reduce over the 16 f-lanes
        p0 += __shfl_xor(p0, m); p1 += __shfl_xor(p1, m);
        p2 += __shfl_xor(p2, m); p3 += __shfl_xor(p3, m);
        p4 += __shfl_xor(p4, m); p5 += __shfl_xor(p5, m);
        p6 += __shfl_xor(p6, m); p7 += __shfl_xor(p7, m);
    }
    if (valid && sub < 2) {
        float q0 = sub ? p4 : p0, q1 = sub ? p5 : p1;
        float q2 = sub ? p6 : p2, q3 = sub ? p7 : p3;
        uint2 o;
        o.x = pk2(q0 * di, q1 * di);
        o.y = pk2(q2 * di, q3 * di);
        g2q[i * 2 + sub] = o;
    }
}

// layer-2 gather (bf16 payload): 16 lanes/node, 4 nodes/wave.
// fused head: h = relu(dinv*agg8 + b2); out = sigmoid(h @ Wfc + bfc)
__global__ void __launch_bounds__(TPB) k_gat2(
        const uint4* __restrict__ g2q, const int* __restrict__ csr,
        const int* __restrict__ rowptr, const int* __restrict__ rowend,
        const float* __restrict__ dinv,
        const float* __restrict__ b2, const float* __restrict__ Wfc,
        const float* __restrict__ bfc, float* __restrict__ out, int n) {
    __shared__ float w[8];
    __shared__ float bb[8];
    __shared__ float bf;
    if (threadIdx.x < 8) { w[threadIdx.x] = Wfc[threadIdx.x]; bb[threadIdx.x] = b2[threadIdx.x]; }
    if (threadIdx.x == 0) bf = bfc[0];
    __syncthreads();
    int sub = threadIdx.x & 15;
    int i = blockIdx.x * 16 + (threadIdx.x >> 4);
    bool valid = (i < n);
    int r0 = rowptr[i], r1 = rowend[i];
    float a0 = 0.f, a1 = 0.f, a2 = 0.f, a3 = 0.f;
    float a4 = 0.f, a5 = 0.f, a6 = 0.f, a7 = 0.f;
    if (valid && sub == 0) {  // self-loop term
        uint4 q = g2q[i];
        a0 += BFLO(q.x); a1 += BFHI(q.x); a2 += BFLO(q.y); a3 += BFHI(q.y);
        a4 += BFLO(q.z); a5 += BFHI(q.z); a6 += BFLO(q.w); a7 += BFHI(q.w);
    }
    float c0 = 0.f, c1 = 0.f, c2 = 0.f, c3 = 0.f;
    float c4 = 0.f, c5 = 0.f, c6 = 0.f, c7 = 0.f;
    int j = r0 + sub;
    while (j + 16 < r1) {
        int i0 = ntload(&csr[j]);
        int i1 = ntload(&csr[j + 16]);
        uint4 q = g2q[i0];
        uint4 p = g2q[i1];
        a0 += BFLO(q.x); a1 += BFHI(q.x); a2 += BFLO(q.y); a3 += BFHI(q.y);
        a4 += BFLO(q.z); a5 += BFHI(q.z); a6 += BFLO(q.w); a7 += BFHI(q.w);
        c0 += BFLO(p.x); c1 += BFHI(p.x); c2 += BFLO(p.y); c3 += BFHI(p.y);
        c4 += BFLO(p.z); c5 += BFHI(p.z); c6 += BFLO(p.w); c7 += BFHI(p.w);
        j += 32;
    }
    if (j < r1) {
        uint4 q = g2q[ntload(&csr[j])];
        a0 += BFLO(q.x); a1 += BFHI(q.x); a2 += BFLO(q.y); a3 += BFHI(q.y);
        a4 += BFLO(q.z); a5 += BFHI(q.z); a6 += BFLO(q.w); a7 += BFHI(q.w);
    }
    a0 += c0; a1 += c1; a2 += c2; a3 += c3;
    a4 += c4; a5 += c5; a6 += c6; a7 += c7;
#pragma unroll
    for (int m = 1; m <= 8; m <<= 1) {  // reduce within 16-lane node group
        a0 += __shfl_xor(a0, m); a1 += __shfl_xor(a1, m);
        a2 += __shfl_xor(a2, m); a3 += __shfl_xor(a3, m);
        a4 += __shfl_xor(a4, m); a5 += __shfl_xor(a5, m);
        a6 += __shfl_xor(a6, m); a7 += __shfl_xor(a7, m);
    }
    if (valid && sub == 0) {  // head computed once per node (cheap, no shfl)
        float di = dinv[i];
        float o = bf;
        o += fmaxf(di * a0 + bb[0], 0.0f) * w[0];
        o += fmaxf(di * a1 + bb[1], 0.0f) * w[1];
        o += fmaxf(di * a2 + bb[2], 0.0f) * w[2];
        o += fmaxf(di * a3 + bb[3], 0.0f) * w[3];
        o += fmaxf(di * a4 + bb[4], 0.0f) * w[4];
        o += fmaxf(di * a5 + bb[5], 0.0f) * w[5];
        o += fmaxf(di * a6 + bb[6], 0.0f) * w[6];
        o += fmaxf(di * a7 + bb[7], 0.0f) * w[7];
        out[i] = 1.0f / (1.0f + expf(-o));
    }
}

extern "C" void kernel_launch(void* const* d_in, const int* in_sizes, int n_in,
                              void* d_out, int out_size, void* d_ws, size_t ws_size,
                              hipStream_t stream) {
    const float* x   = (const float*)d_in[0];
    const int*   ei  = (const int*)d_in[1];
    const float* W1  = (const float*)d_in[2];
    const float* b1  = (const float*)d_in[3];
    const float* W2  = (const float*)d_in[4];
    const float* b2  = (const float*)d_in[5];
    const float* Wfc = (const float*)d_in[6];
    const float* bfc = (const float*)d_in[7];
    float* out = (float*)d_out;

    const int n = in_sizes[0] / 6;   // 200000 (<= 262144 for 18-bit packing)
    const int e = in_sizes[1] / 2;   // 6400000
    const int* src = ei;
    const int* dst = ei + e;
    const int nb = (n + NBKT - 1) >> NBS;  // 782
    const size_t np = (size_t)nb << NBS;   // padded node count (200192)
    const int nblk = (e + CHUNK - 1) / CHUNK;  // 1563 chunks
    const int cps = (nblk + NSEG - 1) / NSEG;  // chunks per segment (49)
    const int ngrp = (nb + TPB - 1) / TPB;     // bucket groups (4)
    const size_t reg = (size_t)nb * CAP;   // bucket-region total (7.2M words)

    int* C       = (int*)d_ws;                 // nblk * nb
    int* O       = C + (size_t)nblk * nb;      // nblk * nb
    int* Sseg    = O + (size_t)nblk * nb;      // NSEG * MAXB
    int* segbase = Sseg + (size_t)NSEG * MAXB; // NSEG * MAXB
    int* btot    = segbase + (size_t)NSEG * MAXB; // MAXB
    int* binned  = btot + MAXB;                // reg
    int* csr     = binned + reg;               // reg
    int* rowptr  = csr + reg;                  // np
    int* rowend  = rowptr + np;                // np
    float* dinv  = (float*)(rowend + np);      // np
    size_t off   = (size_t)((int*)(dinv + np) - (int*)d_ws);
    off = (off + 3) & ~(size_t)3;              // 16B-align the uint4 arrays
    uint4* xdq   = (uint4*)((int*)d_ws + off); // np * 16 B
    uint2* g2q   = (uint2*)(xdq + np);         // np * 16 B

    int gw = (n + 15) / 16;              // node-group blocks (16 nodes/block)

    k_fb1<<<nblk, TPB, 0, stream>>>(dst, C, e, nb);
    k_scan1<<<NSEG * ngrp, TPB, 0, stream>>>(C, O, Sseg, nblk, nb, cps, ngrp);
    k_scan2<<<ngrp, TPB, 0, stream>>>(Sseg, segbase, btot, nb);
    k_fillbin<<<nblk, TPB, 0, stream>>>(src, dst, O, segbase, binned, e, nb, cps);
    k_sort<<<nb, TPB, 0, stream>>>(binned, btot, x, csr, rowptr, rowend, dinv, xdq, n);
    k_gat1<<<gw, TPB, 0, stream>>>(xdq, csr, rowptr, rowend, dinv, b1, W1, W2, (uint2*)g2q, n);
    k_gat2<<<gw, TPB, 0, stream>>>((const uint4*)g2q, csr, rowptr, rowend, dinv, b2, Wfc, bfc, out, n);
}

// Round 8
// 244.368 us; speedup vs baseline: 4.0213x; 1.1478x over previous
//
#include <hip/hip_runtime.h>
#include <math.h>

// GCN 2-layer + sigmoid head. CSR pull-gather, zero fp32 atomics.
// R23: R19 structure (proven 244.6us; R22's nt hints reverted — nt binned
//  stores defeated L2 write-combining of scattered segments, +36us) +
//  LDS-staged csr spans in the gather kernels: a block's 16 consecutive
//  nodes live in one bucket, so their csr rows are ONE contiguous span
//  (~512 words). One coalesced cooperative load -> LDS; the inner loop's
//  dependent chain becomes ds_read(~120cy) -> xdq gather, dropping the
//  global csr load (~200-400cy) off the critical path.
//   k_fb1:   per-chunk bucket histogram -> C[chunk][nb]
//   k_scan1/2: 2-level deterministic offset scan (coalesced, no barriers)
//   k_fillbin: LDS chunk counting-sort -> binned (deterministic, no atomics)
//   k_sort:  bucket counting sort -> dense csr, rowptr/rowend, dinv, xdq
//   k_gat1/2: node-group gathers (16 lanes/node, LDS-staged csr span)

#define TPB 256
#define NBS 8
#define NBKT 256        // nodes per bucket
#define MAXB 1024       // max buckets (n <= 262144)
#define BPT (MAXB / TPB)
#define CHUNK 4096      // edges per fillbin block
#define EPT (CHUNK / TPB)
#define CAP 9216        // bucket region capacity (mean 8192 + ~11 sigma)
#define RPT (CAP / TPB) // 36 register-cached words per k_sort thread
#define NWAVE (TPB / 64)
#define NSEG 32         // chunk segments for the 2-level offset scan
#define SPANW 1088      // LDS csr-span capacity per gather block (16 nodes)

__device__ __forceinline__ unsigned short f2bf(float f) {
    unsigned u = __float_as_uint(f);
    unsigned r = (u + 0x7FFFu + ((u >> 16) & 1u)) >> 16;  // RNE
    return (unsigned short)r;
}
__device__ __forceinline__ unsigned pk2(float a, float b) {
    return (unsigned)f2bf(a) | ((unsigned)f2bf(b) << 16);
}
#define BFLO(u) __uint_as_float((u) << 16)
#define BFHI(u) __uint_as_float((u) & 0xFFFF0000u)

// per-chunk bucket histogram -> C[chunk][nb] (coalesced row store)
__global__ void __launch_bounds__(TPB) k_fb1(
        const int* __restrict__ dst, int* __restrict__ C, int e, int nb) {
    __shared__ int h[MAXB];
    int t = threadIdx.x;
    int c0 = blockIdx.x * CHUNK;
    int csize = min(e - c0, CHUNK);
#pragma unroll
    for (int k = 0; k < BPT; k++) h[t * BPT + k] = 0;
    __syncthreads();
    if (csize == CHUNK && ((((size_t)(const void*)(dst + c0)) & 15) == 0)) {
        const int4* d4 = (const int4*)(dst + c0);
#pragma unroll
        for (int k = 0; k < EPT / 4; k++) {
            int4 d = d4[t + k * TPB];
            atomicAdd(&h[d.x >> NBS], 1);
            atomicAdd(&h[d.y >> NBS], 1);
            atomicAdd(&h[d.z >> NBS], 1);
            atomicAdd(&h[d.w >> NBS], 1);
        }
    } else {
        for (int i = t; i < csize; i += TPB)
            atomicAdd(&h[dst[c0 + i] >> NBS], 1);
    }
    __syncthreads();
    int* row = C + (size_t)blockIdx.x * nb;
    for (int b = t; b < nb; b += TPB) row[b] = h[b];
}

// level-1: thread t serially scans bucket-column b over chunk segment s.
__global__ void __launch_bounds__(TPB) k_scan1(
        const int* __restrict__ C, int* __restrict__ O, int* __restrict__ Sseg,
        int nchunk, int nb, int cps, int ngrp) {
    int bid = blockIdx.x;
    int s = bid / ngrp, g = bid - s * ngrp;
    int b = g * TPB + threadIdx.x;
    if (b >= nb) return;
    int cbeg = s * cps;
    int cend = min(cbeg + cps, nchunk);
    int run = 0;
#pragma unroll 4
    for (int c = cbeg; c < cend; c++) {
        int v = C[(size_t)c * nb + b];
        O[(size_t)c * nb + b] = run;
        run += v;
    }
    Sseg[s * nb + b] = run;
}

// level-2: per bucket, exclusive scan of NSEG segment sums; fold in b*CAP.
__global__ void __launch_bounds__(TPB) k_scan2(
        const int* __restrict__ Sseg, int* __restrict__ segbase,
        int* __restrict__ btot, int nb) {
    int b = blockIdx.x * TPB + threadIdx.x;
    if (b >= nb) return;
    int run = b * CAP;
#pragma unroll
    for (int s = 0; s < NSEG; s++) {
        segbase[s * nb + b] = run;
        run += Sseg[s * nb + b];
    }
    btot[b] = run - b * CAP;
}

// bin edges into fixed-cap bucket regions. LDS counting sort of the chunk;
// deterministic delta from segbase+O (no atomics). word: ((d&255)<<18)|s
__global__ void __launch_bounds__(TPB) k_fillbin(
        const int* __restrict__ src, const int* __restrict__ dst,
        const int* __restrict__ O, const int* __restrict__ segbase,
        int* __restrict__ binned, int e, int nb, int cps) {
    __shared__ int stage[CHUNK];            // 16 KB, bucket-sorted packed words
    __shared__ unsigned short bs[CHUNK];    // 8 KB, bucket id per sorted slot
    __shared__ int h[MAXB];                 // 4 KB, hist -> stage cursor
    __shared__ int delta[MAXB];             // 4 KB
    __shared__ int wsum[NWAVE];
    int t = threadIdx.x;
    int c0 = blockIdx.x * CHUNK;
    int csize = min(e - c0, CHUNK);
#pragma unroll
    for (int k = 0; k < BPT; k++) h[t * BPT + k] = 0;
    __syncthreads();
    int dreg[EPT], sreg[EPT];
    if (csize == CHUNK && ((((size_t)(const void*)(dst + c0)) & 15) == 0)
                       && ((((size_t)(const void*)(src + c0)) & 15) == 0)) {
        const int4* d4 = (const int4*)(dst + c0);
        const int4* s4 = (const int4*)(src + c0);
#pragma unroll
        for (int k = 0; k < EPT / 4; k++) {
            int4 d = d4[t + k * TPB];
            int4 s = s4[t + k * TPB];
            dreg[4 * k + 0] = d.x; sreg[4 * k + 0] = s.x;
            dreg[4 * k + 1] = d.y; sreg[4 * k + 1] = s.y;
            dreg[4 * k + 2] = d.z; sreg[4 * k + 2] = s.z;
            dreg[4 * k + 3] = d.w; sreg[4 * k + 3] = s.w;
            atomicAdd(&h[d.x >> NBS], 1);
            atomicAdd(&h[d.y >> NBS], 1);
            atomicAdd(&h[d.z >> NBS], 1);
            atomicAdd(&h[d.w >> NBS], 1);
        }
    } else {
#pragma unroll
        for (int k = 0; k < EPT; k++) {
            int idx = t + k * TPB;
            int d = (idx < csize) ? dst[c0 + idx] : -1;
            int s = (idx < csize) ? src[c0 + idx] : 0;
            dreg[k] = d;
            sreg[k] = s;
            if (d >= 0) atomicAdd(&h[d >> NBS], 1);
        }
    }
    __syncthreads();
    // per-thread local prefix over its BPT bins
    int loc[BPT], hreg[BPT];
    int ts = 0;
#pragma unroll
    for (int k = 0; k < BPT; k++) {
        hreg[k] = h[t * BPT + k];
        loc[k] = ts;
        ts += hreg[k];
    }
    // block-wide inclusive scan of ts: wave shfl scan + wave-sum combine
    int lane = t & 63, wid = t >> 6;
    int v = ts;
#pragma unroll
    for (int off = 1; off < 64; off <<= 1) {
        int u = __shfl_up(v, off);
        if (lane >= off) v += u;
    }
    if (lane == 63) wsum[wid] = v;
    __syncthreads();
    int pre = 0;
#pragma unroll
    for (int wq = 0; wq < NWAVE - 1; wq++)
        if (wid > wq) pre += wsum[wq];
    int tbase = pre + v - ts;  // exclusive prefix for this thread's first bin
    // deterministic delta: global slot = segbase[s][b] + O[c][b] + rank
    const int* Orow = O + (size_t)blockIdx.x * nb;
    const int* segrow = segbase + (size_t)(blockIdx.x / cps) * nb;
#pragma unroll
    for (int k = 0; k < BPT; k++) {
        int b = t * BPT + k;
        int ex = tbase + loc[k];
        h[b] = ex;  // stage cursor
        delta[b] = (b < nb) ? (segrow[b] + Orow[b] - ex) : 0;
    }
    __syncthreads();
    // LDS counting sort of the chunk (registers -> LDS only)
#pragma unroll
    for (int k = 0; k < EPT; k++) {
        int d = dreg[k];
        if (d >= 0) {
            int b = d >> NBS;
            int r = atomicAdd(&h[b], 1);
            stage[r] = ((d & (NBKT - 1)) << 18) | sreg[k];
            bs[r] = (unsigned short)b;
        }
    }
    __syncthreads();
    for (int k = t; k < csize; k += TPB)
        binned[delta[bs[k]] + k] = stage[k];
}

// full-bucket counting sort, register-cached (single region read), LDS-staged
// dense csr flush. Also rowptr/rowend/dinv/xdq(bf16).
__global__ void __launch_bounds__(TPB) k_sort(
        const int* __restrict__ binned, const int* __restrict__ btot,
        const float* __restrict__ x, int* __restrict__ csr,
        int* __restrict__ rowptr, int* __restrict__ rowend,
        float* __restrict__ dinv, uint4* __restrict__ xdq, int n) {
    __shared__ int stage[CAP];     // 36 KB
    __shared__ int cnt[NBKT];
    __shared__ int curs[NBKT];
    __shared__ int wsum[NWAVE];
    int b = blockIdx.x, t = threadIdx.x;
    int base = b * CAP;
    int c = btot[b];
    cnt[t] = 0;
    __syncthreads();
    // 1) read region once into registers + histogram
    int w[RPT];
#pragma unroll
    for (int k = 0; k < RPT; k++) {
        int idx = t + k * TPB;               // coalesced
        w[k] = (idx < c) ? binned[base + idx] : -1;
        if (w[k] >= 0) atomicAdd(&cnt[w[k] >> 18], 1);
    }
    __syncthreads();
    // 2) exclusive scan of 256 bins: wave shfl scan + combine (1 barrier)
    int v = cnt[t];
    int lane = t & 63, wid = t >> 6;
    int iv = v;
#pragma unroll
    for (int off = 1; off < 64; off <<= 1) {
        int u = __shfl_up(iv, off);
        if (lane >= off) iv += u;
    }
    if (lane == 63) wsum[wid] = iv;
    __syncthreads();
    int pre = 0;
#pragma unroll
    for (int wq = 0; wq < NWAVE - 1; wq++)
        if (wid > wq) pre += wsum[wq];
    int ex = pre + iv - v;  // exclusive
    curs[t] = ex;
    // 3) per-node outputs
    int i = (b << NBS) + t;
    rowptr[i] = base + ex;
    rowend[i] = base + ex + v;
    if (i < n) {
        float di = rsqrtf((float)(v + 1));
        dinv[i] = di;
        uint4 q;
        q.x = pk2(x[i * 6 + 0] * di, x[i * 6 + 1] * di);
        q.y = pk2(x[i * 6 + 2] * di, x[i * 6 + 3] * di);
        q.z = pk2(x[i * 6 + 4] * di, x[i * 6 + 5] * di);
        q.w = 0;
        xdq[i] = q;
    }
    __syncthreads();
    // 4) scatter from registers into LDS stage (node-sorted order)
#pragma unroll
    for (int k = 0; k < RPT; k++) {
        if (w[k] >= 0) {
            int r = atomicAdd(&curs[w[k] >> 18], 1);
            stage[r] = w[k] & 0x3FFFF;
        }
    }
    __syncthreads();
    // 5) dense flush
    for (int k = t; k < c; k += TPB)
        csr[base + k] = stage[k];
}

// layer-1 gather (pre-W1 domain, bf16 payload): 16 lanes/node, 4 nodes/wave.
// csr span for the block's 16 nodes is contiguous -> staged in LDS.
// epilogue: agg6 (incl self) -> @W1 -> relu(di*.+b1) -> @W2 -> *di -> g2q (bf16)
__global__ void __launch_bounds__(TPB) k_gat1(
        const uint4* __restrict__ xdq, const int* __restrict__ csr,
        const int* __restrict__ rowptr, const int* __restrict__ rowend,
        const float* __restrict__ dinv,
        const float* __restrict__ b1, const float* __restrict__ W1,
        const float* __restrict__ W2, uint2* __restrict__ g2q, int n, int np) {
    __shared__ float w1[96];   // 6 x 16
    __shared__ float w2[128];  // 16 x 8
    __shared__ float bb[16];
    __shared__ int lcsr[SPANW];
    if (threadIdx.x < 96) w1[threadIdx.x] = W1[threadIdx.x];
    if (threadIdx.x < 128) w2[threadIdx.x] = W2[threadIdx.x];
    if (threadIdx.x < 16) bb[threadIdx.x] = b1[threadIdx.x];
    int i0 = blockIdx.x * 16;
    int s0 = rowptr[i0];
    int s1 = rowend[min(i0 + 15, np - 1)];
    int span = s1 - s0;
    bool uselds = (span <= SPANW);
    if (uselds)
        for (int k = threadIdx.x; k < span; k += TPB) lcsr[k] = csr[s0 + k];
    __syncthreads();
    int sub = threadIdx.x & 15;                    // lane within node group
    int i = i0 + (threadIdx.x >> 4);               // 16 nodes per block
    bool valid = (i < n);
    int r0 = rowptr[i], r1 = rowend[i];            // padded nodes: r0 == r1
    float a0 = 0.f, a1 = 0.f, a2 = 0.f, a3 = 0.f, a4 = 0.f, a5 = 0.f;
    float c0 = 0.f, c1 = 0.f, c2 = 0.f, c3 = 0.f, c4 = 0.f, c5 = 0.f;
    if (valid && sub == 0) {  // self-loop term
        uint4 q = xdq[i];
        a0 += BFLO(q.x); a1 += BFHI(q.x);
        a2 += BFLO(q.y); a3 += BFHI(q.y);
        a4 += BFLO(q.z); a5 += BFHI(q.z);
    }
    int j = r0 + sub;
    if (uselds) {
        while (j + 16 < r1) {
            uint4 q = xdq[lcsr[j - s0]];
            uint4 p = xdq[lcsr[j + 16 - s0]];
            a0 += BFLO(q.x); a1 += BFHI(q.x);
            a2 += BFLO(q.y); a3 += BFHI(q.y);
            a4 += BFLO(q.z); a5 += BFHI(q.z);
            c0 += BFLO(p.x); c1 += BFHI(p.x);
            c2 += BFLO(p.y); c3 += BFHI(p.y);
            c4 += BFLO(p.z); c5 += BFHI(p.z);
            j += 32;
        }
        if (j < r1) {
            uint4 q = xdq[lcsr[j - s0]];
            a0 += BFLO(q.x); a1 += BFHI(q.x);
            a2 += BFLO(q.y); a3 += BFHI(q.y);
            a4 += BFLO(q.z); a5 += BFHI(q.z);
        }
    } else {
        while (j + 16 < r1) {
            uint4 q = xdq[csr[j]];
            uint4 p = xdq[csr[j + 16]];
            a0 += BFLO(q.x); a1 += BFHI(q.x);
            a2 += BFLO(q.y); a3 += BFHI(q.y);
            a4 += BFLO(q.z); a5 += BFHI(q.z);
            c0 += BFLO(p.x); c1 += BFHI(p.x);
            c2 += BFLO(p.y); c3 += BFHI(p.y);
            c4 += BFLO(p.z); c5 += BFHI(p.z);
            j += 32;
        }
        if (j < r1) {
            uint4 q = xdq[csr[j]];
            a0 += BFLO(q.x); a1 += BFHI(q.x);
            a2 += BFLO(q.y); a3 += BFHI(q.y);
            a4 += BFLO(q.z); a5 += BFHI(q.z);
        }
    }
    a0 += c0; a1 += c1; a2 += c2; a3 += c3; a4 += c4; a5 += c5;
#pragma unroll
    for (int m = 1; m <= 8; m <<= 1) {  // reduce within 16-lane node group
        a0 += __shfl_xor(a0, m); a1 += __shfl_xor(a1, m);
        a2 += __shfl_xor(a2, m); a3 += __shfl_xor(a3, m);
        a4 += __shfl_xor(a4, m); a5 += __shfl_xor(a5, m);
    }
    float di = valid ? dinv[i] : 0.f;
    int f = sub;  // lane = hidden feature
    float hf = a0 * w1[f] + a1 * w1[16 + f] + a2 * w1[32 + f]
             + a3 * w1[48 + f] + a4 * w1[64 + f] + a5 * w1[80 + f];
    float tf = fmaxf(di * hf + bb[f], 0.0f);
    float p0 = tf * w2[f * 8 + 0], p1 = tf * w2[f * 8 + 1];
    float p2 = tf * w2[f * 8 + 2], p3 = tf * w2[f * 8 + 3];
    float p4 = tf * w2[f * 8 + 4], p5 = tf * w2[f * 8 + 5];
    float p6 = tf * w2[f * 8 + 6], p7 = tf * w2[f * 8 + 7];
#pragma unroll
    for (int m = 1; m <= 8; m <<= 1) {  // reduce over the 16 f-lanes
        p0 += __shfl_xor(p0, m); p1 += __shfl_xor(p1, m);
        p2 += __shfl_xor(p2, m); p3 += __shfl_xor(p3, m);
        p4 += __shfl_xor(p4, m); p5 += __shfl_xor(p5, m);
        p6 += __shfl_xor(p6, m); p7 += __shfl_xor(p7, m);
    }
    if (valid && sub < 2) {
        float q0 = sub ? p4 : p0, q1 = sub ? p5 : p1;
        float q2 = sub ? p6 : p2, q3 = sub ? p7 : p3;
        uint2 o;
        o.x = pk2(q0 * di, q1 * di);
        o.y = pk2(q2 * di, q3 * di);
        g2q[i * 2 + sub] = o;
    }
}

// layer-2 gather (bf16 payload): 16 lanes/node, 4 nodes/wave, LDS csr span.
// fused head: h = relu(dinv*agg8 + b2); out = sigmoid(h @ Wfc + bfc)
__global__ void __launch_bounds__(TPB) k_gat2(
        const uint4* __restrict__ g2q, const int* __restrict__ csr,
        const int* __restrict__ rowptr, const int* __restrict__ rowend,
        const float* __restrict__ dinv,
        const float* __restrict__ b2, const float* __restrict__ Wfc,
        const float* __restrict__ bfc, float* __restrict__ out, int n, int np) {
    __shared__ float w[8];
    __shared__ float bb[8];
    __shared__ float bf;
    __shared__ int lcsr[SPANW];
    if (threadIdx.x < 8) { w[threadIdx.x] = Wfc[threadIdx.x]; bb[threadIdx.x] = b2[threadIdx.x]; }
    if (threadIdx.x == 0) bf = bfc[0];
    int i0 = blockIdx.x * 16;
    int s0 = rowptr[i0];
    int s1 = rowend[min(i0 + 15, np - 1)];
    int span = s1 - s0;
    bool uselds = (span <= SPANW);
    if (uselds)
        for (int k = threadIdx.x; k < span; k += TPB) lcsr[k] = csr[s0 + k];
    __syncthreads();
    int sub = threadIdx.x & 15;
    int i = i0 + (threadIdx.x >> 4);
    bool valid = (i < n);
    int r0 = rowptr[i], r1 = rowend[i];
    float a0 = 0.f, a1 = 0.f, a2 = 0.f, a3 = 0.f;
    float a4 = 0.f, a5 = 0.f, a6 = 0.f, a7 = 0.f;
    if (valid && sub == 0) {  // self-loop term
        uint4 q = g2q[i];
        a0 += BFLO(q.x); a1 += BFHI(q.x); a2 += BFLO(q.y); a3 += BFHI(q.y);
        a4 += BFLO(q.z); a5 += BFHI(q.z); a6 += BFLO(q.w); a7 += BFHI(q.w);
    }
    float c0 = 0.f, c1 = 0.f, c2 = 0.f, c3 = 0.f;
    float c4 = 0.f, c5 = 0.f, c6 = 0.f, c7 = 0.f;
    int j = r0 + sub;
    if (uselds) {
        while (j + 16 < r1) {
            uint4 q = g2q[lcsr[j - s0]];
            uint4 p = g2q[lcsr[j + 16 - s0]];
            a0 += BFLO(q.x); a1 += BFHI(q.x); a2 += BFLO(q.y); a3 += BFHI(q.y);
            a4 += BFLO(q.z); a5 += BFHI(q.z); a6 += BFLO(q.w); a7 += BFHI(q.w);
            c0 += BFLO(p.x); c1 += BFHI(p.x); c2 += BFLO(p.y); c3 += BFHI(p.y);
            c4 += BFLO(p.z); c5 += BFHI(p.z); c6 += BFLO(p.w); c7 += BFHI(p.w);
            j += 32;
        }
        if (j < r1) {
            uint4 q = g2q[lcsr[j - s0]];
            a0 += BFLO(q.x); a1 += BFHI(q.x); a2 += BFLO(q.y); a3 += BFHI(q.y);
            a4 += BFLO(q.z); a5 += BFHI(q.z); a6 += BFLO(q.w); a7 += BFHI(q.w);
        }
    } else {
        while (j + 16 < r1) {
            uint4 q = g2q[csr[j]];
            uint4 p = g2q[csr[j + 16]];
            a0 += BFLO(q.x); a1 += BFHI(q.x); a2 += BFLO(q.y); a3 += BFHI(q.y);
            a4 += BFLO(q.z); a5 += BFHI(q.z); a6 += BFLO(q.w); a7 += BFHI(q.w);
            c0 += BFLO(p.x); c1 += BFHI(p.x); c2 += BFLO(p.y); c3 += BFHI(p.y);
            c4 += BFLO(p.z); c5 += BFHI(p.z); c6 += BFLO(p.w); c7 += BFHI(p.w);
            j += 32;
        }
        if (j < r1) {
            uint4 q = g2q[csr[j]];
            a0 += BFLO(q.x); a1 += BFHI(q.x); a2 += BFLO(q.y); a3 += BFHI(q.y);
            a4 += BFLO(q.z); a5 += BFHI(q.z); a6 += BFLO(q.w); a7 += BFHI(q.w);
        }
    }
    a0 += c0; a1 += c1; a2 += c2; a3 += c3;
    a4 += c4; a5 += c5; a6 += c6; a7 += c7;
#pragma unroll
    for (int m = 1; m <= 8; m <<= 1) {  // reduce within 16-lane node group
        a0 += __shfl_xor(a0, m); a1 += __shfl_xor(a1, m);
        a2 += __shfl_xor(a2, m); a3 += __shfl_xor(a3, m);
        a4 += __shfl_xor(a4, m); a5 += __shfl_xor(a5, m);
        a6 += __shfl_xor(a6, m); a7 += __shfl_xor(a7, m);
    }
    if (valid && sub == 0) {  // head computed once per node (cheap, no shfl)
        float di = dinv[i];
        float o = bf;
        o += fmaxf(di * a0 + bb[0], 0.0f) * w[0];
        o += fmaxf(di * a1 + bb[1], 0.0f) * w[1];
        o += fmaxf(di * a2 + bb[2], 0.0f) * w[2];
        o += fmaxf(di * a3 + bb[3], 0.0f) * w[3];
        o += fmaxf(di * a4 + bb[4], 0.0f) * w[4];
        o += fmaxf(di * a5 + bb[5], 0.0f) * w[5];
        o += fmaxf(di * a6 + bb[6], 0.0f) * w[6];
        o += fmaxf(di * a7 + bb[7], 0.0f) * w[7];
        out[i] = 1.0f / (1.0f + expf(-o));
    }
}

extern "C" void kernel_launch(void* const* d_in, const int* in_sizes, int n_in,
                              void* d_out, int out_size, void* d_ws, size_t ws_size,
                              hipStream_t stream) {
    const float* x   = (const float*)d_in[0];
    const int*   ei  = (const int*)d_in[1];
    const float* W1  = (const float*)d_in[2];
    const float* b1  = (const float*)d_in[3];
    const float* W2  = (const float*)d_in[4];
    const float* b2  = (const float*)d_in[5];
    const float* Wfc = (const float*)d_in[6];
    const float* bfc = (const float*)d_in[7];
    float* out = (float*)d_out;

    const int n = in_sizes[0] / 6;   // 200000 (<= 262144 for 18-bit packing)
    const int e = in_sizes[1] / 2;   // 6400000
    const int* src = ei;
    const int* dst = ei + e;
    const int nb = (n + NBKT - 1) >> NBS;  // 782
    const size_t np = (size_t)nb << NBS;   // padded node count (200192)
    const int nblk = (e + CHUNK - 1) / CHUNK;  // 1563 chunks
    const int cps = (nblk + NSEG - 1) / NSEG;  // chunks per segment (49)
    const int ngrp = (nb + TPB - 1) / TPB;     // bucket groups (4)
    const size_t reg = (size_t)nb * CAP;   // bucket-region total (7.2M words)

    int* C       = (int*)d_ws;                 // nblk * nb
    int* O       = C + (size_t)nblk * nb;      // nblk * nb
    int* Sseg    = O + (size_t)nblk * nb;      // NSEG * MAXB
    int* segbase = Sseg + (size_t)NSEG * MAXB; // NSEG * MAXB
    int* btot    = segbase + (size_t)NSEG * MAXB; // MAXB
    int* binned  = btot + MAXB;                // reg
    int* csr     = binned + reg;               // reg
    int* rowptr  = csr + reg;                  // np
    int* rowend  = rowptr + np;                // np
    float* dinv  = (float*)(rowend + np);      // np
    size_t off   = (size_t)((int*)(dinv + np) - (int*)d_ws);
    off = (off + 3) & ~(size_t)3;              // 16B-align the uint4 arrays
    uint4* xdq   = (uint4*)((int*)d_ws + off); // np * 16 B
    uint2* g2q   = (uint2*)(xdq + np);         // np * 16 B

    int gw = (n + 15) / 16;              // node-group blocks (16 nodes/block)

    k_fb1<<<nblk, TPB, 0, stream>>>(dst, C, e, nb);
    k_scan1<<<NSEG * ngrp, TPB, 0, stream>>>(C, O, Sseg, nblk, nb, cps, ngrp);
    k_scan2<<<ngrp, TPB, 0, stream>>>(Sseg, segbase, btot, nb);
    k_fillbin<<<nblk, TPB, 0, stream>>>(src, dst, O, segbase, binned, e, nb, cps);
    k_sort<<<nb, TPB, 0, stream>>>(binned, btot, x, csr, rowptr, rowend, dinv, xdq, n);
    k_gat1<<<gw, TPB, 0, stream>>>(xdq, csr, rowptr, rowend, dinv, b1, W1, W2,
                                   (uint2*)g2q, n, (int)np);
    k_gat2<<<gw, TPB, 0, stream>>>((const uint4*)g2q, csr, rowptr, rowend, dinv,
                                   b2, Wfc, bfc, out, n, (int)np);
}

// Round 9
// 243.570 us; speedup vs baseline: 4.0345x; 1.0033x over previous
//
#include <hip/hip_runtime.h>
#include <math.h>

// GCN 2-layer + sigmoid head. CSR pull-gather, zero fp32 atomics.
// R24: preprocessing kernels are LDS-op-issue-bound (fillbin ~7.5 wave-LDS
//  ops/edge ~ 190K cy/CU > 120K cy kernel time; HBM 20%, VALU 7.5%). Cut op
//  count via vectorization:
//   - k_fillbin flush: stage int4 + bs ushort4 reads (full-chunk fast path)
//   - k_sort: int4 region loads; b128 LDS reads + int4 stores in csr flush
//   - k_gat1/2: plain global-csr (R23's LDS span was neutral -> dropped;
//     gathers are request-rate-bound, not csr-chain-bound)
//  R22 lesson: no nt hints (defeats L2 write-combining). R21: no global deg
//  atomics. R18/R20: staged binning + pull-gather is the right structure.
//   k_fb1:   per-chunk bucket histogram -> C[chunk][nb]
//   k_scan1/2: 2-level deterministic offset scan (coalesced, no barriers)
//   k_fillbin: LDS chunk counting-sort -> binned (deterministic, no atomics)
//   k_sort:  bucket counting sort -> dense csr, rowptr/rowend, dinv, xdq
//   k_gat1/2: node-group gathers (16 lanes/node, bf16 payloads L2-resident)

#define TPB 256
#define NBS 8
#define NBKT 256        // nodes per bucket
#define MAXB 1024       // max buckets (n <= 262144)
#define BPT (MAXB / TPB)
#define CHUNK 4096      // edges per fillbin block
#define EPT (CHUNK / TPB)
#define CAP 9216        // bucket region capacity (mean 8192 + ~11 sigma)
#define RPT (CAP / TPB) // 36 register-cached words per k_sort thread
#define NWAVE (TPB / 64)
#define NSEG 32         // chunk segments for the 2-level offset scan

__device__ __forceinline__ unsigned short f2bf(float f) {
    unsigned u = __float_as_uint(f);
    unsigned r = (u + 0x7FFFu + ((u >> 16) & 1u)) >> 16;  // RNE
    return (unsigned short)r;
}
__device__ __forceinline__ unsigned pk2(float a, float b) {
    return (unsigned)f2bf(a) | ((unsigned)f2bf(b) << 16);
}
#define BFLO(u) __uint_as_float((u) << 16)
#define BFHI(u) __uint_as_float((u) & 0xFFFF0000u)

// per-chunk bucket histogram -> C[chunk][nb] (coalesced row store)
__global__ void __launch_bounds__(TPB) k_fb1(
        const int* __restrict__ dst, int* __restrict__ C, int e, int nb) {
    __shared__ int h[MAXB];
    int t = threadIdx.x;
    int c0 = blockIdx.x * CHUNK;
    int csize = min(e - c0, CHUNK);
#pragma unroll
    for (int k = 0; k < BPT; k++) h[t * BPT + k] = 0;
    __syncthreads();
    if (csize == CHUNK && ((((size_t)(const void*)(dst + c0)) & 15) == 0)) {
        const int4* d4 = (const int4*)(dst + c0);
#pragma unroll
        for (int k = 0; k < EPT / 4; k++) {
            int4 d = d4[t + k * TPB];
            atomicAdd(&h[d.x >> NBS], 1);
            atomicAdd(&h[d.y >> NBS], 1);
            atomicAdd(&h[d.z >> NBS], 1);
            atomicAdd(&h[d.w >> NBS], 1);
        }
    } else {
        for (int i = t; i < csize; i += TPB)
            atomicAdd(&h[dst[c0 + i] >> NBS], 1);
    }
    __syncthreads();
    int* row = C + (size_t)blockIdx.x * nb;
    for (int b = t; b < nb; b += TPB) row[b] = h[b];
}

// level-1: thread t serially scans bucket-column b over chunk segment s.
__global__ void __launch_bounds__(TPB) k_scan1(
        const int* __restrict__ C, int* __restrict__ O, int* __restrict__ Sseg,
        int nchunk, int nb, int cps, int ngrp) {
    int bid = blockIdx.x;
    int s = bid / ngrp, g = bid - s * ngrp;
    int b = g * TPB + threadIdx.x;
    if (b >= nb) return;
    int cbeg = s * cps;
    int cend = min(cbeg + cps, nchunk);
    int run = 0;
#pragma unroll 4
    for (int c = cbeg; c < cend; c++) {
        int v = C[(size_t)c * nb + b];
        O[(size_t)c * nb + b] = run;
        run += v;
    }
    Sseg[s * nb + b] = run;
}

// level-2: per bucket, exclusive scan of NSEG segment sums; fold in b*CAP.
__global__ void __launch_bounds__(TPB) k_scan2(
        const int* __restrict__ Sseg, int* __restrict__ segbase,
        int* __restrict__ btot, int nb) {
    int b = blockIdx.x * TPB + threadIdx.x;
    if (b >= nb) return;
    int run = b * CAP;
#pragma unroll
    for (int s = 0; s < NSEG; s++) {
        segbase[s * nb + b] = run;
        run += Sseg[s * nb + b];
    }
    btot[b] = run - b * CAP;
}

// bin edges into fixed-cap bucket regions. LDS counting sort of the chunk;
// deterministic delta from segbase+O (no atomics). word: ((d&255)<<18)|s
__global__ void __launch_bounds__(TPB) k_fillbin(
        const int* __restrict__ src, const int* __restrict__ dst,
        const int* __restrict__ O, const int* __restrict__ segbase,
        int* __restrict__ binned, int e, int nb, int cps) {
    __shared__ __align__(16) int stage[CHUNK];          // 16 KB, sorted words
    __shared__ __align__(16) unsigned short bs[CHUNK];  // 8 KB, bucket/slot
    __shared__ int h[MAXB];                 // 4 KB, hist -> stage cursor
    __shared__ int delta[MAXB];             // 4 KB
    __shared__ int wsum[NWAVE];
    int t = threadIdx.x;
    int c0 = blockIdx.x * CHUNK;
    int csize = min(e - c0, CHUNK);
#pragma unroll
    for (int k = 0; k < BPT; k++) h[t * BPT + k] = 0;
    __syncthreads();
    int dreg[EPT], sreg[EPT];
    if (csize == CHUNK && ((((size_t)(const void*)(dst + c0)) & 15) == 0)
                       && ((((size_t)(const void*)(src + c0)) & 15) == 0)) {
        const int4* d4 = (const int4*)(dst + c0);
        const int4* s4 = (const int4*)(src + c0);
#pragma unroll
        for (int k = 0; k < EPT / 4; k++) {
            int4 d = d4[t + k * TPB];
            int4 s = s4[t + k * TPB];
            dreg[4 * k + 0] = d.x; sreg[4 * k + 0] = s.x;
            dreg[4 * k + 1] = d.y; sreg[4 * k + 1] = s.y;
            dreg[4 * k + 2] = d.z; sreg[4 * k + 2] = s.z;
            dreg[4 * k + 3] = d.w; sreg[4 * k + 3] = s.w;
            atomicAdd(&h[d.x >> NBS], 1);
            atomicAdd(&h[d.y >> NBS], 1);
            atomicAdd(&h[d.z >> NBS], 1);
            atomicAdd(&h[d.w >> NBS], 1);
        }
    } else {
#pragma unroll
        for (int k = 0; k < EPT; k++) {
            int idx = t + k * TPB;
            int d = (idx < csize) ? dst[c0 + idx] : -1;
            int s = (idx < csize) ? src[c0 + idx] : 0;
            dreg[k] = d;
            sreg[k] = s;
            if (d >= 0) atomicAdd(&h[d >> NBS], 1);
        }
    }
    __syncthreads();
    // per-thread local prefix over its BPT bins
    int loc[BPT], hreg[BPT];
    int ts = 0;
#pragma unroll
    for (int k = 0; k < BPT; k++) {
        hreg[k] = h[t * BPT + k];
        loc[k] = ts;
        ts += hreg[k];
    }
    // block-wide inclusive scan of ts: wave shfl scan + wave-sum combine
    int lane = t & 63, wid = t >> 6;
    int v = ts;
#pragma unroll
    for (int off = 1; off < 64; off <<= 1) {
        int u = __shfl_up(v, off);
        if (lane >= off) v += u;
    }
    if (lane == 63) wsum[wid] = v;
    __syncthreads();
    int pre = 0;
#pragma unroll
    for (int wq = 0; wq < NWAVE - 1; wq++)
        if (wid > wq) pre += wsum[wq];
    int tbase = pre + v - ts;  // exclusive prefix for this thread's first bin
    // deterministic delta: global slot = segbase[s][b] + O[c][b] + rank
    const int* Orow = O + (size_t)blockIdx.x * nb;
    const int* segrow = segbase + (size_t)(blockIdx.x / cps) * nb;
#pragma unroll
    for (int k = 0; k < BPT; k++) {
        int b = t * BPT + k;
        int ex = tbase + loc[k];
        h[b] = ex;  // stage cursor
        delta[b] = (b < nb) ? (segrow[b] + Orow[b] - ex) : 0;
    }
    __syncthreads();
    // LDS counting sort of the chunk (registers -> LDS only)
#pragma unroll
    for (int k = 0; k < EPT; k++) {
        int d = dreg[k];
        if (d >= 0) {
            int b = d >> NBS;
            int r = atomicAdd(&h[b], 1);
            stage[r] = ((d & (NBKT - 1)) << 18) | sreg[k];
            bs[r] = (unsigned short)b;
        }
    }
    __syncthreads();
    // flush: vectorized LDS reads (int4 stage, ushort4 bs) in the full-chunk
    // fast path -> halves flush LDS op count.
    if (csize == CHUNK) {
#pragma unroll
        for (int j = 0; j < CHUNK / (4 * TPB); j++) {
            int kb = 4 * t + j * 4 * TPB;
            int4 sv = *(const int4*)&stage[kb];
            ushort4 bv = *(const ushort4*)&bs[kb];
            binned[delta[bv.x] + kb + 0] = sv.x;
            binned[delta[bv.y] + kb + 1] = sv.y;
            binned[delta[bv.z] + kb + 2] = sv.z;
            binned[delta[bv.w] + kb + 3] = sv.w;
        }
    } else {
        for (int k = t; k < csize; k += TPB)
            binned[delta[bs[k]] + k] = stage[k];
    }
}

// full-bucket counting sort, register-cached (single region read via int4),
// LDS-staged dense csr flush (b128 reads + int4 stores).
// Also rowptr/rowend/dinv/xdq(bf16).
__global__ void __launch_bounds__(TPB) k_sort(
        const int* __restrict__ binned, const int* __restrict__ btot,
        const float* __restrict__ x, int* __restrict__ csr,
        int* __restrict__ rowptr, int* __restrict__ rowend,
        float* __restrict__ dinv, uint4* __restrict__ xdq, int n) {
    __shared__ __align__(16) int stage[CAP];     // 36 KB
    __shared__ int cnt[NBKT];
    __shared__ int curs[NBKT];
    __shared__ int wsum[NWAVE];
    int b = blockIdx.x, t = threadIdx.x;
    int base = b * CAP;
    int c = btot[b];
    cnt[t] = 0;
    __syncthreads();
    // 1) read region once into registers (int4) + histogram
    int w[RPT];
#pragma unroll
    for (int k = 0; k < RPT / 4; k++) {
        int idx = 4 * t + k * 4 * TPB;
        int4 v;
        if (idx + 4 <= c) {
            v = *(const int4*)&binned[base + idx];
        } else {
            v.x = (idx + 0 < c) ? binned[base + idx + 0] : -1;
            v.y = (idx + 1 < c) ? binned[base + idx + 1] : -1;
            v.z = (idx + 2 < c) ? binned[base + idx + 2] : -1;
            v.w = (idx + 3 < c) ? binned[base + idx + 3] : -1;
        }
        w[4 * k + 0] = v.x; w[4 * k + 1] = v.y;
        w[4 * k + 2] = v.z; w[4 * k + 3] = v.w;
        if (v.x >= 0) atomicAdd(&cnt[v.x >> 18], 1);
        if (v.y >= 0) atomicAdd(&cnt[v.y >> 18], 1);
        if (v.z >= 0) atomicAdd(&cnt[v.z >> 18], 1);
        if (v.w >= 0) atomicAdd(&cnt[v.w >> 18], 1);
    }
    __syncthreads();
    // 2) exclusive scan of 256 bins: wave shfl scan + combine (1 barrier)
    int v = cnt[t];
    int lane = t & 63, wid = t >> 6;
    int iv = v;
#pragma unroll
    for (int off = 1; off < 64; off <<= 1) {
        int u = __shfl_up(iv, off);
        if (lane >= off) iv += u;
    }
    if (lane == 63) wsum[wid] = iv;
    __syncthreads();
    int pre = 0;
#pragma unroll
    for (int wq = 0; wq < NWAVE - 1; wq++)
        if (wid > wq) pre += wsum[wq];
    int ex = pre + iv - v;  // exclusive
    curs[t] = ex;
    // 3) per-node outputs
    int i = (b << NBS) + t;
    rowptr[i] = base + ex;
    rowend[i] = base + ex + v;
    if (i < n) {
        float di = rsqrtf((float)(v + 1));
        dinv[i] = di;
        uint4 q;
        q.x = pk2(x[i * 6 + 0] * di, x[i * 6 + 1] * di);
        q.y = pk2(x[i * 6 + 2] * di, x[i * 6 + 3] * di);
        q.z = pk2(x[i * 6 + 4] * di, x[i * 6 + 5] * di);
        q.w = 0;
        xdq[i] = q;
    }
    __syncthreads();
    // 4) scatter from registers into LDS stage (node-sorted order)
#pragma unroll
    for (int k = 0; k < RPT; k++) {
        if (w[k] >= 0) {
            int r = atomicAdd(&curs[w[k] >> 18], 1);
            stage[r] = w[k] & 0x3FFFF;
        }
    }
    __syncthreads();
    // 5) dense flush: b128 LDS reads + int4 global stores, scalar tail
    for (int kb = 4 * t; kb + 4 <= c; kb += 4 * TPB) {
        int4 sv = *(const int4*)&stage[kb];
        *(int4*)&csr[base + kb] = sv;
    }
    for (int k = (c & ~3) + t; k < c; k += TPB)
        csr[base + k] = stage[k];
}

// layer-1 gather (pre-W1 domain, bf16 payload): 16 lanes/node, 4 nodes/wave.
// epilogue: agg6 (incl self) -> @W1 -> relu(di*.+b1) -> @W2 -> *di -> g2q (bf16)
__global__ void __launch_bounds__(TPB) k_gat1(
        const uint4* __restrict__ xdq, const int* __restrict__ csr,
        const int* __restrict__ rowptr, const int* __restrict__ rowend,
        const float* __restrict__ dinv,
        const float* __restrict__ b1, const float* __restrict__ W1,
        const float* __restrict__ W2, uint2* __restrict__ g2q, int n) {
    __shared__ float w1[96];   // 6 x 16
    __shared__ float w2[128];  // 16 x 8
    __shared__ float bb[16];
    if (threadIdx.x < 96) w1[threadIdx.x] = W1[threadIdx.x];
    if (threadIdx.x < 128) w2[threadIdx.x] = W2[threadIdx.x];
    if (threadIdx.x < 16) bb[threadIdx.x] = b1[threadIdx.x];
    __syncthreads();
    int sub = threadIdx.x & 15;                    // lane within node group
    int i = blockIdx.x * 16 + (threadIdx.x >> 4);  // 16 nodes per block
    bool valid = (i < n);
    int r0 = rowptr[i], r1 = rowend[i];            // padded nodes: r0 == r1
    float a0 = 0.f, a1 = 0.f, a2 = 0.f, a3 = 0.f, a4 = 0.f, a5 = 0.f;
    float c0 = 0.f, c1 = 0.f, c2 = 0.f, c3 = 0.f, c4 = 0.f, c5 = 0.f;
    if (valid && sub == 0) {  // self-loop term
        uint4 q = xdq[i];
        a0 += BFLO(q.x); a1 += BFHI(q.x);
        a2 += BFLO(q.y); a3 += BFHI(q.y);
        a4 += BFLO(q.z); a5 += BFHI(q.z);
    }
    int j = r0 + sub;
    while (j + 16 < r1) {
        uint4 q = xdq[csr[j]];
        uint4 p = xdq[csr[j + 16]];
        a0 += BFLO(q.x); a1 += BFHI(q.x);
        a2 += BFLO(q.y); a3 += BFHI(q.y);
        a4 += BFLO(q.z); a5 += BFHI(q.z);
        c0 += BFLO(p.x); c1 += BFHI(p.x);
        c2 += BFLO(p.y); c3 += BFHI(p.y);
        c4 += BFLO(p.z); c5 += BFHI(p.z);
        j += 32;
    }
    if (j < r1) {
        uint4 q = xdq[csr[j]];
        a0 += BFLO(q.x); a1 += BFHI(q.x);
        a2 += BFLO(q.y); a3 += BFHI(q.y);
        a4 += BFLO(q.z); a5 += BFHI(q.z);
    }
    a0 += c0; a1 += c1; a2 += c2; a3 += c3; a4 += c4; a5 += c5;
#pragma unroll
    for (int m = 1; m <= 8; m <<= 1) {  // reduce within 16-lane node group
        a0 += __shfl_xor(a0, m); a1 += __shfl_xor(a1, m);
        a2 += __shfl_xor(a2, m); a3 += __shfl_xor(a3, m);
        a4 += __shfl_xor(a4, m); a5 += __shfl_xor(a5, m);
    }
    float di = valid ? dinv[i] : 0.f;
    int f = sub;  // lane = hidden feature
    float hf = a0 * w1[f] + a1 * w1[16 + f] + a2 * w1[32 + f]
             + a3 * w1[48 + f] + a4 * w1[64 + f] + a5 * w1[80 + f];
    float tf = fmaxf(di * hf + bb[f], 0.0f);
    float p0 = tf * w2[f * 8 + 0], p1 = tf * w2[f * 8 + 1];
    float p2 = tf * w2[f * 8 + 2], p3 = tf * w2[f * 8 + 3];
    float p4 = tf * w2[f * 8 + 4], p5 = tf * w2[f * 8 + 5];
    float p6 = tf * w2[f * 8 + 6], p7 = tf * w2[f * 8 + 7];
#pragma unroll
    for (int m = 1; m <= 8; m <<= 1) {  // reduce over the 16 f-lanes
        p0 += __shfl_xor(p0, m); p1 += __shfl_xor(p1, m);
        p2 += __shfl_xor(p2, m); p3 += __shfl_xor(p3, m);
        p4 += __shfl_xor(p4, m); p5 += __shfl_xor(p5, m);
        p6 += __shfl_xor(p6, m); p7 += __shfl_xor(p7, m);
    }
    if (valid && sub < 2) {
        float q0 = sub ? p4 : p0, q1 = sub ? p5 : p1;
        float q2 = sub ? p6 : p2, q3 = sub ? p7 : p3;
        uint2 o;
        o.x = pk2(q0 * di, q1 * di);
        o.y = pk2(q2 * di, q3 * di);
        g2q[i * 2 + sub] = o;
    }
}

// layer-2 gather (bf16 payload): 16 lanes/node, 4 nodes/wave.
// fused head: h = relu(dinv*agg8 + b2); out = sigmoid(h @ Wfc + bfc)
__global__ void __launch_bounds__(TPB) k_gat2(
        const uint4* __restrict__ g2q, const int* __restrict__ csr,
        const int* __restrict__ rowptr, const int* __restrict__ rowend,
        const float* __restrict__ dinv,
        const float* __restrict__ b2, const float* __restrict__ Wfc,
        const float* __restrict__ bfc, float* __restrict__ out, int n) {
    __shared__ float w[8];
    __shared__ float bb[8];
    __shared__ float bf;
    if (threadIdx.x < 8) { w[threadIdx.x] = Wfc[threadIdx.x]; bb[threadIdx.x] = b2[threadIdx.x]; }
    if (threadIdx.x == 0) bf = bfc[0];
    __syncthreads();
    int sub = threadIdx.x & 15;
    int i = blockIdx.x * 16 + (threadIdx.x >> 4);
    bool valid = (i < n);
    int r0 = rowptr[i], r1 = rowend[i];
    float a0 = 0.f, a1 = 0.f, a2 = 0.f, a3 = 0.f;
    float a4 = 0.f, a5 = 0.f, a6 = 0.f, a7 = 0.f;
    if (valid && sub == 0) {  // self-loop term
        uint4 q = g2q[i];
        a0 += BFLO(q.x); a1 += BFHI(q.x); a2 += BFLO(q.y); a3 += BFHI(q.y);
        a4 += BFLO(q.z); a5 += BFHI(q.z); a6 += BFLO(q.w); a7 += BFHI(q.w);
    }
    float c0 = 0.f, c1 = 0.f, c2 = 0.f, c3 = 0.f;
    float c4 = 0.f, c5 = 0.f, c6 = 0.f, c7 = 0.f;
    int j = r0 + sub;
    while (j + 16 < r1) {
        uint4 q = g2q[csr[j]];
        uint4 p = g2q[csr[j + 16]];
        a0 += BFLO(q.x); a1 += BFHI(q.x); a2 += BFLO(q.y); a3 += BFHI(q.y);
        a4 += BFLO(q.z); a5 += BFHI(q.z); a6 += BFLO(q.w); a7 += BFHI(q.w);
        c0 += BFLO(p.x); c1 += BFHI(p.x); c2 += BFLO(p.y); c3 += BFHI(p.y);
        c4 += BFLO(p.z); c5 += BFHI(p.z); c6 += BFLO(p.w); c7 += BFHI(p.w);
        j += 32;
    }
    if (j < r1) {
        uint4 q = g2q[csr[j]];
        a0 += BFLO(q.x); a1 += BFHI(q.x); a2 += BFLO(q.y); a3 += BFHI(q.y);
        a4 += BFLO(q.z); a5 += BFHI(q.z); a6 += BFLO(q.w); a7 += BFHI(q.w);
    }
    a0 += c0; a1 += c1; a2 += c2; a3 += c3;
    a4 += c4; a5 += c5; a6 += c6; a7 += c7;
#pragma unroll
    for (int m = 1; m <= 8; m <<= 1) {  // reduce within 16-lane node group
        a0 += __shfl_xor(a0, m); a1 += __shfl_xor(a1, m);
        a2 += __shfl_xor(a2, m); a3 += __shfl_xor(a3, m);
        a4 += __shfl_xor(a4, m); a5 += __shfl_xor(a5, m);
        a6 += __shfl_xor(a6, m); a7 += __shfl_xor(a7, m);
    }
    if (valid && sub == 0) {  // head computed once per node (cheap, no shfl)
        float di = dinv[i];
        float o = bf;
        o += fmaxf(di * a0 + bb[0], 0.0f) * w[0];
        o += fmaxf(di * a1 + bb[1], 0.0f) * w[1];
        o += fmaxf(di * a2 + bb[2], 0.0f) * w[2];
        o += fmaxf(di * a3 + bb[3], 0.0f) * w[3];
        o += fmaxf(di * a4 + bb[4], 0.0f) * w[4];
        o += fmaxf(di * a5 + bb[5], 0.0f) * w[5];
        o += fmaxf(di * a6 + bb[6], 0.0f) * w[6];
        o += fmaxf(di * a7 + bb[7], 0.0f) * w[7];
        out[i] = 1.0f / (1.0f + expf(-o));
    }
}

extern "C" void kernel_launch(void* const* d_in, const int* in_sizes, int n_in,
                              void* d_out, int out_size, void* d_ws, size_t ws_size,
                              hipStream_t stream) {
    const float* x   = (const float*)d_in[0];
    const int*   ei  = (const int*)d_in[1];
    const float* W1  = (const float*)d_in[2];
    const float* b1  = (const float*)d_in[3];
    const float* W2  = (const float*)d_in[4];
    const float* b2  = (const float*)d_in[5];
    const float* Wfc = (const float*)d_in[6];
    const float* bfc = (const float*)d_in[7];
    float* out = (float*)d_out;

    const int n = in_sizes[0] / 6;   // 200000 (<= 262144 for 18-bit packing)
    const int e = in_sizes[1] / 2;   // 6400000
    const int* src = ei;
    const int* dst = ei + e;
    const int nb = (n + NBKT - 1) >> NBS;  // 782
    const size_t np = (size_t)nb << NBS;   // padded node count (200192)
    const int nblk = (e + CHUNK - 1) / CHUNK;  // 1563 chunks
    const int cps = (nblk + NSEG - 1) / NSEG;  // chunks per segment (49)
    const int ngrp = (nb + TPB - 1) / TPB;     // bucket groups (4)
    const size_t reg = (size_t)nb * CAP;   // bucket-region total (7.2M words)

    int* C       = (int*)d_ws;                 // nblk * nb
    int* O       = C + (size_t)nblk * nb;      // nblk * nb
    int* Sseg    = O + (size_t)nblk * nb;      // NSEG * MAXB
    int* segbase = Sseg + (size_t)NSEG * MAXB; // NSEG * MAXB
    int* btot    = segbase + (size_t)NSEG * MAXB; // MAXB
    int* binned  = btot + MAXB;                // reg (16B-aligned: offsets sum %4==0)
    int* csr     = binned + reg;               // reg (CAP%4==0 -> rows 16B-tileable)
    int* rowptr  = csr + reg;                  // np
    int* rowend  = rowptr + np;                // np
    float* dinv  = (float*)(rowend + np);      // np
    size_t off   = (size_t)((int*)(dinv + np) - (int*)d_ws);
    off = (off + 3) & ~(size_t)3;              // 16B-align the uint4 arrays
    uint4* xdq   = (uint4*)((int*)d_ws + off); // np * 16 B
    uint2* g2q   = (uint2*)(xdq + np);         // np * 16 B

    int gw = (n + 15) / 16;              // node-group blocks (16 nodes/block)

    k_fb1<<<nblk, TPB, 0, stream>>>(dst, C, e, nb);
    k_scan1<<<NSEG * ngrp, TPB, 0, stream>>>(C, O, Sseg, nblk, nb, cps, ngrp);
    k_scan2<<<ngrp, TPB, 0, stream>>>(Sseg, segbase, btot, nb);
    k_fillbin<<<nblk, TPB, 0, stream>>>(src, dst, O, segbase, binned, e, nb, cps);
    k_sort<<<nb, TPB, 0, stream>>>(binned, btot, x, csr, rowptr, rowend, dinv, xdq, n);
    k_gat1<<<gw, TPB, 0, stream>>>(xdq, csr, rowptr, rowend, dinv, b1, W1, W2, (uint2*)g2q, n);
    k_gat2<<<gw, TPB, 0, stream>>>((const uint4*)g2q, csr, rowptr, rowend, dinv, b2, Wfc, bfc, out, n);
}

// Round 11
// 241.537 us; speedup vs baseline: 4.0684x; 1.0084x over previous
//
#include <hip/hip_runtime.h>
#include <math.h>

// GCN 2-layer + sigmoid head. CSR pull-gather, zero fp32 atomics.
// R25b: R25 retry with the ROCm-7 buffer builtin spelling. Payload gathers
//  via buffer_load_dwordx4 sc0 (GLC): read from L2 WITHOUT allocating L1
//  lines. Theory: gathers are L1-miss/fill-rate bound (~1 random 16B gather
//  per 4.8 cy/CU across 5 structural variants; L2 BW and VALU far from
//  limits; 3.2MB tables ~0% L1 hit -> every gather pays L1 allocate/fill
//  for nothing). Guarded by __has_builtin -> falls back to plain loads.
//  R24: fillbin not LDS-op bound. R23: gathers not csr-chain bound.
//  R22: no nt on scattered stores. R21: no global deg atomics.
//   k_fb1:   per-chunk bucket histogram -> C[chunk][nb]
//   k_scan1/2: 2-level deterministic offset scan (coalesced, no barriers)
//   k_fillbin: LDS chunk counting-sort -> binned (deterministic, no atomics)
//   k_sort:  bucket counting sort -> dense csr, rowptr/rowend, dinv, xdq
//   k_gat1/2: node-group gathers (16 lanes/node, sc0 L1-bypass payloads)

#define TPB 256
#define NBS 8
#define NBKT 256        // nodes per bucket
#define MAXB 1024       // max buckets (n <= 262144)
#define BPT (MAXB / TPB)
#define CHUNK 4096      // edges per fillbin block
#define EPT (CHUNK / TPB)
#define CAP 9216        // bucket region capacity (mean 8192 + ~11 sigma)
#define RPT (CAP / TPB) // 36 register-cached words per k_sort thread
#define NWAVE (TPB / 64)
#define NSEG 32         // chunk segments for the 2-level offset scan

#if defined(__has_builtin)
#if __has_builtin(__builtin_amdgcn_make_buffer_rsrc) && \
    __has_builtin(__builtin_amdgcn_raw_buffer_load_b128)
#define HAVE_BUFLOAD 1
#endif
#endif

#ifdef HAVE_BUFLOAD
typedef unsigned int u32x4v __attribute__((ext_vector_type(4)));
typedef __amdgpu_buffer_rsrc_t rsrc_t;
__device__ __forceinline__ rsrc_t mkrs(const void* p, int bytes) {
    // stride=0 (raw), num_records=bytes, word3=0x00020000 (raw dword access)
    return __builtin_amdgcn_make_buffer_rsrc(const_cast<void*>(p),
                                             (short)0, bytes, 0x00020000);
}
// 16B gather with aux=1 (sc0/GLC): L2 read, no L1 allocation.
__device__ __forceinline__ uint4 g16(rsrc_t rs, const uint4* tbl, int idx) {
    u32x4v v = __builtin_amdgcn_raw_buffer_load_b128(rs, idx * 16, 0, 1);
    uint4 q;
    q.x = v.x; q.y = v.y; q.z = v.z; q.w = v.w;
    return q;
}
#else
typedef int rsrc_t;
__device__ __forceinline__ rsrc_t mkrs(const void* p, int bytes) { return 0; }
__device__ __forceinline__ uint4 g16(rsrc_t rs, const uint4* tbl, int idx) {
    return tbl[idx];
}
#endif

__device__ __forceinline__ unsigned short f2bf(float f) {
    unsigned u = __float_as_uint(f);
    unsigned r = (u + 0x7FFFu + ((u >> 16) & 1u)) >> 16;  // RNE
    return (unsigned short)r;
}
__device__ __forceinline__ unsigned pk2(float a, float b) {
    return (unsigned)f2bf(a) | ((unsigned)f2bf(b) << 16);
}
#define BFLO(u) __uint_as_float((u) << 16)
#define BFHI(u) __uint_as_float((u) & 0xFFFF0000u)

// per-chunk bucket histogram -> C[chunk][nb] (coalesced row store)
__global__ void __launch_bounds__(TPB) k_fb1(
        const int* __restrict__ dst, int* __restrict__ C, int e, int nb) {
    __shared__ int h[MAXB];
    int t = threadIdx.x;
    int c0 = blockIdx.x * CHUNK;
    int csize = min(e - c0, CHUNK);
#pragma unroll
    for (int k = 0; k < BPT; k++) h[t * BPT + k] = 0;
    __syncthreads();
    if (csize == CHUNK && ((((size_t)(const void*)(dst + c0)) & 15) == 0)) {
        const int4* d4 = (const int4*)(dst + c0);
#pragma unroll
        for (int k = 0; k < EPT / 4; k++) {
            int4 d = d4[t + k * TPB];
            atomicAdd(&h[d.x >> NBS], 1);
            atomicAdd(&h[d.y >> NBS], 1);
            atomicAdd(&h[d.z >> NBS], 1);
            atomicAdd(&h[d.w >> NBS], 1);
        }
    } else {
        for (int i = t; i < csize; i += TPB)
            atomicAdd(&h[dst[c0 + i] >> NBS], 1);
    }
    __syncthreads();
    int* row = C + (size_t)blockIdx.x * nb;
    for (int b = t; b < nb; b += TPB) row[b] = h[b];
}

// level-1: thread t serially scans bucket-column b over chunk segment s.
__global__ void __launch_bounds__(TPB) k_scan1(
        const int* __restrict__ C, int* __restrict__ O, int* __restrict__ Sseg,
        int nchunk, int nb, int cps, int ngrp) {
    int bid = blockIdx.x;
    int s = bid / ngrp, g = bid - s * ngrp;
    int b = g * TPB + threadIdx.x;
    if (b >= nb) return;
    int cbeg = s * cps;
    int cend = min(cbeg + cps, nchunk);
    int run = 0;
#pragma unroll 4
    for (int c = cbeg; c < cend; c++) {
        int v = C[(size_t)c * nb + b];
        O[(size_t)c * nb + b] = run;
        run += v;
    }
    Sseg[s * nb + b] = run;
}

// level-2: per bucket, exclusive scan of NSEG segment sums; fold in b*CAP.
__global__ void __launch_bounds__(TPB) k_scan2(
        const int* __restrict__ Sseg, int* __restrict__ segbase,
        int* __restrict__ btot, int nb) {
    int b = blockIdx.x * TPB + threadIdx.x;
    if (b >= nb) return;
    int run = b * CAP;
#pragma unroll
    for (int s = 0; s < NSEG; s++) {
        segbase[s * nb + b] = run;
        run += Sseg[s * nb + b];
    }
    btot[b] = run - b * CAP;
}

// bin edges into fixed-cap bucket regions. LDS counting sort of the chunk;
// deterministic delta from segbase+O (no atomics). word: ((d&255)<<18)|s
__global__ void __launch_bounds__(TPB) k_fillbin(
        const int* __restrict__ src, const int* __restrict__ dst,
        const int* __restrict__ O, const int* __restrict__ segbase,
        int* __restrict__ binned, int e, int nb, int cps) {
    __shared__ __align__(16) int stage[CHUNK];          // 16 KB, sorted words
    __shared__ __align__(16) unsigned short bs[CHUNK];  // 8 KB, bucket/slot
    __shared__ int h[MAXB];                 // 4 KB, hist -> stage cursor
    __shared__ int delta[MAXB];             // 4 KB
    __shared__ int wsum[NWAVE];
    int t = threadIdx.x;
    int c0 = blockIdx.x * CHUNK;
    int csize = min(e - c0, CHUNK);
#pragma unroll
    for (int k = 0; k < BPT; k++) h[t * BPT + k] = 0;
    __syncthreads();
    int dreg[EPT], sreg[EPT];
    if (csize == CHUNK && ((((size_t)(const void*)(dst + c0)) & 15) == 0)
                       && ((((size_t)(const void*)(src + c0)) & 15) == 0)) {
        const int4* d4 = (const int4*)(dst + c0);
        const int4* s4 = (const int4*)(src + c0);
#pragma unroll
        for (int k = 0; k < EPT / 4; k++) {
            int4 d = d4[t + k * TPB];
            int4 s = s4[t + k * TPB];
            dreg[4 * k + 0] = d.x; sreg[4 * k + 0] = s.x;
            dreg[4 * k + 1] = d.y; sreg[4 * k + 1] = s.y;
            dreg[4 * k + 2] = d.z; sreg[4 * k + 2] = s.z;
            dreg[4 * k + 3] = d.w; sreg[4 * k + 3] = s.w;
            atomicAdd(&h[d.x >> NBS], 1);
            atomicAdd(&h[d.y >> NBS], 1);
            atomicAdd(&h[d.z >> NBS], 1);
            atomicAdd(&h[d.w >> NBS], 1);
        }
    } else {
#pragma unroll
        for (int k = 0; k < EPT; k++) {
            int idx = t + k * TPB;
            int d = (idx < csize) ? dst[c0 + idx] : -1;
            int s = (idx < csize) ? src[c0 + idx] : 0;
            dreg[k] = d;
            sreg[k] = s;
            if (d >= 0) atomicAdd(&h[d >> NBS], 1);
        }
    }
    __syncthreads();
    // per-thread local prefix over its BPT bins
    int loc[BPT], hreg[BPT];
    int ts = 0;
#pragma unroll
    for (int k = 0; k < BPT; k++) {
        hreg[k] = h[t * BPT + k];
        loc[k] = ts;
        ts += hreg[k];
    }
    // block-wide inclusive scan of ts: wave shfl scan + wave-sum combine
    int lane = t & 63, wid = t >> 6;
    int v = ts;
#pragma unroll
    for (int off = 1; off < 64; off <<= 1) {
        int u = __shfl_up(v, off);
        if (lane >= off) v += u;
    }
    if (lane == 63) wsum[wid] = v;
    __syncthreads();
    int pre = 0;
#pragma unroll
    for (int wq = 0; wq < NWAVE - 1; wq++)
        if (wid > wq) pre += wsum[wq];
    int tbase = pre + v - ts;  // exclusive prefix for this thread's first bin
    // deterministic delta: global slot = segbase[s][b] + O[c][b] + rank
    const int* Orow = O + (size_t)blockIdx.x * nb;
    const int* segrow = segbase + (size_t)(blockIdx.x / cps) * nb;
#pragma unroll
    for (int k = 0; k < BPT; k++) {
        int b = t * BPT + k;
        int ex = tbase + loc[k];
        h[b] = ex;  // stage cursor
        delta[b] = (b < nb) ? (segrow[b] + Orow[b] - ex) : 0;
    }
    __syncthreads();
    // LDS counting sort of the chunk (registers -> LDS only)
#pragma unroll
    for (int k = 0; k < EPT; k++) {
        int d = dreg[k];
        if (d >= 0) {
            int b = d >> NBS;
            int r = atomicAdd(&h[b], 1);
            stage[r] = ((d & (NBKT - 1)) << 18) | sreg[k];
            bs[r] = (unsigned short)b;
        }
    }
    __syncthreads();
    // flush: vectorized LDS reads (int4 stage, ushort4 bs) full-chunk path
    if (csize == CHUNK) {
#pragma unroll
        for (int j = 0; j < CHUNK / (4 * TPB); j++) {
            int kb = 4 * t + j * 4 * TPB;
            int4 sv = *(const int4*)&stage[kb];
            ushort4 bv = *(const ushort4*)&bs[kb];
            binned[delta[bv.x] + kb + 0] = sv.x;
            binned[delta[bv.y] + kb + 1] = sv.y;
            binned[delta[bv.z] + kb + 2] = sv.z;
            binned[delta[bv.w] + kb + 3] = sv.w;
        }
    } else {
        for (int k = t; k < csize; k += TPB)
            binned[delta[bs[k]] + k] = stage[k];
    }
}

// full-bucket counting sort, register-cached (single region read via int4),
// LDS-staged dense csr flush (b128 reads + int4 stores).
__global__ void __launch_bounds__(TPB) k_sort(
        const int* __restrict__ binned, const int* __restrict__ btot,
        const float* __restrict__ x, int* __restrict__ csr,
        int* __restrict__ rowptr, int* __restrict__ rowend,
        float* __restrict__ dinv, uint4* __restrict__ xdq, int n) {
    __shared__ __align__(16) int stage[CAP];     // 36 KB
    __shared__ int cnt[NBKT];
    __shared__ int curs[NBKT];
    __shared__ int wsum[NWAVE];
    int b = blockIdx.x, t = threadIdx.x;
    int base = b * CAP;
    int c = btot[b];
    cnt[t] = 0;
    __syncthreads();
    // 1) read region once into registers (int4) + histogram
    int w[RPT];
#pragma unroll
    for (int k = 0; k < RPT / 4; k++) {
        int idx = 4 * t + k * 4 * TPB;
        int4 v;
        if (idx + 4 <= c) {
            v = *(const int4*)&binned[base + idx];
        } else {
            v.x = (idx + 0 < c) ? binned[base + idx + 0] : -1;
            v.y = (idx + 1 < c) ? binned[base + idx + 1] : -1;
            v.z = (idx + 2 < c) ? binned[base + idx + 2] : -1;
            v.w = (idx + 3 < c) ? binned[base + idx + 3] : -1;
        }
        w[4 * k + 0] = v.x; w[4 * k + 1] = v.y;
        w[4 * k + 2] = v.z; w[4 * k + 3] = v.w;
        if (v.x >= 0) atomicAdd(&cnt[v.x >> 18], 1);
        if (v.y >= 0) atomicAdd(&cnt[v.y >> 18], 1);
        if (v.z >= 0) atomicAdd(&cnt[v.z >> 18], 1);
        if (v.w >= 0) atomicAdd(&cnt[v.w >> 18], 1);
    }
    __syncthreads();
    // 2) exclusive scan of 256 bins: wave shfl scan + combine (1 barrier)
    int v = cnt[t];
    int lane = t & 63, wid = t >> 6;
    int iv = v;
#pragma unroll
    for (int off = 1; off < 64; off <<= 1) {
        int u = __shfl_up(iv, off);
        if (lane >= off) iv += u;
    }
    if (lane == 63) wsum[wid] = iv;
    __syncthreads();
    int pre = 0;
#pragma unroll
    for (int wq = 0; wq < NWAVE - 1; wq++)
        if (wid > wq) pre += wsum[wq];
    int ex = pre + iv - v;  // exclusive
    curs[t] = ex;
    // 3) per-node outputs
    int i = (b << NBS) + t;
    rowptr[i] = base + ex;
    rowend[i] = base + ex + v;
    if (i < n) {
        float di = rsqrtf((float)(v + 1));
        dinv[i] = di;
        uint4 q;
        q.x = pk2(x[i * 6 + 0] * di, x[i * 6 + 1] * di);
        q.y = pk2(x[i * 6 + 2] * di, x[i * 6 + 3] * di);
        q.z = pk2(x[i * 6 + 4] * di, x[i * 6 + 5] * di);
        q.w = 0;
        xdq[i] = q;
    }
    __syncthreads();
    // 4) scatter from registers into LDS stage (node-sorted order)
#pragma unroll
    for (int k = 0; k < RPT; k++) {
        if (w[k] >= 0) {
            int r = atomicAdd(&curs[w[k] >> 18], 1);
            stage[r] = w[k] & 0x3FFFF;
        }
    }
    __syncthreads();
    // 5) dense flush: b128 LDS reads + int4 global stores, scalar tail
    for (int kb = 4 * t; kb + 4 <= c; kb += 4 * TPB) {
        int4 sv = *(const int4*)&stage[kb];
        *(int4*)&csr[base + kb] = sv;
    }
    for (int k = (c & ~3) + t; k < c; k += TPB)
        csr[base + k] = stage[k];
}

// layer-1 gather (pre-W1 domain, bf16 payload): 16 lanes/node, 4 nodes/wave.
// neighbor payloads via sc0 buffer loads (L1 bypass).
// epilogue: agg6 (incl self) -> @W1 -> relu(di*.+b1) -> @W2 -> *di -> g2q (bf16)
__global__ void __launch_bounds__(TPB) k_gat1(
        const uint4* __restrict__ xdq, const int* __restrict__ csr,
        const int* __restrict__ rowptr, const int* __restrict__ rowend,
        const float* __restrict__ dinv,
        const float* __restrict__ b1, const float* __restrict__ W1,
        const float* __restrict__ W2, uint2* __restrict__ g2q, int n, int np) {
    __shared__ float w1[96];   // 6 x 16
    __shared__ float w2[128];  // 16 x 8
    __shared__ float bb[16];
    if (threadIdx.x < 96) w1[threadIdx.x] = W1[threadIdx.x];
    if (threadIdx.x < 128) w2[threadIdx.x] = W2[threadIdx.x];
    if (threadIdx.x < 16) bb[threadIdx.x] = b1[threadIdx.x];
    __syncthreads();
    rsrc_t rs = mkrs(xdq, np * 16);
    int sub = threadIdx.x & 15;                    // lane within node group
    int i = blockIdx.x * 16 + (threadIdx.x >> 4);  // 16 nodes per block
    bool valid = (i < n);
    int r0 = rowptr[i], r1 = rowend[i];            // padded nodes: r0 == r1
    float a0 = 0.f, a1 = 0.f, a2 = 0.f, a3 = 0.f, a4 = 0.f, a5 = 0.f;
    float c0 = 0.f, c1 = 0.f, c2 = 0.f, c3 = 0.f, c4 = 0.f, c5 = 0.f;
    if (valid && sub == 0) {  // self-loop term
        uint4 q = xdq[i];
        a0 += BFLO(q.x); a1 += BFHI(q.x);
        a2 += BFLO(q.y); a3 += BFHI(q.y);
        a4 += BFLO(q.z); a5 += BFHI(q.z);
    }
    int j = r0 + sub;
    while (j + 16 < r1) {
        uint4 q = g16(rs, xdq, csr[j]);
        uint4 p = g16(rs, xdq, csr[j + 16]);
        a0 += BFLO(q.x); a1 += BFHI(q.x);
        a2 += BFLO(q.y); a3 += BFHI(q.y);
        a4 += BFLO(q.z); a5 += BFHI(q.z);
        c0 += BFLO(p.x); c1 += BFHI(p.x);
        c2 += BFLO(p.y); c3 += BFHI(p.y);
        c4 += BFLO(p.z); c5 += BFHI(p.z);
        j += 32;
    }
    if (j < r1) {
        uint4 q = g16(rs, xdq, csr[j]);
        a0 += BFLO(q.x); a1 += BFHI(q.x);
        a2 += BFLO(q.y); a3 += BFHI(q.y);
        a4 += BFLO(q.z); a5 += BFHI(q.z);
    }
    a0 += c0; a1 += c1; a2 += c2; a3 += c3; a4 += c4; a5 += c5;
#pragma unroll
    for (int m = 1; m <= 8; m <<= 1) {  // reduce within 16-lane node group
        a0 += __shfl_xor(a0, m); a1 += __shfl_xor(a1, m);
        a2 += __shfl_xor(a2, m); a3 += __shfl_xor(a3, m);
        a4 += __shfl_xor(a4, m); a5 += __shfl_xor(a5, m);
    }
    float di = valid ? dinv[i] : 0.f;
    int f = sub;  // lane = hidden feature
    float hf = a0 * w1[f] + a1 * w1[16 + f] + a2 * w1[32 + f]
             + a3 * w1[48 + f] + a4 * w1[64 + f] + a5 * w1[80 + f];
    float tf = fmaxf(di * hf + bb[f], 0.0f);
    float p0 = tf * w2[f * 8 + 0], p1 = tf * w2[f * 8 + 1];
    float p2 = tf * w2[f * 8 + 2], p3 = tf * w2[f * 8 + 3];
    float p4 = tf * w2[f * 8 + 4], p5 = tf * w2[f * 8 + 5];
    float p6 = tf * w2[f * 8 + 6], p7 = tf * w2[f * 8 + 7];
#pragma unroll
    for (int m = 1; m <= 8; m <<= 1) {  // reduce over the 16 f-lanes
        p0 += __shfl_xor(p0, m); p1 += __shfl_xor(p1, m);
        p2 += __shfl_xor(p2, m); p3 += __shfl_xor(p3, m);
        p4 += __shfl_xor(p4, m); p5 += __shfl_xor(p5, m);
        p6 += __shfl_xor(p6, m); p7 += __shfl_xor(p7, m);
    }
    if (valid && sub < 2) {
        float q0 = sub ? p4 : p0, q1 = sub ? p5 : p1;
        float q2 = sub ? p6 : p2, q3 = sub ? p7 : p3;
        uint2 o;
        o.x = pk2(q0 * di, q1 * di);
        o.y = pk2(q2 * di, q3 * di);
        g2q[i * 2 + sub] = o;
    }
}

// layer-2 gather (bf16 payload): 16 lanes/node, 4 nodes/wave, sc0 gathers.
// fused head: h = relu(dinv*agg8 + b2); out = sigmoid(h @ Wfc + bfc)
__global__ void __launch_bounds__(TPB) k_gat2(
        const uint4* __restrict__ g2q, const int* __restrict__ csr,
        const int* __restrict__ rowptr, const int* __restrict__ rowend,
        const float* __restrict__ dinv,
        const float* __restrict__ b2, const float* __restrict__ Wfc,
        const float* __restrict__ bfc, float* __restrict__ out, int n, int np) {
    __shared__ float w[8];
    __shared__ float bb[8];
    __shared__ float bf;
    if (threadIdx.x < 8) { w[threadIdx.x] = Wfc[threadIdx.x]; bb[threadIdx.x] = b2[threadIdx.x]; }
    if (threadIdx.x == 0) bf = bfc[0];
    __syncthreads();
    rsrc_t rs = mkrs(g2q, np * 16);
    int sub = threadIdx.x & 15;
    int i = blockIdx.x * 16 + (threadIdx.x >> 4);
    bool valid = (i < n);
    int r0 = rowptr[i], r1 = rowend[i];
    float a0 = 0.f, a1 = 0.f, a2 = 0.f, a3 = 0.f;
    float a4 = 0.f, a5 = 0.f, a6 = 0.f, a7 = 0.f;
    if (valid && sub == 0) {  // self-loop term
        uint4 q = g2q[i];
        a0 += BFLO(q.x); a1 += BFHI(q.x); a2 += BFLO(q.y); a3 += BFHI(q.y);
        a4 += BFLO(q.z); a5 += BFHI(q.z); a6 += BFLO(q.w); a7 += BFHI(q.w);
    }
    float c0 = 0.f, c1 = 0.f, c2 = 0.f, c3 = 0.f;
    float c4 = 0.f, c5 = 0.f, c6 = 0.f, c7 = 0.f;
    int j = r0 + sub;
    while (j + 16 < r1) {
        uint4 q = g16(rs, g2q, csr[j]);
        uint4 p = g16(rs, g2q, csr[j + 16]);
        a0 += BFLO(q.x); a1 += BFHI(q.x); a2 += BFLO(q.y); a3 += BFHI(q.y);
        a4 += BFLO(q.z); a5 += BFHI(q.z); a6 += BFLO(q.w); a7 += BFHI(q.w);
        c0 += BFLO(p.x); c1 += BFHI(p.x); c2 += BFLO(p.y); c3 += BFHI(p.y);
        c4 += BFLO(p.z); c5 += BFHI(p.z); c6 += BFLO(p.w); c7 += BFHI(p.w);
        j += 32;
    }
    if (j < r1) {
        uint4 q = g16(rs, g2q, csr[j]);
        a0 += BFLO(q.x); a1 += BFHI(q.x); a2 += BFLO(q.y); a3 += BFHI(q.y);
        a4 += BFLO(q.z); a5 += BFHI(q.z); a6 += BFLO(q.w); a7 += BFHI(q.w);
    }
    a0 += c0; a1 += c1; a2 += c2; a3 += c3;
    a4 += c4; a5 += c5; a6 += c6; a7 += c7;
#pragma unroll
    for (int m = 1; m <= 8; m <<= 1) {  // reduce within 16-lane node group
        a0 += __shfl_xor(a0, m); a1 += __shfl_xor(a1, m);
        a2 += __shfl_xor(a2, m); a3 += __shfl_xor(a3, m);
        a4 += __shfl_xor(a4, m); a5 += __shfl_xor(a5, m);
        a6 += __shfl_xor(a6, m); a7 += __shfl_xor(a7, m);
    }
    if (valid && sub == 0) {  // head computed once per node (cheap, no shfl)
        float di = dinv[i];
        float o = bf;
        o += fmaxf(di * a0 + bb[0], 0.0f) * w[0];
        o += fmaxf(di * a1 + bb[1], 0.0f) * w[1];
        o += fmaxf(di * a2 + bb[2], 0.0f) * w[2];
        o += fmaxf(di * a3 + bb[3], 0.0f) * w[3];
        o += fmaxf(di * a4 + bb[4], 0.0f) * w[4];
        o += fmaxf(di * a5 + bb[5], 0.0f) * w[5];
        o += fmaxf(di * a6 + bb[6], 0.0f) * w[6];
        o += fmaxf(di * a7 + bb[7], 0.0f) * w[7];
        out[i] = 1.0f / (1.0f + expf(-o));
    }
}

extern "C" void kernel_launch(void* const* d_in, const int* in_sizes, int n_in,
                              void* d_out, int out_size, void* d_ws, size_t ws_size,
                              hipStream_t stream) {
    const float* x   = (const float*)d_in[0];
    const int*   ei  = (const int*)d_in[1];
    const float* W1  = (const float*)d_in[2];
    const float* b1  = (const float*)d_in[3];
    const float* W2  = (const float*)d_in[4];
    const float* b2  = (const float*)d_in[5];
    const float* Wfc = (const float*)d_in[6];
    const float* bfc = (const float*)d_in[7];
    float* out = (float*)d_out;

    const int n = in_sizes[0] / 6;   // 200000 (<= 262144 for 18-bit packing)
    const int e = in_sizes[1] / 2;   // 6400000
    const int* src = ei;
    const int* dst = ei + e;
    const int nb = (n + NBKT - 1) >> NBS;  // 782
    const size_t np = (size_t)nb << NBS;   // padded node count (200192)
    const int nblk = (e + CHUNK - 1) / CHUNK;  // 1563 chunks
    const int cps = (nblk + NSEG - 1) / NSEG;  // chunks per segment (49)
    const int ngrp = (nb + TPB - 1) / TPB;     // bucket groups (4)
    const size_t reg = (size_t)nb * CAP;   // bucket-region total (7.2M words)

    int* C       = (int*)d_ws;                 // nblk * nb
    int* O       = C + (size_t)nblk * nb;      // nblk * nb
    int* Sseg    = O + (size_t)nblk * nb;      // NSEG * MAXB
    int* segbase = Sseg + (size_t)NSEG * MAXB; // NSEG * MAXB
    int* btot    = segbase + (size_t)NSEG * MAXB; // MAXB
    int* binned  = btot + MAXB;                // reg
    int* csr     = binned + reg;               // reg
    int* rowptr  = csr + reg;                  // np
    int* rowend  = rowptr + np;                // np
    float* dinv  = (float*)(rowend + np);      // np
    size_t off   = (size_t)((int*)(dinv + np) - (int*)d_ws);
    off = (off + 3) & ~(size_t)3;              // 16B-align the uint4 arrays
    uint4* xdq   = (uint4*)((int*)d_ws + off); // np * 16 B
    uint2* g2q   = (uint2*)(xdq + np);         // np * 16 B

    int gw = (n + 15) / 16;              // node-group blocks (16 nodes/block)

    k_fb1<<<nblk, TPB, 0, stream>>>(dst, C, e, nb);
    k_scan1<<<NSEG * ngrp, TPB, 0, stream>>>(C, O, Sseg, nblk, nb, cps, ngrp);
    k_scan2<<<ngrp, TPB, 0, stream>>>(Sseg, segbase, btot, nb);
    k_fillbin<<<nblk, TPB, 0, stream>>>(src, dst, O, segbase, binned, e, nb, cps);
    k_sort<<<nb, TPB, 0, stream>>>(binned, btot, x, csr, rowptr, rowend, dinv, xdq, n);
    k_gat1<<<gw, TPB, 0, stream>>>(xdq, csr, rowptr, rowend, dinv, b1, W1, W2,
                                   (uint2*)g2q, n, (int)np);
    k_gat2<<<gw, TPB, 0, stream>>>((const uint4*)g2q, csr, rowptr, rowend, dinv,
                                   b2, Wfc, bfc, out, n, (int)np);
}

// Round 12
// 231.259 us; speedup vs baseline: 4.2493x; 1.0444x over previous
//
#include <hip/hip_runtime.h>
#include <math.h>

// GCN 2-layer + sigmoid head. CSR pull-gather, zero fp32 atomics.
// R26: attack fillbin's scattered partial-line segment writes (1.6TB/s,
//  WRITE 58MB for 25.6 logical). CHUNK 4096->8192 doubles per-(chunk,bucket)
//  segment length (21B->42B) and halves C/O. bs[] deleted (16KB LDS + 1 LDS
//  write/edge): per-bucket flush — thread t owns buckets [4t,4t+4); after
//  scatter h[b] = bucket end cursor, so t's stage range is contiguous and
//  delta lives in registers. LDS 36.9KB -> 4 blk/CU.
//  Gather lessons (R19..R25b): k_gat1 pinned at ~50us across 6 variants ->
//  per-CU random-gather request-rate floor (~4.8cy/req, MSHR-throughput).
//  sc0 L1-bypass kept (+2us). No nt stores (R22). No global deg atomics (R21).
//   k_fb1:   per-chunk bucket histogram -> C[chunk][nb]
//   k_scan1/2: 2-level deterministic offset scan (coalesced, no barriers)
//   k_fillbin: LDS chunk counting-sort -> binned (deterministic, no atomics)
//   k_sort:  bucket counting sort -> dense csr, rowptr/rowend, dinv, xdq
//   k_gat1/2: node-group gathers (16 lanes/node, sc0 L1-bypass payloads)

#define TPB 256
#define NBS 8
#define NBKT 256        // nodes per bucket
#define MAXB 1024       // max buckets (n <= 262144)
#define BPT (MAXB / TPB)
#define CHUNK 8192      // edges per fillbin block (42B avg segments)
#define EPT (CHUNK / TPB)
#define CAP 9216        // bucket region capacity (mean 8192 + ~11 sigma)
#define RPT (CAP / TPB) // 36 register-cached words per k_sort thread
#define NWAVE (TPB / 64)
#define NSEG 32         // chunk segments for the 2-level offset scan

#if defined(__has_builtin)
#if __has_builtin(__builtin_amdgcn_make_buffer_rsrc) && \
    __has_builtin(__builtin_amdgcn_raw_buffer_load_b128)
#define HAVE_BUFLOAD 1
#endif
#endif

#ifdef HAVE_BUFLOAD
typedef unsigned int u32x4v __attribute__((ext_vector_type(4)));
typedef __amdgpu_buffer_rsrc_t rsrc_t;
__device__ __forceinline__ rsrc_t mkrs(const void* p, int bytes) {
    return __builtin_amdgcn_make_buffer_rsrc(const_cast<void*>(p),
                                             (short)0, bytes, 0x00020000);
}
__device__ __forceinline__ uint4 g16(rsrc_t rs, const uint4* tbl, int idx) {
    u32x4v v = __builtin_amdgcn_raw_buffer_load_b128(rs, idx * 16, 0, 1);
    uint4 q;
    q.x = v.x; q.y = v.y; q.z = v.z; q.w = v.w;
    return q;
}
#else
typedef int rsrc_t;
__device__ __forceinline__ rsrc_t mkrs(const void* p, int bytes) { return 0; }
__device__ __forceinline__ uint4 g16(rsrc_t rs, const uint4* tbl, int idx) {
    return tbl[idx];
}
#endif

__device__ __forceinline__ unsigned short f2bf(float f) {
    unsigned u = __float_as_uint(f);
    unsigned r = (u + 0x7FFFu + ((u >> 16) & 1u)) >> 16;  // RNE
    return (unsigned short)r;
}
__device__ __forceinline__ unsigned pk2(float a, float b) {
    return (unsigned)f2bf(a) | ((unsigned)f2bf(b) << 16);
}
#define BFLO(u) __uint_as_float((u) << 16)
#define BFHI(u) __uint_as_float((u) & 0xFFFF0000u)

// per-chunk bucket histogram -> C[chunk][nb] (coalesced row store)
__global__ void __launch_bounds__(TPB) k_fb1(
        const int* __restrict__ dst, int* __restrict__ C, int e, int nb) {
    __shared__ int h[MAXB];
    int t = threadIdx.x;
    int c0 = blockIdx.x * CHUNK;
    int csize = min(e - c0, CHUNK);
#pragma unroll
    for (int k = 0; k < BPT; k++) h[t * BPT + k] = 0;
    __syncthreads();
    if (csize == CHUNK && ((((size_t)(const void*)(dst + c0)) & 15) == 0)) {
        const int4* d4 = (const int4*)(dst + c0);
#pragma unroll
        for (int k = 0; k < EPT / 4; k++) {
            int4 d = d4[t + k * TPB];
            atomicAdd(&h[d.x >> NBS], 1);
            atomicAdd(&h[d.y >> NBS], 1);
            atomicAdd(&h[d.z >> NBS], 1);
            atomicAdd(&h[d.w >> NBS], 1);
        }
    } else {
        for (int i = t; i < csize; i += TPB)
            atomicAdd(&h[dst[c0 + i] >> NBS], 1);
    }
    __syncthreads();
    int* row = C + (size_t)blockIdx.x * nb;
    for (int b = t; b < nb; b += TPB) row[b] = h[b];
}

// level-1: thread t serially scans bucket-column b over chunk segment s.
__global__ void __launch_bounds__(TPB) k_scan1(
        const int* __restrict__ C, int* __restrict__ O, int* __restrict__ Sseg,
        int nchunk, int nb, int cps, int ngrp) {
    int bid = blockIdx.x;
    int s = bid / ngrp, g = bid - s * ngrp;
    int b = g * TPB + threadIdx.x;
    if (b >= nb) return;
    int cbeg = s * cps;
    int cend = min(cbeg + cps, nchunk);
    int run = 0;
#pragma unroll 4
    for (int c = cbeg; c < cend; c++) {
        int v = C[(size_t)c * nb + b];
        O[(size_t)c * nb + b] = run;
        run += v;
    }
    Sseg[s * nb + b] = run;
}

// level-2: per bucket, exclusive scan of NSEG segment sums; fold in b*CAP.
__global__ void __launch_bounds__(TPB) k_scan2(
        const int* __restrict__ Sseg, int* __restrict__ segbase,
        int* __restrict__ btot, int nb) {
    int b = blockIdx.x * TPB + threadIdx.x;
    if (b >= nb) return;
    int run = b * CAP;
#pragma unroll
    for (int s = 0; s < NSEG; s++) {
        segbase[s * nb + b] = run;
        run += Sseg[s * nb + b];
    }
    btot[b] = run - b * CAP;
}

// bin edges into fixed-cap bucket regions. LDS counting sort of the chunk;
// deterministic delta from segbase+O (no atomics); per-bucket register-delta
// flush (no bs[] array). word: ((d&255)<<18)|s
__global__ void __launch_bounds__(TPB) k_fillbin(
        const int* __restrict__ src, const int* __restrict__ dst,
        const int* __restrict__ O, const int* __restrict__ segbase,
        int* __restrict__ binned, int e, int nb, int cps) {
    __shared__ __align__(16) int stage[CHUNK];  // 32 KB, bucket-sorted words
    __shared__ int h[MAXB];                     // 4 KB, hist -> cursor -> end
    __shared__ int wsum[NWAVE];
    int t = threadIdx.x;
    int c0 = blockIdx.x * CHUNK;
    int csize = min(e - c0, CHUNK);
#pragma unroll
    for (int k = 0; k < BPT; k++) h[t * BPT + k] = 0;
    __syncthreads();
    int dreg[EPT], sreg[EPT];
    if (csize == CHUNK && ((((size_t)(const void*)(dst + c0)) & 15) == 0)
                       && ((((size_t)(const void*)(src + c0)) & 15) == 0)) {
        const int4* d4 = (const int4*)(dst + c0);
        const int4* s4 = (const int4*)(src + c0);
#pragma unroll
        for (int k = 0; k < EPT / 4; k++) {
            int4 d = d4[t + k * TPB];
            int4 s = s4[t + k * TPB];
            dreg[4 * k + 0] = d.x; sreg[4 * k + 0] = s.x;
            dreg[4 * k + 1] = d.y; sreg[4 * k + 1] = s.y;
            dreg[4 * k + 2] = d.z; sreg[4 * k + 2] = s.z;
            dreg[4 * k + 3] = d.w; sreg[4 * k + 3] = s.w;
            atomicAdd(&h[d.x >> NBS], 1);
            atomicAdd(&h[d.y >> NBS], 1);
            atomicAdd(&h[d.z >> NBS], 1);
            atomicAdd(&h[d.w >> NBS], 1);
        }
    } else {
#pragma unroll
        for (int k = 0; k < EPT; k++) {
            int idx = t + k * TPB;
            int d = (idx < csize) ? dst[c0 + idx] : -1;
            int s = (idx < csize) ? src[c0 + idx] : 0;
            dreg[k] = d;
            sreg[k] = s;
            if (d >= 0) atomicAdd(&h[d >> NBS], 1);
        }
    }
    __syncthreads();
    // per-thread local prefix over its BPT bins
    int loc[BPT], hreg[BPT];
    int ts = 0;
#pragma unroll
    for (int k = 0; k < BPT; k++) {
        hreg[k] = h[t * BPT + k];
        loc[k] = ts;
        ts += hreg[k];
    }
    // block-wide inclusive scan of ts: wave shfl scan + wave-sum combine
    int lane = t & 63, wid = t >> 6;
    int v = ts;
#pragma unroll
    for (int off = 1; off < 64; off <<= 1) {
        int u = __shfl_up(v, off);
        if (lane >= off) v += u;
    }
    if (lane == 63) wsum[wid] = v;
    __syncthreads();
    int pre = 0;
#pragma unroll
    for (int wq = 0; wq < NWAVE - 1; wq++)
        if (wid > wq) pre += wsum[wq];
    int tbase = pre + v - ts;  // exclusive prefix for this thread's first bin
    // deterministic delta (registers; same buckets this thread flushes):
    // global slot = segbase[s][b] + O[c][b] + rank
    const int* Orow = O + (size_t)blockIdx.x * nb;
    const int* segrow = segbase + (size_t)(blockIdx.x / cps) * nb;
    int myd[BPT];
#pragma unroll
    for (int k = 0; k < BPT; k++) {
        int b = t * BPT + k;
        int ex = tbase + loc[k];
        h[b] = ex;  // stage cursor (published at next barrier)
        myd[k] = (b < nb) ? (segrow[b] + Orow[b] - ex) : 0;
    }
    __syncthreads();
    // LDS counting sort of the chunk (registers -> LDS only)
#pragma unroll
    for (int k = 0; k < EPT; k++) {
        int d = dreg[k];
        if (d >= 0) {
            int b = d >> NBS;
            int r = atomicAdd(&h[b], 1);
            stage[r] = ((d & (NBKT - 1)) << 18) | sreg[k];
        }
    }
    __syncthreads();
    // per-bucket flush: h[b] is now bucket b's END cursor; thread t's buckets
    // [4t,4t+4) occupy one contiguous stage range; delta from registers.
    int bfirst = t * BPT;
    int s0 = (bfirst == 0) ? 0 : h[bfirst - 1];
#pragma unroll
    for (int k2 = 0; k2 < BPT; k2++) {
        int s1 = h[bfirst + k2];
        int d = myd[k2];
        for (int k = s0; k < s1; k++)
            binned[d + k] = stage[k];
        s0 = s1;
    }
}

// full-bucket counting sort, register-cached (single region read via int4),
// LDS-staged dense csr flush (b128 reads + int4 stores).
__global__ void __launch_bounds__(TPB) k_sort(
        const int* __restrict__ binned, const int* __restrict__ btot,
        const float* __restrict__ x, int* __restrict__ csr,
        int* __restrict__ rowptr, int* __restrict__ rowend,
        float* __restrict__ dinv, uint4* __restrict__ xdq, int n) {
    __shared__ __align__(16) int stage[CAP];     // 36 KB
    __shared__ int cnt[NBKT];
    __shared__ int curs[NBKT];
    __shared__ int wsum[NWAVE];
    int b = blockIdx.x, t = threadIdx.x;
    int base = b * CAP;
    int c = btot[b];
    cnt[t] = 0;
    __syncthreads();
    // 1) read region once into registers (int4) + histogram
    int w[RPT];
#pragma unroll
    for (int k = 0; k < RPT / 4; k++) {
        int idx = 4 * t + k * 4 * TPB;
        int4 v;
        if (idx + 4 <= c) {
            v = *(const int4*)&binned[base + idx];
        } else {
            v.x = (idx + 0 < c) ? binned[base + idx + 0] : -1;
            v.y = (idx + 1 < c) ? binned[base + idx + 1] : -1;
            v.z = (idx + 2 < c) ? binned[base + idx + 2] : -1;
            v.w = (idx + 3 < c) ? binned[base + idx + 3] : -1;
        }
        w[4 * k + 0] = v.x; w[4 * k + 1] = v.y;
        w[4 * k + 2] = v.z; w[4 * k + 3] = v.w;
        if (v.x >= 0) atomicAdd(&cnt[v.x >> 18], 1);
        if (v.y >= 0) atomicAdd(&cnt[v.y >> 18], 1);
        if (v.z >= 0) atomicAdd(&cnt[v.z >> 18], 1);
        if (v.w >= 0) atomicAdd(&cnt[v.w >> 18], 1);
    }
    __syncthreads();
    // 2) exclusive scan of 256 bins: wave shfl scan + combine (1 barrier)
    int v = cnt[t];
    int lane = t & 63, wid = t >> 6;
    int iv = v;
#pragma unroll
    for (int off = 1; off < 64; off <<= 1) {
        int u = __shfl_up(iv, off);
        if (lane >= off) iv += u;
    }
    if (lane == 63) wsum[wid] = iv;
    __syncthreads();
    int pre = 0;
#pragma unroll
    for (int wq = 0; wq < NWAVE - 1; wq++)
        if (wid > wq) pre += wsum[wq];
    int ex = pre + iv - v;  // exclusive
    curs[t] = ex;
    // 3) per-node outputs
    int i = (b << NBS) + t;
    rowptr[i] = base + ex;
    rowend[i] = base + ex + v;
    if (i < n) {
        float di = rsqrtf((float)(v + 1));
        dinv[i] = di;
        uint4 q;
        q.x = pk2(x[i * 6 + 0] * di, x[i * 6 + 1] * di);
        q.y = pk2(x[i * 6 + 2] * di, x[i * 6 + 3] * di);
        q.z = pk2(x[i * 6 + 4] * di, x[i * 6 + 5] * di);
        q.w = 0;
        xdq[i] = q;
    }
    __syncthreads();
    // 4) scatter from registers into LDS stage (node-sorted order)
#pragma unroll
    for (int k = 0; k < RPT; k++) {
        if (w[k] >= 0) {
            int r = atomicAdd(&curs[w[k] >> 18], 1);
            stage[r] = w[k] & 0x3FFFF;
        }
    }
    __syncthreads();
    // 5) dense flush: b128 LDS reads + int4 global stores, scalar tail
    for (int kb = 4 * t; kb + 4 <= c; kb += 4 * TPB) {
        int4 sv = *(const int4*)&stage[kb];
        *(int4*)&csr[base + kb] = sv;
    }
    for (int k = (c & ~3) + t; k < c; k += TPB)
        csr[base + k] = stage[k];
}

// layer-1 gather (pre-W1 domain, bf16 payload): 16 lanes/node, 4 nodes/wave.
// neighbor payloads via sc0 buffer loads (L1 bypass).
// epilogue: agg6 (incl self) -> @W1 -> relu(di*.+b1) -> @W2 -> *di -> g2q (bf16)
__global__ void __launch_bounds__(TPB) k_gat1(
        const uint4* __restrict__ xdq, const int* __restrict__ csr,
        const int* __restrict__ rowptr, const int* __restrict__ rowend,
        const float* __restrict__ dinv,
        const float* __restrict__ b1, const float* __restrict__ W1,
        const float* __restrict__ W2, uint2* __restrict__ g2q, int n, int np) {
    __shared__ float w1[96];   // 6 x 16
    __shared__ float w2[128];  // 16 x 8
    __shared__ float bb[16];
    if (threadIdx.x < 96) w1[threadIdx.x] = W1[threadIdx.x];
    if (threadIdx.x < 128) w2[threadIdx.x] = W2[threadIdx.x];
    if (threadIdx.x < 16) bb[threadIdx.x] = b1[threadIdx.x];
    __syncthreads();
    rsrc_t rs = mkrs(xdq, np * 16);
    int sub = threadIdx.x & 15;                    // lane within node group
    int i = blockIdx.x * 16 + (threadIdx.x >> 4);  // 16 nodes per block
    bool valid = (i < n);
    int r0 = rowptr[i], r1 = rowend[i];            // padded nodes: r0 == r1
    float a0 = 0.f, a1 = 0.f, a2 = 0.f, a3 = 0.f, a4 = 0.f, a5 = 0.f;
    float c0 = 0.f, c1 = 0.f, c2 = 0.f, c3 = 0.f, c4 = 0.f, c5 = 0.f;
    if (valid && sub == 0) {  // self-loop term
        uint4 q = xdq[i];
        a0 += BFLO(q.x); a1 += BFHI(q.x);
        a2 += BFLO(q.y); a3 += BFHI(q.y);
        a4 += BFLO(q.z); a5 += BFHI(q.z);
    }
    int j = r0 + sub;
    while (j + 16 < r1) {
        uint4 q = g16(rs, xdq, csr[j]);
        uint4 p = g16(rs, xdq, csr[j + 16]);
        a0 += BFLO(q.x); a1 += BFHI(q.x);
        a2 += BFLO(q.y); a3 += BFHI(q.y);
        a4 += BFLO(q.z); a5 += BFHI(q.z);
        c0 += BFLO(p.x); c1 += BFHI(p.x);
        c2 += BFLO(p.y); c3 += BFHI(p.y);
        c4 += BFLO(p.z); c5 += BFHI(p.z);
        j += 32;
    }
    if (j < r1) {
        uint4 q = g16(rs, xdq, csr[j]);
        a0 += BFLO(q.x); a1 += BFHI(q.x);
        a2 += BFLO(q.y); a3 += BFHI(q.y);
        a4 += BFLO(q.z); a5 += BFHI(q.z);
    }
    a0 += c0; a1 += c1; a2 += c2; a3 += c3; a4 += c4; a5 += c5;
#pragma unroll
    for (int m = 1; m <= 8; m <<= 1) {  // reduce within 16-lane node group
        a0 += __shfl_xor(a0, m); a1 += __shfl_xor(a1, m);
        a2 += __shfl_xor(a2, m); a3 += __shfl_xor(a3, m);
        a4 += __shfl_xor(a4, m); a5 += __shfl_xor(a5, m);
    }
    float di = valid ? dinv[i] : 0.f;
    int f = sub;  // lane = hidden feature
    float hf = a0 * w1[f] + a1 * w1[16 + f] + a2 * w1[32 + f]
             + a3 * w1[48 + f] + a4 * w1[64 + f] + a5 * w1[80 + f];
    float tf = fmaxf(di * hf + bb[f], 0.0f);
    float p0 = tf * w2[f * 8 + 0], p1 = tf * w2[f * 8 + 1];
    float p2 = tf * w2[f * 8 + 2], p3 = tf * w2[f * 8 + 3];
    float p4 = tf * w2[f * 8 + 4], p5 = tf * w2[f * 8 + 5];
    float p6 = tf * w2[f * 8 + 6], p7 = tf * w2[f * 8 + 7];
#pragma unroll
    for (int m = 1; m <= 8; m <<= 1) {  // reduce over the 16 f-lanes
        p0 += __shfl_xor(p0, m); p1 += __shfl_xor(p1, m);
        p2 += __shfl_xor(p2, m); p3 += __shfl_xor(p3, m);
        p4 += __shfl_xor(p4, m); p5 += __shfl_xor(p5, m);
        p6 += __shfl_xor(p6, m); p7 += __shfl_xor(p7, m);
    }
    if (valid && sub < 2) {
        float q0 = sub ? p4 : p0, q1 = sub ? p5 : p1;
        float q2 = sub ? p6 : p2, q3 = sub ? p7 : p3;
        uint2 o;
        o.x = pk2(q0 * di, q1 * di);
        o.y = pk2(q2 * di, q3 * di);
        g2q[i * 2 + sub] = o;
    }
}

// layer-2 gather (bf16 payload): 16 lanes/node, 4 nodes/wave, sc0 gathers.
// fused head: h = relu(dinv*agg8 + b2); out = sigmoid(h @ Wfc + bfc)
__global__ void __launch_bounds__(TPB) k_gat2(
        const uint4* __restrict__ g2q, const int* __restrict__ csr,
        const int* __restrict__ rowptr, const int* __restrict__ rowend,
        const float* __restrict__ dinv,
        const float* __restrict__ b2, const float* __restrict__ Wfc,
        const float* __restrict__ bfc, float* __restrict__ out, int n, int np) {
    __shared__ float w[8];
    __shared__ float bb[8];
    __shared__ float bf;
    if (threadIdx.x < 8) { w[threadIdx.x] = Wfc[threadIdx.x]; bb[threadIdx.x] = b2[threadIdx.x]; }
    if (threadIdx.x == 0) bf = bfc[0];
    __syncthreads();
    rsrc_t rs = mkrs(g2q, np * 16);
    int sub = threadIdx.x & 15;
    int i = blockIdx.x * 16 + (threadIdx.x >> 4);
    bool valid = (i < n);
    int r0 = rowptr[i], r1 = rowend[i];
    float a0 = 0.f, a1 = 0.f, a2 = 0.f, a3 = 0.f;
    float a4 = 0.f, a5 = 0.f, a6 = 0.f, a7 = 0.f;
    if (valid && sub == 0) {  // self-loop term
        uint4 q = g2q[i];
        a0 += BFLO(q.x); a1 += BFHI(q.x); a2 += BFLO(q.y); a3 += BFHI(q.y);
        a4 += BFLO(q.z); a5 += BFHI(q.z); a6 += BFLO(q.w); a7 += BFHI(q.w);
    }
    float c0 = 0.f, c1 = 0.f, c2 = 0.f, c3 = 0.f;
    float c4 = 0.f, c5 = 0.f, c6 = 0.f, c7 = 0.f;
    int j = r0 + sub;
    while (j + 16 < r1) {
        uint4 q = g16(rs, g2q, csr[j]);
        uint4 p = g16(rs, g2q, csr[j + 16]);
        a0 += BFLO(q.x); a1 += BFHI(q.x); a2 += BFLO(q.y); a3 += BFHI(q.y);
        a4 += BFLO(q.z); a5 += BFHI(q.z); a6 += BFLO(q.w); a7 += BFHI(q.w);
        c0 += BFLO(p.x); c1 += BFHI(p.x); c2 += BFLO(p.y); c3 += BFHI(p.y);
        c4 += BFLO(p.z); c5 += BFHI(p.z); c6 += BFLO(p.w); c7 += BFHI(p.w);
        j += 32;
    }
    if (j < r1) {
        uint4 q = g16(rs, g2q, csr[j]);
        a0 += BFLO(q.x); a1 += BFHI(q.x); a2 += BFLO(q.y); a3 += BFHI(q.y);
        a4 += BFLO(q.z); a5 += BFHI(q.z); a6 += BFLO(q.w); a7 += BFHI(q.w);
    }
    a0 += c0; a1 += c1; a2 += c2; a3 += c3;
    a4 += c4; a5 += c5; a6 += c6; a7 += c7;
#pragma unroll
    for (int m = 1; m <= 8; m <<= 1) {  // reduce within 16-lane node group
        a0 += __shfl_xor(a0, m); a1 += __shfl_xor(a1, m);
        a2 += __shfl_xor(a2, m); a3 += __shfl_xor(a3, m);
        a4 += __shfl_xor(a4, m); a5 += __shfl_xor(a5, m);
        a6 += __shfl_xor(a6, m); a7 += __shfl_xor(a7, m);
    }
    if (valid && sub == 0) {  // head computed once per node (cheap, no shfl)
        float di = dinv[i];
        float o = bf;
        o += fmaxf(di * a0 + bb[0], 0.0f) * w[0];
        o += fmaxf(di * a1 + bb[1], 0.0f) * w[1];
        o += fmaxf(di * a2 + bb[2], 0.0f) * w[2];
        o += fmaxf(di * a3 + bb[3], 0.0f) * w[3];
        o += fmaxf(di * a4 + bb[4], 0.0f) * w[4];
        o += fmaxf(di * a5 + bb[5], 0.0f) * w[5];
        o += fmaxf(di * a6 + bb[6], 0.0f) * w[6];
        o += fmaxf(di * a7 + bb[7], 0.0f) * w[7];
        out[i] = 1.0f / (1.0f + expf(-o));
    }
}

extern "C" void kernel_launch(void* const* d_in, const int* in_sizes, int n_in,
                              void* d_out, int out_size, void* d_ws, size_t ws_size,
                              hipStream_t stream) {
    const float* x   = (const float*)d_in[0];
    const int*   ei  = (const int*)d_in[1];
    const float* W1  = (const float*)d_in[2];
    const float* b1  = (const float*)d_in[3];
    const float* W2  = (const float*)d_in[4];
    const float* b2  = (const float*)d_in[5];
    const float* Wfc = (const float*)d_in[6];
    const float* bfc = (const float*)d_in[7];
    float* out = (float*)d_out;

    const int n = in_sizes[0] / 6;   // 200000 (<= 262144 for 18-bit packing)
    const int e = in_sizes[1] / 2;   // 6400000
    const int* src = ei;
    const int* dst = ei + e;
    const int nb = (n + NBKT - 1) >> NBS;  // 782
    const size_t np = (size_t)nb << NBS;   // padded node count (200192)
    const int nblk = (e + CHUNK - 1) / CHUNK;  // 782 chunks
    const int cps = (nblk + NSEG - 1) / NSEG;  // chunks per segment (25)
    const int ngrp = (nb + TPB - 1) / TPB;     // bucket groups (4)
    const size_t reg = (size_t)nb * CAP;   // bucket-region total (7.2M words)

    int* C       = (int*)d_ws;                 // nblk * nb
    int* O       = C + (size_t)nblk * nb;      // nblk * nb
    int* Sseg    = O + (size_t)nblk * nb;      // NSEG * MAXB
    int* segbase = Sseg + (size_t)NSEG * MAXB; // NSEG * MAXB
    int* btot    = segbase + (size_t)NSEG * MAXB; // MAXB
    int* binned  = btot + MAXB;                // reg
    int* csr     = binned + reg;               // reg
    int* rowptr  = csr + reg;                  // np
    int* rowend  = rowptr + np;                // np
    float* dinv  = (float*)(rowend + np);      // np
    size_t off   = (size_t)((int*)(dinv + np) - (int*)d_ws);
    off = (off + 3) & ~(size_t)3;              // 16B-align the uint4 arrays
    uint4* xdq   = (uint4*)((int*)d_ws + off); // np * 16 B
    uint2* g2q   = (uint2*)(xdq + np);         // np * 16 B

    int gw = (n + 15) / 16;              // node-group blocks (16 nodes/block)

    k_fb1<<<nblk, TPB, 0, stream>>>(dst, C, e, nb);
    k_scan1<<<NSEG * ngrp, TPB, 0, stream>>>(C, O, Sseg, nblk, nb, cps, ngrp);
    k_scan2<<<ngrp, TPB, 0, stream>>>(Sseg, segbase, btot, nb);
    k_fillbin<<<nblk, TPB, 0, stream>>>(src, dst, O, segbase, binned, e, nb, cps);
    k_sort<<<nb, TPB, 0, stream>>>(binned, btot, x, csr, rowptr, rowend, dinv, xdq, n);
    k_gat1<<<gw, TPB, 0, stream>>>(xdq, csr, rowptr, rowend, dinv, b1, W1, W2,
                                   (uint2*)g2q, n, (int)np);
    k_gat2<<<gw, TPB, 0, stream>>>((const uint4*)g2q, csr, rowptr, rowend, dinv,
                                   b2, Wfc, bfc, out, n, (int)np);
}

// Round 13
// 231.210 us; speedup vs baseline: 4.2502x; 1.0002x over previous
//
#include <hip/hip_runtime.h>
#include <math.h>

// GCN 2-layer + sigmoid head. CSR pull-gather, zero fp32 atomics.
// R27: 16B-aligned binned segments. scan1 rounds each (chunk,bucket) count
//  up to a multiple of 4 (run += (v+3)&~3), so every segment starts 16B-
//  aligned; holes padded with -1 (k_sort already skips w[k]<0). fillbin's
//  flush becomes aligned int4 stores -> no partial-line straddles, 4x fewer
//  store insts. CAP 9216->10240 (padded bucket totals ~9360 avg).
//  R26: CHUNK=8192 + register-delta flush (-10us). Gather lessons
//  (R19..R25b): k_gat1 pinned ~50us across 6 variants = per-CU random-
//  gather request-rate floor; sc0 L1-bypass kept. No nt stores (R22),
//  no global deg atomics (R21), staged binning mandatory (R18/R20).
//   k_fb1:   per-chunk bucket histogram -> C[chunk][nb]
//   k_scan1/2: 2-level deterministic offset scan (4-rounded counts)
//   k_fillbin: LDS chunk counting-sort -> binned (aligned int4 segments)
//   k_sort:  bucket counting sort -> dense csr, rowptr/rowend, dinv, xdq
//   k_gat1/2: node-group gathers (16 lanes/node, sc0 L1-bypass payloads)

#define TPB 256
#define NBS 8
#define NBKT 256        // nodes per bucket
#define MAXB 1024       // max buckets (n <= 262144)
#define BPT (MAXB / TPB)
#define CHUNK 8192      // edges per fillbin block
#define EPT (CHUNK / TPB)
#define CAP 10240       // bucket region capacity (padded mean ~9360 + slack)
#define RPT (CAP / TPB) // 40 register-cached words per k_sort thread
#define NWAVE (TPB / 64)
#define NSEG 32         // chunk segments for the 2-level offset scan

#if defined(__has_builtin)
#if __has_builtin(__builtin_amdgcn_make_buffer_rsrc) && \
    __has_builtin(__builtin_amdgcn_raw_buffer_load_b128)
#define HAVE_BUFLOAD 1
#endif
#endif

#ifdef HAVE_BUFLOAD
typedef unsigned int u32x4v __attribute__((ext_vector_type(4)));
typedef __amdgpu_buffer_rsrc_t rsrc_t;
__device__ __forceinline__ rsrc_t mkrs(const void* p, int bytes) {
    return __builtin_amdgcn_make_buffer_rsrc(const_cast<void*>(p),
                                             (short)0, bytes, 0x00020000);
}
__device__ __forceinline__ uint4 g16(rsrc_t rs, const uint4* tbl, int idx) {
    u32x4v v = __builtin_amdgcn_raw_buffer_load_b128(rs, idx * 16, 0, 1);
    uint4 q;
    q.x = v.x; q.y = v.y; q.z = v.z; q.w = v.w;
    return q;
}
#else
typedef int rsrc_t;
__device__ __forceinline__ rsrc_t mkrs(const void* p, int bytes) { return 0; }
__device__ __forceinline__ uint4 g16(rsrc_t rs, const uint4* tbl, int idx) {
    return tbl[idx];
}
#endif

__device__ __forceinline__ unsigned short f2bf(float f) {
    unsigned u = __float_as_uint(f);
    unsigned r = (u + 0x7FFFu + ((u >> 16) & 1u)) >> 16;  // RNE
    return (unsigned short)r;
}
__device__ __forceinline__ unsigned pk2(float a, float b) {
    return (unsigned)f2bf(a) | ((unsigned)f2bf(b) << 16);
}
#define BFLO(u) __uint_as_float((u) << 16)
#define BFHI(u) __uint_as_float((u) & 0xFFFF0000u)

// per-chunk bucket histogram -> C[chunk][nb] (coalesced row store)
__global__ void __launch_bounds__(TPB) k_fb1(
        const int* __restrict__ dst, int* __restrict__ C, int e, int nb) {
    __shared__ int h[MAXB];
    int t = threadIdx.x;
    int c0 = blockIdx.x * CHUNK;
    int csize = min(e - c0, CHUNK);
#pragma unroll
    for (int k = 0; k < BPT; k++) h[t * BPT + k] = 0;
    __syncthreads();
    if (csize == CHUNK && ((((size_t)(const void*)(dst + c0)) & 15) == 0)) {
        const int4* d4 = (const int4*)(dst + c0);
#pragma unroll
        for (int k = 0; k < EPT / 4; k++) {
            int4 d = d4[t + k * TPB];
            atomicAdd(&h[d.x >> NBS], 1);
            atomicAdd(&h[d.y >> NBS], 1);
            atomicAdd(&h[d.z >> NBS], 1);
            atomicAdd(&h[d.w >> NBS], 1);
        }
    } else {
        for (int i = t; i < csize; i += TPB)
            atomicAdd(&h[dst[c0 + i] >> NBS], 1);
    }
    __syncthreads();
    int* row = C + (size_t)blockIdx.x * nb;
    for (int b = t; b < nb; b += TPB) row[b] = h[b];
}

// level-1: thread t serially scans bucket-column b over chunk segment s.
// Counts rounded up to multiples of 4 -> every segment start is 16B-aligned.
__global__ void __launch_bounds__(TPB) k_scan1(
        const int* __restrict__ C, int* __restrict__ O, int* __restrict__ Sseg,
        int nchunk, int nb, int cps, int ngrp) {
    int bid = blockIdx.x;
    int s = bid / ngrp, g = bid - s * ngrp;
    int b = g * TPB + threadIdx.x;
    if (b >= nb) return;
    int cbeg = s * cps;
    int cend = min(cbeg + cps, nchunk);
    int run = 0;
#pragma unroll 4
    for (int c = cbeg; c < cend; c++) {
        int v = C[(size_t)c * nb + b];
        O[(size_t)c * nb + b] = run;
        run += (v + 3) & ~3;   // 4-rounded: aligned segments, -1 pad holes
    }
    Sseg[s * nb + b] = run;
}

// level-2: per bucket, exclusive scan of NSEG segment sums; fold in b*CAP.
__global__ void __launch_bounds__(TPB) k_scan2(
        const int* __restrict__ Sseg, int* __restrict__ segbase,
        int* __restrict__ btot, int nb) {
    int b = blockIdx.x * TPB + threadIdx.x;
    if (b >= nb) return;
    int run = b * CAP;
#pragma unroll
    for (int s = 0; s < NSEG; s++) {
        segbase[s * nb + b] = run;
        run += Sseg[s * nb + b];
    }
    btot[b] = run - b * CAP;   // padded bucket total (incl. -1 holes)
}

// bin edges into fixed-cap bucket regions. LDS counting sort of the chunk;
// deterministic delta from segbase+O (no atomics); per-bucket register-delta
// flush with aligned int4 stores (-1 pad tail). word: ((d&255)<<18)|s
__global__ void __launch_bounds__(TPB) k_fillbin(
        const int* __restrict__ src, const int* __restrict__ dst,
        const int* __restrict__ O, const int* __restrict__ segbase,
        int* __restrict__ binned, int e, int nb, int cps) {
    __shared__ __align__(16) int stage[CHUNK];  // 32 KB, bucket-sorted words
    __shared__ int h[MAXB];                     // 4 KB, hist -> cursor -> end
    __shared__ int wsum[NWAVE];
    int t = threadIdx.x;
    int c0 = blockIdx.x * CHUNK;
    int csize = min(e - c0, CHUNK);
#pragma unroll
    for (int k = 0; k < BPT; k++) h[t * BPT + k] = 0;
    __syncthreads();
    int dreg[EPT], sreg[EPT];
    if (csize == CHUNK && ((((size_t)(const void*)(dst + c0)) & 15) == 0)
                       && ((((size_t)(const void*)(src + c0)) & 15) == 0)) {
        const int4* d4 = (const int4*)(dst + c0);
        const int4* s4 = (const int4*)(src + c0);
#pragma unroll
        for (int k = 0; k < EPT / 4; k++) {
            int4 d = d4[t + k * TPB];
            int4 s = s4[t + k * TPB];
            dreg[4 * k + 0] = d.x; sreg[4 * k + 0] = s.x;
            dreg[4 * k + 1] = d.y; sreg[4 * k + 1] = s.y;
            dreg[4 * k + 2] = d.z; sreg[4 * k + 2] = s.z;
            dreg[4 * k + 3] = d.w; sreg[4 * k + 3] = s.w;
            atomicAdd(&h[d.x >> NBS], 1);
            atomicAdd(&h[d.y >> NBS], 1);
            atomicAdd(&h[d.z >> NBS], 1);
            atomicAdd(&h[d.w >> NBS], 1);
        }
    } else {
#pragma unroll
        for (int k = 0; k < EPT; k++) {
            int idx = t + k * TPB;
            int d = (idx < csize) ? dst[c0 + idx] : -1;
            int s = (idx < csize) ? src[c0 + idx] : 0;
            dreg[k] = d;
            sreg[k] = s;
            if (d >= 0) atomicAdd(&h[d >> NBS], 1);
        }
    }
    __syncthreads();
    // per-thread local prefix over its BPT bins
    int loc[BPT], hreg[BPT];
    int ts = 0;
#pragma unroll
    for (int k = 0; k < BPT; k++) {
        hreg[k] = h[t * BPT + k];
        loc[k] = ts;
        ts += hreg[k];
    }
    // block-wide inclusive scan of ts: wave shfl scan + wave-sum combine
    int lane = t & 63, wid = t >> 6;
    int v = ts;
#pragma unroll
    for (int off = 1; off < 64; off <<= 1) {
        int u = __shfl_up(v, off);
        if (lane >= off) v += u;
    }
    if (lane == 63) wsum[wid] = v;
    __syncthreads();
    int pre = 0;
#pragma unroll
    for (int wq = 0; wq < NWAVE - 1; wq++)
        if (wid > wq) pre += wsum[wq];
    int tbase = pre + v - ts;  // exclusive prefix for this thread's first bin
    // deterministic per-bucket dest base (registers; aligned):
    // global start for bucket b's segment = segbase[s][b] + O[c][b]
    const int* Orow = O + (size_t)blockIdx.x * nb;
    const int* segrow = segbase + (size_t)(blockIdx.x / cps) * nb;
    int myg[BPT];
#pragma unroll
    for (int k = 0; k < BPT; k++) {
        int b = t * BPT + k;
        int ex = tbase + loc[k];
        h[b] = ex;  // stage cursor (published at next barrier)
        myg[k] = (b < nb) ? (segrow[b] + Orow[b]) : 0;  // 16B-aligned
    }
    __syncthreads();
    // LDS counting sort of the chunk (registers -> LDS only)
#pragma unroll
    for (int k = 0; k < EPT; k++) {
        int d = dreg[k];
        if (d >= 0) {
            int b = d >> NBS;
            int r = atomicAdd(&h[b], 1);
            stage[r] = ((d & (NBKT - 1)) << 18) | sreg[k];
        }
    }
    __syncthreads();
    // per-bucket flush: h[b] is bucket b's END cursor; thread t's buckets
    // [4t,4t+4) occupy one contiguous stage range. Aligned int4 stores,
    // tail padded with -1 up to the 4-rounded segment length.
    int bfirst = t * BPT;
    int s0 = (bfirst == 0) ? 0 : h[bfirst - 1];
#pragma unroll
    for (int k2 = 0; k2 < BPT; k2++) {
        int s1 = h[bfirst + k2];
        int g = myg[k2];  // global aligned start; stage range [s0,s1)
        for (int k = s0; k < s1; k += 4) {
            int4 v4;
            v4.x = stage[k];
            v4.y = (k + 1 < s1) ? stage[k + 1] : -1;
            v4.z = (k + 2 < s1) ? stage[k + 2] : -1;
            v4.w = (k + 3 < s1) ? stage[k + 3] : -1;
            *(int4*)&binned[g + (k - s0)] = v4;
        }
        s0 = s1;
    }
}

// full-bucket counting sort, register-cached (single region read via int4),
// LDS-staged dense csr flush (b128 reads + int4 stores). Pads (w<0) skipped.
__global__ void __launch_bounds__(TPB) k_sort(
        const int* __restrict__ binned, const int* __restrict__ btot,
        const float* __restrict__ x, int* __restrict__ csr,
        int* __restrict__ rowptr, int* __restrict__ rowend,
        float* __restrict__ dinv, uint4* __restrict__ xdq, int n) {
    __shared__ __align__(16) int stage[CAP];     // 40 KB
    __shared__ int cnt[NBKT];
    __shared__ int curs[NBKT];
    __shared__ int wsum[NWAVE];
    int b = blockIdx.x, t = threadIdx.x;
    int base = b * CAP;
    int c = btot[b];
    cnt[t] = 0;
    __syncthreads();
    // 1) read region once into registers (int4) + histogram
    int w[RPT];
#pragma unroll
    for (int k = 0; k < RPT / 4; k++) {
        int idx = 4 * t + k * 4 * TPB;
        int4 v;
        if (idx + 4 <= c) {
            v = *(const int4*)&binned[base + idx];
        } else {
            v.x = (idx + 0 < c) ? binned[base + idx + 0] : -1;
            v.y = (idx + 1 < c) ? binned[base + idx + 1] : -1;
            v.z = (idx + 2 < c) ? binned[base + idx + 2] : -1;
            v.w = (idx + 3 < c) ? binned[base + idx + 3] : -1;
        }
        w[4 * k + 0] = v.x; w[4 * k + 1] = v.y;
        w[4 * k + 2] = v.z; w[4 * k + 3] = v.w;
        if (v.x >= 0) atomicAdd(&cnt[v.x >> 18], 1);
        if (v.y >= 0) atomicAdd(&cnt[v.y >> 18], 1);
        if (v.z >= 0) atomicAdd(&cnt[v.z >> 18], 1);
        if (v.w >= 0) atomicAdd(&cnt[v.w >> 18], 1);
    }
    __syncthreads();
    // 2) exclusive scan of 256 bins: wave shfl scan + combine (1 barrier)
    int v = cnt[t];
    int lane = t & 63, wid = t >> 6;
    int iv = v;
#pragma unroll
    for (int off = 1; off < 64; off <<= 1) {
        int u = __shfl_up(iv, off);
        if (lane >= off) iv += u;
    }
    if (lane == 63) wsum[wid] = iv;
    __syncthreads();
    int pre = 0;
#pragma unroll
    for (int wq = 0; wq < NWAVE - 1; wq++)
        if (wid > wq) pre += wsum[wq];
    int ex = pre + iv - v;  // exclusive (valid edges only; pads excluded)
    curs[t] = ex;
    // 3) per-node outputs
    int i = (b << NBS) + t;
    rowptr[i] = base + ex;
    rowend[i] = base + ex + v;
    if (i < n) {
        float di = rsqrtf((float)(v + 1));
        dinv[i] = di;
        uint4 q;
        q.x = pk2(x[i * 6 + 0] * di, x[i * 6 + 1] * di);
        q.y = pk2(x[i * 6 + 2] * di, x[i * 6 + 3] * di);
        q.z = pk2(x[i * 6 + 4] * di, x[i * 6 + 5] * di);
        q.w = 0;
        xdq[i] = q;
    }
    __syncthreads();
    // 4) scatter from registers into LDS stage (node-sorted order)
#pragma unroll
    for (int k = 0; k < RPT; k++) {
        if (w[k] >= 0) {
            int r = atomicAdd(&curs[w[k] >> 18], 1);
            stage[r] = w[k] & 0x3FFFF;
        }
    }
    __syncthreads();
    // 5) dense flush of valid entries: total = curs-derived end of last node
    int cv = curs[NBKT - 1];   // after scatter: end cursor of last node = total valid
    for (int kb = 4 * t; kb + 4 <= cv; kb += 4 * TPB) {
        int4 sv = *(const int4*)&stage[kb];
        *(int4*)&csr[base + kb] = sv;
    }
    for (int k = (cv & ~3) + t; k < cv; k += TPB)
        csr[base + k] = stage[k];
}

// layer-1 gather (pre-W1 domain, bf16 payload): 16 lanes/node, 4 nodes/wave.
// neighbor payloads via sc0 buffer loads (L1 bypass).
// epilogue: agg6 (incl self) -> @W1 -> relu(di*.+b1) -> @W2 -> *di -> g2q (bf16)
__global__ void __launch_bounds__(TPB) k_gat1(
        const uint4* __restrict__ xdq, const int* __restrict__ csr,
        const int* __restrict__ rowptr, const int* __restrict__ rowend,
        const float* __restrict__ dinv,
        const float* __restrict__ b1, const float* __restrict__ W1,
        const float* __restrict__ W2, uint2* __restrict__ g2q, int n, int np) {
    __shared__ float w1[96];   // 6 x 16
    __shared__ float w2[128];  // 16 x 8
    __shared__ float bb[16];
    if (threadIdx.x < 96) w1[threadIdx.x] = W1[threadIdx.x];
    if (threadIdx.x < 128) w2[threadIdx.x] = W2[threadIdx.x];
    if (threadIdx.x < 16) bb[threadIdx.x] = b1[threadIdx.x];
    __syncthreads();
    rsrc_t rs = mkrs(xdq, np * 16);
    int sub = threadIdx.x & 15;                    // lane within node group
    int i = blockIdx.x * 16 + (threadIdx.x >> 4);  // 16 nodes per block
    bool valid = (i < n);
    int r0 = rowptr[i], r1 = rowend[i];            // padded nodes: r0 == r1
    float a0 = 0.f, a1 = 0.f, a2 = 0.f, a3 = 0.f, a4 = 0.f, a5 = 0.f;
    float c0 = 0.f, c1 = 0.f, c2 = 0.f, c3 = 0.f, c4 = 0.f, c5 = 0.f;
    if (valid && sub == 0) {  // self-loop term
        uint4 q = xdq[i];
        a0 += BFLO(q.x); a1 += BFHI(q.x);
        a2 += BFLO(q.y); a3 += BFHI(q.y);
        a4 += BFLO(q.z); a5 += BFHI(q.z);
    }
    int j = r0 + sub;
    while (j + 16 < r1) {
        uint4 q = g16(rs, xdq, csr[j]);
        uint4 p = g16(rs, xdq, csr[j + 16]);
        a0 += BFLO(q.x); a1 += BFHI(q.x);
        a2 += BFLO(q.y); a3 += BFHI(q.y);
        a4 += BFLO(q.z); a5 += BFHI(q.z);
        c0 += BFLO(p.x); c1 += BFHI(p.x);
        c2 += BFLO(p.y); c3 += BFHI(p.y);
        c4 += BFLO(p.z); c5 += BFHI(p.z);
        j += 32;
    }
    if (j < r1) {
        uint4 q = g16(rs, xdq, csr[j]);
        a0 += BFLO(q.x); a1 += BFHI(q.x);
        a2 += BFLO(q.y); a3 += BFHI(q.y);
        a4 += BFLO(q.z); a5 += BFHI(q.z);
    }
    a0 += c0; a1 += c1; a2 += c2; a3 += c3; a4 += c4; a5 += c5;
#pragma unroll
    for (int m = 1; m <= 8; m <<= 1) {  // reduce within 16-lane node group
        a0 += __shfl_xor(a0, m); a1 += __shfl_xor(a1, m);
        a2 += __shfl_xor(a2, m); a3 += __shfl_xor(a3, m);
        a4 += __shfl_xor(a4, m); a5 += __shfl_xor(a5, m);
    }
    float di = valid ? dinv[i] : 0.f;
    int f = sub;  // lane = hidden feature
    float hf = a0 * w1[f] + a1 * w1[16 + f] + a2 * w1[32 + f]
             + a3 * w1[48 + f] + a4 * w1[64 + f] + a5 * w1[80 + f];
    float tf = fmaxf(di * hf + bb[f], 0.0f);
    float p0 = tf * w2[f * 8 + 0], p1 = tf * w2[f * 8 + 1];
    float p2 = tf * w2[f * 8 + 2], p3 = tf * w2[f * 8 + 3];
    float p4 = tf * w2[f * 8 + 4], p5 = tf * w2[f * 8 + 5];
    float p6 = tf * w2[f * 8 + 6], p7 = tf * w2[f * 8 + 7];
#pragma unroll
    for (int m = 1; m <= 8; m <<= 1) {  // reduce over the 16 f-lanes
        p0 += __shfl_xor(p0, m); p1 += __shfl_xor(p1, m);
        p2 += __shfl_xor(p2, m); p3 += __shfl_xor(p3, m);
        p4 += __shfl_xor(p4, m); p5 += __shfl_xor(p5, m);
        p6 += __shfl_xor(p6, m); p7 += __shfl_xor(p7, m);
    }
    if (valid && sub < 2) {
        float q0 = sub ? p4 : p0, q1 = sub ? p5 : p1;
        float q2 = sub ? p6 : p2, q3 = sub ? p7 : p3;
        uint2 o;
        o.x = pk2(q0 * di, q1 * di);
        o.y = pk2(q2 * di, q3 * di);
        g2q[i * 2 + sub] = o;
    }
}

// layer-2 gather (bf16 payload): 16 lanes/node, 4 nodes/wave, sc0 gathers.
// fused head: h = relu(dinv*agg8 + b2); out = sigmoid(h @ Wfc + bfc)
__global__ void __launch_bounds__(TPB) k_gat2(
        const uint4* __restrict__ g2q, const int* __restrict__ csr,
        const int* __restrict__ rowptr, const int* __restrict__ rowend,
        const float* __restrict__ dinv,
        const float* __restrict__ b2, const float* __restrict__ Wfc,
        const float* __restrict__ bfc, float* __restrict__ out, int n, int np) {
    __shared__ float w[8];
    __shared__ float bb[8];
    __shared__ float bf;
    if (threadIdx.x < 8) { w[threadIdx.x] = Wfc[threadIdx.x]; bb[threadIdx.x] = b2[threadIdx.x]; }
    if (threadIdx.x == 0) bf = bfc[0];
    __syncthreads();
    rsrc_t rs = mkrs(g2q, np * 16);
    int sub = threadIdx.x & 15;
    int i = blockIdx.x * 16 + (threadIdx.x >> 4);
    bool valid = (i < n);
    int r0 = rowptr[i], r1 = rowend[i];
    float a0 = 0.f, a1 = 0.f, a2 = 0.f, a3 = 0.f;
    float a4 = 0.f, a5 = 0.f, a6 = 0.f, a7 = 0.f;
    if (valid && sub == 0) {  // self-loop term
        uint4 q = g2q[i];
        a0 += BFLO(q.x); a1 += BFHI(q.x); a2 += BFLO(q.y); a3 += BFHI(q.y);
        a4 += BFLO(q.z); a5 += BFHI(q.z); a6 += BFLO(q.w); a7 += BFHI(q.w);
    }
    float c0 = 0.f, c1 = 0.f, c2 = 0.f, c3 = 0.f;
    float c4 = 0.f, c5 = 0.f, c6 = 0.f, c7 = 0.f;
    int j = r0 + sub;
    while (j + 16 < r1) {
        uint4 q = g16(rs, g2q, csr[j]);
        uint4 p = g16(rs, g2q, csr[j + 16]);
        a0 += BFLO(q.x); a1 += BFHI(q.x); a2 += BFLO(q.y); a3 += BFHI(q.y);
        a4 += BFLO(q.z); a5 += BFHI(q.z); a6 += BFLO(q.w); a7 += BFHI(q.w);
        c0 += BFLO(p.x); c1 += BFHI(p.x); c2 += BFLO(p.y); c3 += BFHI(p.y);
        c4 += BFLO(p.z); c5 += BFHI(p.z); c6 += BFLO(p.w); c7 += BFHI(p.w);
        j += 32;
    }
    if (j < r1) {
        uint4 q = g16(rs, g2q, csr[j]);
        a0 += BFLO(q.x); a1 += BFHI(q.x); a2 += BFLO(q.y); a3 += BFHI(q.y);
        a4 += BFLO(q.z); a5 += BFHI(q.z); a6 += BFLO(q.w); a7 += BFHI(q.w);
    }
    a0 += c0; a1 += c1; a2 += c2; a3 += c3;
    a4 += c4; a5 += c5; a6 += c6; a7 += c7;
#pragma unroll
    for (int m = 1; m <= 8; m <<= 1) {  // reduce within 16-lane node group
        a0 += __shfl_xor(a0, m); a1 += __shfl_xor(a1, m);
        a2 += __shfl_xor(a2, m); a3 += __shfl_xor(a3, m);
        a4 += __shfl_xor(a4, m); a5 += __shfl_xor(a5, m);
        a6 += __shfl_xor(a6, m); a7 += __shfl_xor(a7, m);
    }
    if (valid && sub == 0) {  // head computed once per node (cheap, no shfl)
        float di = dinv[i];
        float o = bf;
        o += fmaxf(di * a0 + bb[0], 0.0f) * w[0];
        o += fmaxf(di * a1 + bb[1], 0.0f) * w[1];
        o += fmaxf(di * a2 + bb[2], 0.0f) * w[2];
        o += fmaxf(di * a3 + bb[3], 0.0f) * w[3];
        o += fmaxf(di * a4 + bb[4], 0.0f) * w[4];
        o += fmaxf(di * a5 + bb[5], 0.0f) * w[5];
        o += fmaxf(di * a6 + bb[6], 0.0f) * w[6];
        o += fmaxf(di * a7 + bb[7], 0.0f) * w[7];
        out[i] = 1.0f / (1.0f + expf(-o));
    }
}

extern "C" void kernel_launch(void* const* d_in, const int* in_sizes, int n_in,
                              void* d_out, int out_size, void* d_ws, size_t ws_size,
                              hipStream_t stream) {
    const float* x   = (const float*)d_in[0];
    const int*   ei  = (const int*)d_in[1];
    const float* W1  = (const float*)d_in[2];
    const float* b1  = (const float*)d_in[3];
    const float* W2  = (const float*)d_in[4];
    const float* b2  = (const float*)d_in[5];
    const float* Wfc = (const float*)d_in[6];
    const float* bfc = (const float*)d_in[7];
    float* out = (float*)d_out;

    const int n = in_sizes[0] / 6;   // 200000 (<= 262144 for 18-bit packing)
    const int e = in_sizes[1] / 2;   // 6400000
    const int* src = ei;
    const int* dst = ei + e;
    const int nb = (n + NBKT - 1) >> NBS;  // 782
    const size_t np = (size_t)nb << NBS;   // padded node count (200192)
    const int nblk = (e + CHUNK - 1) / CHUNK;  // 782 chunks
    const int cps = (nblk + NSEG - 1) / NSEG;  // chunks per segment (25)
    const int ngrp = (nb + TPB - 1) / TPB;     // bucket groups (4)
    const size_t reg = (size_t)nb * CAP;   // bucket-region total (8.0M words)

    int* C       = (int*)d_ws;                 // nblk * nb
    int* O       = C + (size_t)nblk * nb;      // nblk * nb
    int* Sseg    = O + (size_t)nblk * nb;      // NSEG * MAXB
    int* segbase = Sseg + (size_t)NSEG * MAXB; // NSEG * MAXB
    int* btot    = segbase + (size_t)NSEG * MAXB; // MAXB
    int* binned  = btot + MAXB;                // reg (16B-aligned)
    int* csr     = binned + reg;               // reg
    int* rowptr  = csr + reg;                  // np
    int* rowend  = rowptr + np;                // np
    float* dinv  = (float*)(rowend + np);      // np
    size_t off   = (size_t)((int*)(dinv + np) - (int*)d_ws);
    off = (off + 3) & ~(size_t)3;              // 16B-align the uint4 arrays
    uint4* xdq   = (uint4*)((int*)d_ws + off); // np * 16 B
    uint2* g2q   = (uint2*)(xdq + np);         // np * 16 B

    int gw = (n + 15) / 16;              // node-group blocks (16 nodes/block)

    k_fb1<<<nblk, TPB, 0, stream>>>(dst, C, e, nb);
    k_scan1<<<NSEG * ngrp, TPB, 0, stream>>>(C, O, Sseg, nblk, nb, cps, ngrp);
    k_scan2<<<ngrp, TPB, 0, stream>>>(Sseg, segbase, btot, nb);
    k_fillbin<<<nblk, TPB, 0, stream>>>(src, dst, O, segbase, binned, e, nb, cps);
    k_sort<<<nb, TPB, 0, stream>>>(binned, btot, x, csr, rowptr, rowend, dinv, xdq, n);
    k_gat1<<<gw, TPB, 0, stream>>>(xdq, csr, rowptr, rowend, dinv, b1, W1, W2,
                                   (uint2*)g2q, n, (int)np);
    k_gat2<<<gw, TPB, 0, stream>>>((const uint4*)g2q, csr, rowptr, rowend, dinv,
                                   b2, Wfc, bfc, out, n, (int)np);
}

// Round 15
// 231.044 us; speedup vs baseline: 4.2532x; 1.0007x over previous
//
#include <hip/hip_runtime.h>
#include <math.h>

// GCN 2-layer + sigmoid head. CSR pull-gather, zero fp32 atomics.
// R29: R27 base (231.2us proven; R28's cooperative fusion REVERTED —
//  cross-XCD visibility of plain stores across grid.sync() failed
//  correctness, absmax 0.438). Safe slice of the same redundancy:
//  k_fillbin reads its per-bucket counts from C[chunk][.] (3KB coalesced
//  row, already computed by k_fb1) instead of rebuilding them with 8192
//  LDS atomics per block. Removes 1 of 2 per-edge LDS atomic ops + one
//  barrier from fillbin's load phase.
//  R27: 16B-aligned segments. R26: CHUNK=8192 + register-delta flush.
//  Gather lessons (R19..R25b): k_gat1 pinned ~50us across 6 variants =
//  per-CU random-gather request-rate floor; sc0 L1-bypass kept. No nt
//  stores (R22), no global deg atomics (R21), no LDS push (R20), no
//  direct scatter (R18), no cross-XCD plain-store handoff (R28).
//   k_fb1:   per-chunk bucket histogram -> C[chunk][nb]
//   k_scan1/2: 2-level deterministic offset scan (4-rounded counts)
//   k_fillbin: LDS chunk counting-sort (counts from C) -> aligned binned
//   k_sort:  bucket counting sort -> dense csr, rowptr/rowend, dinv, xdq
//   k_gat1/2: node-group gathers (16 lanes/node, sc0 L1-bypass payloads)

#define TPB 256
#define NBS 8
#define NBKT 256        // nodes per bucket
#define MAXB 1024       // max buckets (n <= 262144)
#define BPT (MAXB / TPB)
#define CHUNK 8192      // edges per fillbin block
#define EPT (CHUNK / TPB)
#define CAP 10240       // bucket region capacity (padded mean ~9360 + slack)
#define RPT (CAP / TPB) // 40 register-cached words per k_sort thread
#define NWAVE (TPB / 64)
#define NSEG 32         // chunk segments for the 2-level offset scan

#if defined(__has_builtin)
#if __has_builtin(__builtin_amdgcn_make_buffer_rsrc) && \
    __has_builtin(__builtin_amdgcn_raw_buffer_load_b128)
#define HAVE_BUFLOAD 1
#endif
#endif

#ifdef HAVE_BUFLOAD
typedef unsigned int u32x4v __attribute__((ext_vector_type(4)));
typedef __amdgpu_buffer_rsrc_t rsrc_t;
__device__ __forceinline__ rsrc_t mkrs(const void* p, int bytes) {
    return __builtin_amdgcn_make_buffer_rsrc(const_cast<void*>(p),
                                             (short)0, bytes, 0x00020000);
}
__device__ __forceinline__ uint4 g16(rsrc_t rs, const uint4* tbl, int idx) {
    u32x4v v = __builtin_amdgcn_raw_buffer_load_b128(rs, idx * 16, 0, 1);
    uint4 q;
    q.x = v.x; q.y = v.y; q.z = v.z; q.w = v.w;
    return q;
}
#else
typedef int rsrc_t;
__device__ __forceinline__ rsrc_t mkrs(const void* p, int bytes) { return 0; }
__device__ __forceinline__ uint4 g16(rsrc_t rs, const uint4* tbl, int idx) {
    return tbl[idx];
}
#endif

__device__ __forceinline__ unsigned short f2bf(float f) {
    unsigned u = __float_as_uint(f);
    unsigned r = (u + 0x7FFFu + ((u >> 16) & 1u)) >> 16;  // RNE
    return (unsigned short)r;
}
__device__ __forceinline__ unsigned pk2(float a, float b) {
    return (unsigned)f2bf(a) | ((unsigned)f2bf(b) << 16);
}
#define BFLO(u) __uint_as_float((u) << 16)
#define BFHI(u) __uint_as_float((u) & 0xFFFF0000u)

// per-chunk bucket histogram -> C[chunk][nb] (coalesced row store)
__global__ void __launch_bounds__(TPB) k_fb1(
        const int* __restrict__ dst, int* __restrict__ C, int e, int nb) {
    __shared__ int h[MAXB];
    int t = threadIdx.x;
    int c0 = blockIdx.x * CHUNK;
    int csize = min(e - c0, CHUNK);
#pragma unroll
    for (int k = 0; k < BPT; k++) h[t * BPT + k] = 0;
    __syncthreads();
    if (csize == CHUNK && ((((size_t)(const void*)(dst + c0)) & 15) == 0)) {
        const int4* d4 = (const int4*)(dst + c0);
#pragma unroll
        for (int k = 0; k < EPT / 4; k++) {
            int4 d = d4[t + k * TPB];
            atomicAdd(&h[d.x >> NBS], 1);
            atomicAdd(&h[d.y >> NBS], 1);
            atomicAdd(&h[d.z >> NBS], 1);
            atomicAdd(&h[d.w >> NBS], 1);
        }
    } else {
        for (int i = t; i < csize; i += TPB)
            atomicAdd(&h[dst[c0 + i] >> NBS], 1);
    }
    __syncthreads();
    int* row = C + (size_t)blockIdx.x * nb;
    for (int b = t; b < nb; b += TPB) row[b] = h[b];
}

// level-1: thread t serially scans bucket-column b over chunk segment s.
// Counts rounded up to multiples of 4 -> every segment start is 16B-aligned.
__global__ void __launch_bounds__(TPB) k_scan1(
        const int* __restrict__ C, int* __restrict__ O, int* __restrict__ Sseg,
        int nchunk, int nb, int cps, int ngrp) {
    int bid = blockIdx.x;
    int s = bid / ngrp, g = bid - s * ngrp;
    int b = g * TPB + threadIdx.x;
    if (b >= nb) return;
    int cbeg = s * cps;
    int cend = min(cbeg + cps, nchunk);
    int run = 0;
#pragma unroll 4
    for (int c = cbeg; c < cend; c++) {
        int v = C[(size_t)c * nb + b];
        O[(size_t)c * nb + b] = run;
        run += (v + 3) & ~3;   // 4-rounded: aligned segments, -1 pad holes
    }
    Sseg[s * nb + b] = run;
}

// level-2: per bucket, exclusive scan of NSEG segment sums; fold in b*CAP.
__global__ void __launch_bounds__(TPB) k_scan2(
        const int* __restrict__ Sseg, int* __restrict__ segbase,
        int* __restrict__ btot, int nb) {
    int b = blockIdx.x * TPB + threadIdx.x;
    if (b >= nb) return;
    int run = b * CAP;
#pragma unroll
    for (int s = 0; s < NSEG; s++) {
        segbase[s * nb + b] = run;
        run += Sseg[s * nb + b];
    }
    btot[b] = run - b * CAP;   // padded bucket total (incl. -1 holes)
}

// bin edges into fixed-cap bucket regions. LDS counting sort of the chunk;
// per-bucket counts read from C (no LDS-atomic histogram); deterministic
// delta from segbase+O; aligned int4 flush. word: ((d&255)<<18)|s
__global__ void __launch_bounds__(TPB) k_fillbin(
        const int* __restrict__ src, const int* __restrict__ dst,
        const int* __restrict__ C, const int* __restrict__ O,
        const int* __restrict__ segbase,
        int* __restrict__ binned, int e, int nb, int cps) {
    __shared__ __align__(16) int stage[CHUNK];  // 32 KB, bucket-sorted words
    __shared__ int h[MAXB];                     // 4 KB, scatter cursor
    __shared__ int wsum[NWAVE];
    int t = threadIdx.x;
    int c0 = blockIdx.x * CHUNK;
    int csize = min(e - c0, CHUNK);
    int dreg[EPT], sreg[EPT];
    if (csize == CHUNK && ((((size_t)(const void*)(dst + c0)) & 15) == 0)
                       && ((((size_t)(const void*)(src + c0)) & 15) == 0)) {
        const int4* d4 = (const int4*)(dst + c0);
        const int4* s4 = (const int4*)(src + c0);
#pragma unroll
        for (int k = 0; k < EPT / 4; k++) {
            int4 d = d4[t + k * TPB];
            int4 s = s4[t + k * TPB];
            dreg[4 * k + 0] = d.x; sreg[4 * k + 0] = s.x;
            dreg[4 * k + 1] = d.y; sreg[4 * k + 1] = s.y;
            dreg[4 * k + 2] = d.z; sreg[4 * k + 2] = s.z;
            dreg[4 * k + 3] = d.w; sreg[4 * k + 3] = s.w;
        }
    } else {
#pragma unroll
        for (int k = 0; k < EPT; k++) {
            int idx = t + k * TPB;
            dreg[k] = (idx < csize) ? dst[c0 + idx] : -1;
            sreg[k] = (idx < csize) ? src[c0 + idx] : 0;
        }
    }
    // per-bucket counts from C row (coalesced; replaces 8192 LDS atomics)
    const int* Crow = C + (size_t)blockIdx.x * nb;
    int loc[BPT], hreg[BPT];
    int ts = 0;
#pragma unroll
    for (int k = 0; k < BPT; k++) {
        int b = t * BPT + k;
        hreg[k] = (b < nb) ? Crow[b] : 0;
        loc[k] = ts;
        ts += hreg[k];
    }
    // block-wide inclusive scan of ts: wave shfl scan + wave-sum combine
    int lane = t & 63, wid = t >> 6;
    int v = ts;
#pragma unroll
    for (int off = 1; off < 64; off <<= 1) {
        int u = __shfl_up(v, off);
        if (lane >= off) v += u;
    }
    if (lane == 63) wsum[wid] = v;
    __syncthreads();
    int pre = 0;
#pragma unroll
    for (int wq = 0; wq < NWAVE - 1; wq++)
        if (wid > wq) pre += wsum[wq];
    int tbase = pre + v - ts;  // exclusive prefix for this thread's first bin
    // deterministic per-bucket dest base (registers; 16B-aligned)
    const int* Orow = O + (size_t)blockIdx.x * nb;
    const int* segrow = segbase + (size_t)(blockIdx.x / cps) * nb;
    int myg[BPT];
#pragma unroll
    for (int k = 0; k < BPT; k++) {
        int b = t * BPT + k;
        int ex = tbase + loc[k];
        h[b] = ex;  // stage cursor (published at next barrier)
        myg[k] = (b < nb) ? (segrow[b] + Orow[b]) : 0;  // 16B-aligned
    }
    __syncthreads();
    // LDS counting sort of the chunk (registers -> LDS only)
#pragma unroll
    for (int k = 0; k < EPT; k++) {
        int d = dreg[k];
        if (d >= 0) {
            int b = d >> NBS;
            int r = atomicAdd(&h[b], 1);
            stage[r] = ((d & (NBKT - 1)) << 18) | sreg[k];
        }
    }
    __syncthreads();
    // per-bucket flush: h[b] is bucket b's END cursor; thread t's buckets
    // [4t,4t+4) occupy one contiguous stage range. Aligned int4 stores,
    // tail padded with -1 up to the 4-rounded segment length.
    int bfirst = t * BPT;
    int s0 = (bfirst == 0) ? 0 : h[bfirst - 1];
#pragma unroll
    for (int k2 = 0; k2 < BPT; k2++) {
        int s1 = h[bfirst + k2];
        int g = myg[k2];  // global aligned start; stage range [s0,s1)
        for (int k = s0; k < s1; k += 4) {
            int4 v4;
            v4.x = stage[k];
            v4.y = (k + 1 < s1) ? stage[k + 1] : -1;
            v4.z = (k + 2 < s1) ? stage[k + 2] : -1;
            v4.w = (k + 3 < s1) ? stage[k + 3] : -1;
            *(int4*)&binned[g + (k - s0)] = v4;
        }
        s0 = s1;
    }
}

// full-bucket counting sort, register-cached (single region read via int4),
// LDS-staged dense csr flush (b128 reads + int4 stores). Pads (w<0) skipped.
__global__ void __launch_bounds__(TPB) k_sort(
        const int* __restrict__ binned, const int* __restrict__ btot,
        const float* __restrict__ x, int* __restrict__ csr,
        int* __restrict__ rowptr, int* __restrict__ rowend,
        float* __restrict__ dinv, uint4* __restrict__ xdq, int n) {
    __shared__ __align__(16) int stage[CAP];     // 40 KB
    __shared__ int cnt[NBKT];
    __shared__ int curs[NBKT];
    __shared__ int wsum[NWAVE];
    int b = blockIdx.x, t = threadIdx.x;
    int base = b * CAP;
    int c = btot[b];
    cnt[t] = 0;
    __syncthreads();
    // 1) read region once into registers (int4) + histogram
    int w[RPT];
#pragma unroll
    for (int k = 0; k < RPT / 4; k++) {
        int idx = 4 * t + k * 4 * TPB;
        int4 v;
        if (idx + 4 <= c) {
            v = *(const int4*)&binned[base + idx];
        } else {
            v.x = (idx + 0 < c) ? binned[base + idx + 0] : -1;
            v.y = (idx + 1 < c) ? binned[base + idx + 1] : -1;
            v.z = (idx + 2 < c) ? binned[base + idx + 2] : -1;
            v.w = (idx + 3 < c) ? binned[base + idx + 3] : -1;
        }
        w[4 * k + 0] = v.x; w[4 * k + 1] = v.y;
        w[4 * k + 2] = v.z; w[4 * k + 3] = v.w;
        if (v.x >= 0) atomicAdd(&cnt[v.x >> 18], 1);
        if (v.y >= 0) atomicAdd(&cnt[v.y >> 18], 1);
        if (v.z >= 0) atomicAdd(&cnt[v.z >> 18], 1);
        if (v.w >= 0) atomicAdd(&cnt[v.w >> 18], 1);
    }
    __syncthreads();
    // 2) exclusive scan of 256 bins: wave shfl scan + combine (1 barrier)
    int v = cnt[t];
    int lane = t & 63, wid = t >> 6;
    int iv = v;
#pragma unroll
    for (int off = 1; off < 64; off <<= 1) {
        int u = __shfl_up(iv, off);
        if (lane >= off) iv += u;
    }
    if (lane == 63) wsum[wid] = iv;
    __syncthreads();
    int pre = 0;
#pragma unroll
    for (int wq = 0; wq < NWAVE - 1; wq++)
        if (wid > wq) pre += wsum[wq];
    int ex = pre + iv - v;  // exclusive (valid edges only; pads excluded)
    curs[t] = ex;
    // 3) per-node outputs
    int i = (b << NBS) + t;
    rowptr[i] = base + ex;
    rowend[i] = base + ex + v;
    if (i < n) {
        float di = rsqrtf((float)(v + 1));
        dinv[i] = di;
        uint4 q;
        q.x = pk2(x[i * 6 + 0] * di, x[i * 6 + 1] * di);
        q.y = pk2(x[i * 6 + 2] * di, x[i * 6 + 3] * di);
        q.z = pk2(x[i * 6 + 4] * di, x[i * 6 + 5] * di);
        q.w = 0;
        xdq[i] = q;
    }
    __syncthreads();
    // 4) scatter from registers into LDS stage (node-sorted order)
#pragma unroll
    for (int k = 0; k < RPT; k++) {
        if (w[k] >= 0) {
            int r = atomicAdd(&curs[w[k] >> 18], 1);
            stage[r] = w[k] & 0x3FFFF;
        }
    }
    __syncthreads();
    // 5) dense flush of valid entries
    int cv = curs[NBKT - 1];   // total valid entries in this bucket
    for (int kb = 4 * t; kb + 4 <= cv; kb += 4 * TPB) {
        int4 sv = *(const int4*)&stage[kb];
        *(int4*)&csr[base + kb] = sv;
    }
    for (int k = (cv & ~3) + t; k < cv; k += TPB)
        csr[base + k] = stage[k];
}

// layer-1 gather (pre-W1 domain, bf16 payload): 16 lanes/node, 4 nodes/wave.
// neighbor payloads via sc0 buffer loads (L1 bypass).
// epilogue: agg6 (incl self) -> @W1 -> relu(di*.+b1) -> @W2 -> *di -> g2q (bf16)
__global__ void __launch_bounds__(TPB) k_gat1(
        const uint4* __restrict__ xdq, const int* __restrict__ csr,
        const int* __restrict__ rowptr, const int* __restrict__ rowend,
        const float* __restrict__ dinv,
        const float* __restrict__ b1, const float* __restrict__ W1,
        const float* __restrict__ W2, uint2* __restrict__ g2q, int n, int np) {
    __shared__ float w1[96];   // 6 x 16
    __shared__ float w2[128];  // 16 x 8
    __shared__ float bb[16];
    if (threadIdx.x < 96) w1[threadIdx.x] = W1[threadIdx.x];
    if (threadIdx.x < 128) w2[threadIdx.x] = W2[threadIdx.x];
    if (threadIdx.x < 16) bb[threadIdx.x] = b1[threadIdx.x];
    __syncthreads();
    rsrc_t rs = mkrs(xdq, np * 16);
    int sub = threadIdx.x & 15;                    // lane within node group
    int i = blockIdx.x * 16 + (threadIdx.x >> 4);  // 16 nodes per block
    bool valid = (i < n);
    int r0 = rowptr[i], r1 = rowend[i];            // padded nodes: r0 == r1
    float a0 = 0.f, a1 = 0.f, a2 = 0.f, a3 = 0.f, a4 = 0.f, a5 = 0.f;
    float c0 = 0.f, c1 = 0.f, c2 = 0.f, c3 = 0.f, c4 = 0.f, c5 = 0.f;
    if (valid && sub == 0) {  // self-loop term
        uint4 q = xdq[i];
        a0 += BFLO(q.x); a1 += BFHI(q.x);
        a2 += BFLO(q.y); a3 += BFHI(q.y);
        a4 += BFLO(q.z); a5 += BFHI(q.z);
    }
    int j = r0 + sub;
    while (j + 16 < r1) {
        uint4 q = g16(rs, xdq, csr[j]);
        uint4 p = g16(rs, xdq, csr[j + 16]);
        a0 += BFLO(q.x); a1 += BFHI(q.x);
        a2 += BFLO(q.y); a3 += BFHI(q.y);
        a4 += BFLO(q.z); a5 += BFHI(q.z);
        c0 += BFLO(p.x); c1 += BFHI(p.x);
        c2 += BFLO(p.y); c3 += BFHI(p.y);
        c4 += BFLO(p.z); c5 += BFHI(p.z);
        j += 32;
    }
    if (j < r1) {
        uint4 q = g16(rs, xdq, csr[j]);
        a0 += BFLO(q.x); a1 += BFHI(q.x);
        a2 += BFLO(q.y); a3 += BFHI(q.y);
        a4 += BFLO(q.z); a5 += BFHI(q.z);
    }
    a0 += c0; a1 += c1; a2 += c2; a3 += c3; a4 += c4; a5 += c5;
#pragma unroll
    for (int m = 1; m <= 8; m <<= 1) {  // reduce within 16-lane node group
        a0 += __shfl_xor(a0, m); a1 += __shfl_xor(a1, m);
        a2 += __shfl_xor(a2, m); a3 += __shfl_xor(a3, m);
        a4 += __shfl_xor(a4, m); a5 += __shfl_xor(a5, m);
    }
    float di = valid ? dinv[i] : 0.f;
    int f = sub;  // lane = hidden feature
    float hf = a0 * w1[f] + a1 * w1[16 + f] + a2 * w1[32 + f]
             + a3 * w1[48 + f] + a4 * w1[64 + f] + a5 * w1[80 + f];
    float tf = fmaxf(di * hf + bb[f], 0.0f);
    float p0 = tf * w2[f * 8 + 0], p1 = tf * w2[f * 8 + 1];
    float p2 = tf * w2[f * 8 + 2], p3 = tf * w2[f * 8 + 3];
    float p4 = tf * w2[f * 8 + 4], p5 = tf * w2[f * 8 + 5];
    float p6 = tf * w2[f * 8 + 6], p7 = tf * w2[f * 8 + 7];
#pragma unroll
    for (int m = 1; m <= 8; m <<= 1) {  // reduce over the 16 f-lanes
        p0 += __shfl_xor(p0, m); p1 += __shfl_xor(p1, m);
        p2 += __shfl_xor(p2, m); p3 += __shfl_xor(p3, m);
        p4 += __shfl_xor(p4, m); p5 += __shfl_xor(p5, m);
        p6 += __shfl_xor(p6, m); p7 += __shfl_xor(p7, m);
    }
    if (valid && sub < 2) {
        float q0 = sub ? p4 : p0, q1 = sub ? p5 : p1;
        float q2 = sub ? p6 : p2, q3 = sub ? p7 : p3;
        uint2 o;
        o.x = pk2(q0 * di, q1 * di);
        o.y = pk2(q2 * di, q3 * di);
        g2q[i * 2 + sub] = o;
    }
}

// layer-2 gather (bf16 payload): 16 lanes/node, 4 nodes/wave, sc0 gathers.
// fused head: h = relu(dinv*agg8 + b2); out = sigmoid(h @ Wfc + bfc)
__global__ void __launch_bounds__(TPB) k_gat2(
        const uint4* __restrict__ g2q, const int* __restrict__ csr,
        const int* __restrict__ rowptr, const int* __restrict__ rowend,
        const float* __restrict__ dinv,
        const float* __restrict__ b2, const float* __restrict__ Wfc,
        const float* __restrict__ bfc, float* __restrict__ out, int n, int np) {
    __shared__ float w[8];
    __shared__ float bb[8];
    __shared__ float bf;
    if (threadIdx.x < 8) { w[threadIdx.x] = Wfc[threadIdx.x]; bb[threadIdx.x] = b2[threadIdx.x]; }
    if (threadIdx.x == 0) bf = bfc[0];
    __syncthreads();
    rsrc_t rs = mkrs(g2q, np * 16);
    int sub = threadIdx.x & 15;
    int i = blockIdx.x * 16 + (threadIdx.x >> 4);
    bool valid = (i < n);
    int r0 = rowptr[i], r1 = rowend[i];
    float a0 = 0.f, a1 = 0.f, a2 = 0.f, a3 = 0.f;
    float a4 = 0.f, a5 = 0.f, a6 = 0.f, a7 = 0.f;
    if (valid && sub == 0) {  // self-loop term
        uint4 q = g2q[i];
        a0 += BFLO(q.x); a1 += BFHI(q.x); a2 += BFLO(q.y); a3 += BFHI(q.y);
        a4 += BFLO(q.z); a5 += BFHI(q.z); a6 += BFLO(q.w); a7 += BFHI(q.w);
    }
    float c0 = 0.f, c1 = 0.f, c2 = 0.f, c3 = 0.f;
    float c4 = 0.f, c5 = 0.f, c6 = 0.f, c7 = 0.f;
    int j = r0 + sub;
    while (j + 16 < r1) {
        uint4 q = g16(rs, g2q, csr[j]);
        uint4 p = g16(rs, g2q, csr[j + 16]);
        a0 += BFLO(q.x); a1 += BFHI(q.x); a2 += BFLO(q.y); a3 += BFHI(q.y);
        a4 += BFLO(q.z); a5 += BFHI(q.z); a6 += BFLO(q.w); a7 += BFHI(q.w);
        c0 += BFLO(p.x); c1 += BFHI(p.x); c2 += BFLO(p.y); c3 += BFHI(p.y);
        c4 += BFLO(p.z); c5 += BFHI(p.z); c6 += BFLO(p.w); c7 += BFHI(p.w);
        j += 32;
    }
    if (j < r1) {
        uint4 q = g16(rs, g2q, csr[j]);
        a0 += BFLO(q.x); a1 += BFHI(q.x); a2 += BFLO(q.y); a3 += BFHI(q.y);
        a4 += BFLO(q.z); a5 += BFHI(q.z); a6 += BFLO(q.w); a7 += BFHI(q.w);
    }
    a0 += c0; a1 += c1; a2 += c2; a3 += c3;
    a4 += c4; a5 += c5; a6 += c6; a7 += c7;
#pragma unroll
    for (int m = 1; m <= 8; m <<= 1) {  // reduce within 16-lane node group
        a0 += __shfl_xor(a0, m); a1 += __shfl_xor(a1, m);
        a2 += __shfl_xor(a2, m); a3 += __shfl_xor(a3, m);
        a4 += __shfl_xor(a4, m); a5 += __shfl_xor(a5, m);
        a6 += __shfl_xor(a6, m); a7 += __shfl_xor(a7, m);
    }
    if (valid && sub == 0) {  // head computed once per node (cheap, no shfl)
        float di = dinv[i];
        float o = bf;
        o += fmaxf(di * a0 + bb[0], 0.0f) * w[0];
        o += fmaxf(di * a1 + bb[1], 0.0f) * w[1];
        o += fmaxf(di * a2 + bb[2], 0.0f) * w[2];
        o += fmaxf(di * a3 + bb[3], 0.0f) * w[3];
        o += fmaxf(di * a4 + bb[4], 0.0f) * w[4];
        o += fmaxf(di * a5 + bb[5], 0.0f) * w[5];
        o += fmaxf(di * a6 + bb[6], 0.0f) * w[6];
        o += fmaxf(di * a7 + bb[7], 0.0f) * w[7];
        out[i] = 1.0f / (1.0f + expf(-o));
    }
}

extern "C" void kernel_launch(void* const* d_in, const int* in_sizes, int n_in,
                              void* d_out, int out_size, void* d_ws, size_t ws_size,
                              hipStream_t stream) {
    const float* x   = (const float*)d_in[0];
    const int*   ei  = (const int*)d_in[1];
    const float* W1  = (const float*)d_in[2];
    const float* b1  = (const float*)d_in[3];
    const float* W2  = (const float*)d_in[4];
    const float* b2  = (const float*)d_in[5];
    const float* Wfc = (const float*)d_in[6];
    const float* bfc = (const float*)d_in[7];
    float* out = (float*)d_out;

    const int n = in_sizes[0] / 6;   // 200000 (<= 262144 for 18-bit packing)
    const int e = in_sizes[1] / 2;   // 6400000
    const int* src = ei;
    const int* dst = ei + e;
    const int nb = (n + NBKT - 1) >> NBS;  // 782
    const size_t np = (size_t)nb << NBS;   // padded node count (200192)
    const int nblk = (e + CHUNK - 1) / CHUNK;  // 782 chunks
    const int cps = (nblk + NSEG - 1) / NSEG;  // chunks per segment (25)
    const int ngrp = (nb + TPB - 1) / TPB;     // bucket groups (4)
    const size_t reg = (size_t)nb * CAP;   // bucket-region total (8.0M words)

    int* C       = (int*)d_ws;                 // nblk * nb
    int* O       = C + (size_t)nblk * nb;      // nblk * nb
    int* Sseg    = O + (size_t)nblk * nb;      // NSEG * MAXB
    int* segbase = Sseg + (size_t)NSEG * MAXB; // NSEG * MAXB
    int* btot    = segbase + (size_t)NSEG * MAXB; // MAXB
    int* binned  = btot + MAXB;                // reg (16B-aligned)
    int* csr     = binned + reg;               // reg
    int* rowptr  = csr + reg;                  // np
    int* rowend  = rowptr + np;                // np
    float* dinv  = (float*)(rowend + np);      // np
    size_t off   = (size_t)((int*)(dinv + np) - (int*)d_ws);
    off = (off + 3) & ~(size_t)3;              // 16B-align the uint4 arrays
    uint4* xdq   = (uint4*)((int*)d_ws + off); // np * 16 B
    uint2* g2q   = (uint2*)(xdq + np);         // np * 16 B

    int gw = (n + 15) / 16;              // node-group blocks (16 nodes/block)
    int npw = (int)np;

    k_fb1<<<nblk, TPB, 0, stream>>>(dst, C, e, nb);
    k_scan1<<<NSEG * ngrp, TPB, 0, stream>>>(C, O, Sseg, nblk, nb, cps, ngrp);
    k_scan2<<<ngrp, TPB, 0, stream>>>(Sseg, segbase, btot, nb);
    k_fillbin<<<nblk, TPB, 0, stream>>>(src, dst, C, O, segbase, binned, e, nb, cps);
    k_sort<<<nb, TPB, 0, stream>>>(binned, btot, x, csr, rowptr, rowend, dinv, xdq, n);
    k_gat1<<<gw, TPB, 0, stream>>>(xdq, csr, rowptr, rowend, dinv, b1, W1, W2,
                                   (uint2*)g2q, n, npw);
    k_gat2<<<gw, TPB, 0, stream>>>((const uint4*)g2q, csr, rowptr, rowend, dinv,
                                   b2, Wfc, bfc, out, n, npw);
}